// Round 5
// baseline (751.734 us; speedup 1.0000x reference)
//
#include <hip/hip_runtime.h>
#include <math.h>

constexpr int DIN = 256;
constexpr int HID = 128;
constexpr int LAT = 64;

typedef short bfrag __attribute__((ext_vector_type(8)));   // 8 bf16 (4 VGPRs)
typedef float f32x4 __attribute__((ext_vector_type(4)));

__device__ __forceinline__ float4 ld4(const float* p) { return *reinterpret_cast<const float4*>(p); }
__device__ __forceinline__ void st4(float* p, float4 v) { *reinterpret_cast<float4*>(p) = v; }

__device__ __forceinline__ unsigned short f2bf(float f) {
  unsigned int u = __float_as_uint(f);
  unsigned int r = (u + 0x7FFFu + ((u >> 16) & 1u)) >> 16;  // RNE
  return (unsigned short)r;
}

__device__ __forceinline__ float bf2f(unsigned short u) {
  return __uint_as_float(((unsigned int)u) << 16);
}

// ---------------- generic f32 GEMM: C[M,N] = A[M,K] @ B[K,N] (+ crow[N]) ----------------
__global__ __launch_bounds__(256) void gemm64(const float* __restrict__ A, const float* __restrict__ B,
                                              const float* __restrict__ crow, float* __restrict__ C,
                                              int M, int N, int K) {
  __shared__ float As[32][68];
  __shared__ float Bs[32][68];
  int t = threadIdx.x;
  int m0 = blockIdx.x * 64, n0 = blockIdx.y * 64;
  int tm = t & 15, tn = t >> 4;
  float acc[4][4];
#pragma unroll
  for (int i = 0; i < 4; i++)
#pragma unroll
    for (int j = 0; j < 4; j++) acc[i][j] = 0.f;

  for (int kt = 0; kt < K; kt += 32) {
#pragma unroll
    for (int i = 0; i < 2; ++i) {
      int f4 = t + i * 256;
      int m = f4 >> 3;
      int k4 = (f4 & 7) << 2;
      int gm = m0 + m;
      float4 v = make_float4(0.f, 0.f, 0.f, 0.f);
      if (gm < M) v = ld4(A + (size_t)gm * K + kt + k4);
      As[k4 + 0][m] = v.x; As[k4 + 1][m] = v.y; As[k4 + 2][m] = v.z; As[k4 + 3][m] = v.w;
    }
#pragma unroll
    for (int i = 0; i < 2; ++i) {
      int f4 = t + i * 256;
      int k = f4 >> 4;
      int n4 = (f4 & 15) << 2;
      float4 v = ld4(B + (size_t)(kt + k) * N + n0 + n4);
      st4(&Bs[k][n4], v);
    }
    __syncthreads();
#pragma unroll
    for (int k = 0; k < 32; ++k) {
      float4 a = ld4(&As[k][tm << 2]);
      float4 b = ld4(&Bs[k][tn << 2]);
      float av[4] = {a.x, a.y, a.z, a.w};
      float bv[4] = {b.x, b.y, b.z, b.w};
#pragma unroll
      for (int i = 0; i < 4; i++)
#pragma unroll
        for (int j = 0; j < 4; j++) acc[i][j] = fmaf(av[i], bv[j], acc[i][j]);
    }
    __syncthreads();
  }
#pragma unroll
  for (int i = 0; i < 4; ++i) {
    int gm = m0 + (tm << 2) + i;
    if (gm < M) {
      int nb = n0 + (tn << 2);
      float4 v = make_float4(acc[i][0], acc[i][1], acc[i][2], acc[i][3]);
      if (crow) { v.x += crow[nb]; v.y += crow[nb + 1]; v.z += crow[nb + 2]; v.w += crow[nb + 3]; }
      st4(C + (size_t)gm * N + nb, v);
    }
  }
}

// ---------------- attention scores ----------------
__global__ __launch_bounds__(256) void attn_scores(const float* __restrict__ xp,
                                                   const float* __restrict__ att_src,
                                                   const float* __restrict__ att_dst,
                                                   float* __restrict__ a_src, float* __restrict__ a_dst, int N) {
  int wid = threadIdx.x >> 6, lane = threadIdx.x & 63;
  int n = blockIdx.x * 4 + wid;
  if (n >= N) return;
  int h = lane >> 5;
  int f4 = (lane & 31) << 2;
  float4 v = ld4(xp + (size_t)n * 256 + h * 128 + f4);
  float4 as = ld4(att_src + h * 128 + f4);
  float4 ad = ld4(att_dst + h * 128 + f4);
  float ps = v.x * as.x + v.y * as.y + v.z * as.z + v.w * as.w;
  float pd = v.x * ad.x + v.y * ad.y + v.z * ad.z + v.w * ad.w;
#pragma unroll
  for (int m = 16; m >= 1; m >>= 1) { ps += __shfl_xor(ps, m); pd += __shfl_xor(pd, m); }
  if ((lane & 31) == 0) { a_src[n * 2 + h] = ps; a_dst[n * 2 + h] = pd; }
}

// ---------------- in-place f32 row -> bf16 half-row convert (wave per row) ----------------
__global__ __launch_bounds__(256) void cvt_rows_inplace(float* __restrict__ xp, int N) {
  int wid = threadIdx.x >> 6, lane = threadIdx.x & 63;
  int n = blockIdx.x * 4 + wid;
  float4 v = make_float4(0.f, 0.f, 0.f, 0.f);
  float* row = xp + (size_t)n * 256;
  if (n < N) v = ld4(row + (lane << 2));
  __syncthreads();
  if (n < N) {
    ushort4 o;
    o.x = f2bf(v.x); o.y = f2bf(v.y); o.z = f2bf(v.z); o.w = f2bf(v.w);
    ((ushort4*)row)[lane] = o;
  }
}

// ---------------- CSR build ----------------
__global__ void deg_count(const int* __restrict__ ei, int E, int Et, int* __restrict__ deg) {
  int i = blockIdx.x * blockDim.x + threadIdx.x;
  if (i >= Et) return;
  int d = (i < E) ? ei[E + i] : (i - E);
  atomicAdd(&deg[d], 1);
}

__global__ __launch_bounds__(256) void bsum_kernel(const int* __restrict__ deg, int N, int* __restrict__ bsum) {
  int t = threadIdx.x;
  int i = blockIdx.x * 256 + t;
  int v = (i < N) ? deg[i] : 0;
#pragma unroll
  for (int m = 32; m >= 1; m >>= 1) v += __shfl_xor(v, m);
  __shared__ int sh[4];
  if ((t & 63) == 0) sh[t >> 6] = v;
  __syncthreads();
  if (t == 0) bsum[blockIdx.x] = sh[0] + sh[1] + sh[2] + sh[3];
}

__global__ __launch_bounds__(256) void bscan_kernel(int* __restrict__ bsum, int B) {
  __shared__ int sh[256];
  int t = threadIdx.x;
  int v = (t < B) ? bsum[t] : 0;
  sh[t] = v;
  __syncthreads();
  for (int d = 1; d < 256; d <<= 1) {
    int x = (t >= d) ? sh[t - d] : 0;
    __syncthreads();
    sh[t] += x;
    __syncthreads();
  }
  if (t < B) bsum[t] = sh[t] - v;
}

__global__ __launch_bounds__(256) void scan_apply(const int* __restrict__ deg, const int* __restrict__ bsum, int N,
                                                  int* __restrict__ offs, int* __restrict__ cursor,
                                                  float* __restrict__ dinv) {
  int t = threadIdx.x;
  int i = blockIdx.x * 256 + t;
  int v = (i < N) ? deg[i] : 0;
  __shared__ int sh[256];
  sh[t] = v;
  __syncthreads();
  for (int d = 1; d < 256; d <<= 1) {
    int x = (t >= d) ? sh[t - d] : 0;
    __syncthreads();
    sh[t] += x;
    __syncthreads();
  }
  if (i < N) {
    int off = bsum[blockIdx.x] + sh[t] - v;
    offs[i] = off;
    cursor[i] = off;
    dinv[i] = rsqrtf((float)v);   // deg >= 1 (self-loop)
  }
}

__global__ void csr_fill(const int* __restrict__ ei, int E, int Et, int* __restrict__ cursor, int* __restrict__ csr) {
  int i = blockIdx.x * blockDim.x + threadIdx.x;
  if (i >= Et) return;
  int s, d;
  if (i < E) { s = ei[i]; d = ei[E + i]; } else { s = i - E; d = i - E; }
  int pos = atomicAdd(&cursor[d], 1);
  csr[pos] = s;
}

// ---------------- GAT softmax per dst node (wave per node) ----------------
__global__ __launch_bounds__(256) void gat_softmax(const int* __restrict__ offs, const int* __restrict__ deg,
                                                   const int* __restrict__ csr, const float* __restrict__ a_src,
                                                   const float* __restrict__ a_dst, float* __restrict__ alpha, int N) {
  int wid = threadIdx.x >> 6, lane = threadIdx.x & 63;
  int n = blockIdx.x * 4 + wid;
  if (n >= N) return;
  int off = offs[n], dg = deg[n];
  float ad0 = a_dst[n * 2], ad1 = a_dst[n * 2 + 1];
  float m0 = -1e30f, m1 = -1e30f;
  for (int k = lane; k < dg; k += 64) {
    int s = csr[off + k];
    float e0 = a_src[s * 2] + ad0; e0 = e0 >= 0.f ? e0 : 0.2f * e0;
    float e1 = a_src[s * 2 + 1] + ad1; e1 = e1 >= 0.f ? e1 : 0.2f * e1;
    m0 = fmaxf(m0, e0); m1 = fmaxf(m1, e1);
  }
#pragma unroll
  for (int m = 32; m >= 1; m >>= 1) { m0 = fmaxf(m0, __shfl_xor(m0, m)); m1 = fmaxf(m1, __shfl_xor(m1, m)); }
  float s0 = 0.f, s1 = 0.f;
  float2* al2 = (float2*)alpha;
  for (int k = lane; k < dg; k += 64) {
    int s = csr[off + k];
    float e0 = a_src[s * 2] + ad0; e0 = e0 >= 0.f ? e0 : 0.2f * e0;
    float e1 = a_src[s * 2 + 1] + ad1; e1 = e1 >= 0.f ? e1 : 0.2f * e1;
    float x0 = __expf(e0 - m0), x1 = __expf(e1 - m1);
    al2[off + k] = make_float2(x0, x1);
    s0 += x0; s1 += x1;
  }
#pragma unroll
  for (int m = 32; m >= 1; m >>= 1) { s0 += __shfl_xor(s0, m); s1 += __shfl_xor(s1, m); }
  float r0 = 1.f / s0, r1 = 1.f / s1;
  for (int k = lane; k < dg; k += 64) {
    float2 v = al2[off + k];
    al2[off + k] = make_float2(v.x * r0, v.y * r1);
  }
}

// ---------------- GAT aggregation, bf16 gather (wave per node) ----------------
__global__ __launch_bounds__(256) void gat_aggregate_bf(const int* __restrict__ offs, const int* __restrict__ deg,
                                                        const int* __restrict__ csr, const float* __restrict__ alpha,
                                                        const unsigned short* __restrict__ xpb,
                                                        const float* __restrict__ bias,
                                                        float* __restrict__ h1, int N) {
  int wid = threadIdx.x >> 6, lane = threadIdx.x & 63;
  int n = blockIdx.x * 4 + wid;
  if (n >= N) return;
  int off = offs[n], dg = deg[n];
  float4 acc = make_float4(0.f, 0.f, 0.f, 0.f);
  int f4 = lane << 2;
  bool h0 = lane < 32;
  const float2* al2 = (const float2*)alpha;
  for (int k = 0; k < dg; ++k) {
    int s = csr[off + k];
    float2 al = al2[off + k];
    float a = h0 ? al.x : al.y;
    ushort4 u = ((const ushort4*)(xpb + (size_t)s * 512))[lane];
    acc.x = fmaf(bf2f(u.x), a, acc.x);
    acc.y = fmaf(bf2f(u.y), a, acc.y);
    acc.z = fmaf(bf2f(u.z), a, acc.z);
    acc.w = fmaf(bf2f(u.w), a, acc.w);
  }
  float ox = __shfl_down(acc.x, 32);
  float oy = __shfl_down(acc.y, 32);
  float oz = __shfl_down(acc.z, 32);
  float ow = __shfl_down(acc.w, 32);
  if (h0) {
    float4 b = ld4(bias + f4);
    float4 o;
    o.x = fmaxf(0.f, (acc.x + ox) * 0.5f + b.x);
    o.y = fmaxf(0.f, (acc.y + oy) * 0.5f + b.y);
    o.z = fmaxf(0.f, (acc.z + oz) * 0.5f + b.z);
    o.w = fmaxf(0.f, (acc.w + ow) * 0.5f + b.w);
    st4(h1 + (size_t)n * 128 + f4, o);
  }
}

// ---------------- BatchNorm stats ----------------
template <int C>
__global__ __launch_bounds__(256) void bn_stats(const float* __restrict__ h, int N, float* __restrict__ P,
                                                float* __restrict__ PS) {
  constexpr int R = 256 / C;
  __shared__ float sh[256], sh2[256];
  int t = threadIdx.x;
  int c = t % C, r = t / C;
  float s = 0.f, ss = 0.f;
  for (int n = blockIdx.x * R + r; n < N; n += gridDim.x * R) {
    float v = h[(size_t)n * C + c];
    s += v; ss += v * v;
  }
  sh[t] = s; sh2[t] = ss;
  __syncthreads();
  if (r == 0) {
#pragma unroll
    for (int i = 1; i < R; ++i) { s += sh[i * C + c]; ss += sh2[i * C + c]; }
    P[blockIdx.x * C + c] = s;
    PS[blockIdx.x * C + c] = ss;
  }
}

template <int C>
__global__ void bn_reduce(const float* __restrict__ P, const float* __restrict__ PS, int G, int N,
                          const float* __restrict__ g, const float* __restrict__ b,
                          float* __restrict__ svec, float* __restrict__ tvec) {
  int c = threadIdx.x;
  if (c >= C) return;
  float s = 0.f, ss = 0.f;
  for (int i = 0; i < G; ++i) { s += P[i * C + c]; ss += PS[i * C + c]; }
  float mean = s / N;
  float var = ss / N - mean * mean;
  float sc = g[c] * rsqrtf(var + 1e-5f);
  svec[c] = sc;
  tvec[c] = b[c] - mean * sc;
}

__global__ __launch_bounds__(256) void fold_gcn(const float* __restrict__ W, const float* __restrict__ svec,
                                                const float* __restrict__ tvec, float* __restrict__ Wf,
                                                float* __restrict__ cvec) {
  int t = threadIdx.x;
  for (int i = t; i < 128 * 64; i += 256) {
    int k = i >> 6;
    Wf[i] = svec[k] * W[i];
  }
  if (t < 64) {
    float c = 0.f;
    for (int k = 0; k < 128; ++k) c += tvec[k] * W[k * 64 + t];
    cvec[t] = c;
  }
}

__global__ __launch_bounds__(256) void fold_mulv(const float* __restrict__ Wmu, const float* __restrict__ mub,
                                                 const float* __restrict__ Wlv, const float* __restrict__ lvb,
                                                 const float* __restrict__ svec, const float* __restrict__ tvec,
                                                 float* __restrict__ Wmuf, float* __restrict__ cmu,
                                                 float* __restrict__ Wlvf, float* __restrict__ clv) {
  int t = threadIdx.x;
  for (int i = t; i < 4096; i += 256) {
    int k = i >> 6;
    Wmuf[i] = svec[k] * Wmu[i];
    Wlvf[i] = svec[k] * Wlv[i];
  }
  if (t < 64) {
    float cm = mub[t], cl = lvb[t];
    for (int k = 0; k < 64; ++k) { cm += tvec[k] * Wmu[k * 64 + t]; cl += tvec[k] * Wlv[k * 64 + t]; }
    cmu[t] = cm; clv[t] = cl;
  }
}

// ---------------- GCN aggregation ----------------
__global__ __launch_bounds__(256) void gcn_aggregate(const int* __restrict__ offs, const int* __restrict__ deg,
                                                     const int* __restrict__ csr, const float* __restrict__ xp2,
                                                     const float* __restrict__ dinv, const float* __restrict__ bias,
                                                     float* __restrict__ g2, int N) {
  int wid = threadIdx.x >> 6, lane = threadIdx.x & 63;
  int n = blockIdx.x * 4 + wid;
  if (n >= N) return;
  int off = offs[n], dg = deg[n];
  float acc = 0.f;
  for (int k = 0; k < dg; ++k) {
    int s = csr[off + k];
    acc = fmaf(xp2[(size_t)s * 64 + lane], dinv[s], acc);
  }
  float v = acc * dinv[n] + bias[lane];
  g2[(size_t)n * 64 + lane] = fmaxf(v, 0.f);
}

// ---------------- reparameterize ----------------
__global__ void reparam(const float* __restrict__ mu, const float* __restrict__ lv,
                        const float* __restrict__ eps, float* __restrict__ z, int total) {
  int i = blockIdx.x * blockDim.x + threadIdx.x;
  if (i >= total) return;
  z[i] = fmaf(eps[i], __expf(0.5f * lv[i]), mu[i]);
}

// ---------------- bf16 conversion of res_z ----------------
__global__ void cvt_bf16(const float* __restrict__ in, unsigned short* __restrict__ out, int n4) {
  int i = blockIdx.x * blockDim.x + threadIdx.x;
  if (i >= n4) return;
  float4 v = ((const float4*)in)[i];
  ushort4 o;
  o.x = f2bf(v.x); o.y = f2bf(v.y); o.z = f2bf(v.z); o.w = f2bf(v.w);
  ((ushort4*)out)[i] = o;
}

// ---------------- prep W1 → bf16 decoder-ready layout [4 kt][256 j][32 k] (unpadded) ----------------
__global__ void prep_W1(const float* __restrict__ W1, unsigned short* __restrict__ W1t) {
  int i = blockIdx.x * blockDim.x + threadIdx.x;
  if (i >= 4 * 256 * 32) return;
  int kt = i >> 13;            // / 8192
  int rem = i & 8191;
  int j = rem >> 5;            // / 32
  int kp = rem & 31;
  W1t[i] = f2bf(W1[(size_t)(kt * 32 + kp) * 256 + j]);
}

// ---------------- MFMA decoder, B (W1) in registers ----------------
// block = 64 edges, 256 threads (4 waves), wave wv owns j in [64wv, 64wv+64), K=128.
// A: LDS [64 e][128 k] bf16, XOR-swizzled (byte ^= (e&7)<<4). B: 16 bfrags/wave in VGPRs,
// loaded once from W1t [kt][256 j][32 k]. Single barrier; no B staging through LDS.
__global__ __launch_bounds__(256) void decoder_mfma(const int* __restrict__ ei, int E,
                                                    const unsigned short* __restrict__ rzb,
                                                    const unsigned short* __restrict__ W1t,
                                                    const float* __restrict__ b1, const float* __restrict__ W2,
                                                    const float* __restrict__ b2, float* __restrict__ recon) {
  __shared__ unsigned short Als[64 * 128];   // 16 KB
  __shared__ float red[4][64];
  int t = threadIdx.x;
  int wv = t >> 6, l = t & 63;
  int lg = l >> 4, ll = l & 15;
  int e0 = blockIdx.x * 64;

  // ---- B fragments in registers: breg[kt][fn] (64 VGPRs), L2-resident read ----
  bfrag breg[4][4];
#pragma unroll
  for (int kt = 0; kt < 4; ++kt)
#pragma unroll
    for (int fn = 0; fn < 4; ++fn) {
      int j = wv * 64 + fn * 16 + ll;
      breg[kt][fn] = *(const bfrag*)(W1t + kt * 8192 + j * 32 + lg * 8);
    }

  // ---- stage A: gather e_emb rows (bf16), swizzled ----
  {
    int e = t >> 2;
    int part = (t >> 1) & 1;
    int half = t & 1;
    int eg = e0 + e;
    if (eg >= E) eg = E - 1;
    int r = (part == 0) ? ei[eg] : ei[E + eg];
    const uint4* gsrc = (const uint4*)(rzb + (size_t)r * 64 + half * 32);
    int bo0 = part * 128 + half * 64;
    int swz = (e & 7) << 4;
#pragma unroll
    for (int c = 0; c < 4; ++c) {
      uint4 v = gsrc[c];
      int bo = bo0 + c * 16;
      *(uint4*)&Als[e * 128 + ((bo ^ swz) >> 1)] = v;
    }
  }

  f32x4 acc[4][4];
#pragma unroll
  for (int a = 0; a < 4; ++a)
#pragma unroll
    for (int b = 0; b < 4; ++b) acc[a][b] = (f32x4){0.f, 0.f, 0.f, 0.f};

  __syncthreads();

#pragma unroll
  for (int kt = 0; kt < 4; ++kt) {
    bfrag af[4];
#pragma unroll
    for (int fm = 0; fm < 4; ++fm) {
      int e = fm * 16 + ll;
      int bo = kt * 64 + lg * 16;
      af[fm] = *(const bfrag*)&Als[e * 128 + ((bo ^ ((e & 7) << 4)) >> 1)];
    }
#pragma unroll
    for (int fn = 0; fn < 4; ++fn)
#pragma unroll
      for (int fm = 0; fm < 4; ++fm)
        acc[fm][fn] = __builtin_amdgcn_mfma_f32_16x16x32_bf16(af[fm], breg[kt][fn], acc[fm][fn], 0, 0, 0);
  }

  // ---- epilogue: relu + W2 dot, reduce ----
  float bj[4], wj[4];
#pragma unroll
  for (int fn = 0; fn < 4; ++fn) {
    int j = wv * 64 + fn * 16 + ll;
    bj[fn] = b1[j];
    wj[fn] = W2[j];
  }
#pragma unroll
  for (int fm = 0; fm < 4; ++fm) {
    float pr[4] = {0.f, 0.f, 0.f, 0.f};
#pragma unroll
    for (int fn = 0; fn < 4; ++fn) {
#pragma unroll
      for (int r = 0; r < 4; ++r)
        pr[r] = fmaf(fmaxf(acc[fm][fn][r] + bj[fn], 0.f), wj[fn], pr[r]);
    }
#pragma unroll
    for (int m = 8; m >= 1; m >>= 1) {
#pragma unroll
      for (int r = 0; r < 4; ++r) pr[r] += __shfl_xor(pr[r], m);
    }
    if (ll == 0) {
#pragma unroll
      for (int r = 0; r < 4; ++r) red[wv][fm * 16 + lg * 4 + r] = pr[r];
    }
  }
  __syncthreads();
  if (t < 64) {
    int eg = e0 + t;
    if (eg < E) recon[eg] = red[0][t] + red[1][t] + red[2][t] + red[3][t] + b2[0];
  }
}

extern "C" void kernel_launch(void* const* d_in, const int* in_sizes, int n_in,
                              void* d_out, int out_size, void* d_ws, size_t ws_size,
                              hipStream_t stream) {
  const float* x = (const float*)d_in[0];
  const int* ei = (const int*)d_in[1];
  const float* gat_W = (const float*)d_in[2];
  const float* att_src = (const float*)d_in[3];
  const float* att_dst = (const float*)d_in[4];
  const float* gat_bias = (const float*)d_in[5];
  const float* bn1_g = (const float*)d_in[6];
  const float* bn1_b = (const float*)d_in[7];
  const float* gcn_W = (const float*)d_in[8];
  const float* gcn_bias = (const float*)d_in[9];
  const float* bn2_g = (const float*)d_in[10];
  const float* bn2_b = (const float*)d_in[11];
  const float* mu_W = (const float*)d_in[12];
  const float* mu_b = (const float*)d_in[13];
  const float* lv_W = (const float*)d_in[14];
  const float* lv_b = (const float*)d_in[15];
  const float* res_W = (const float*)d_in[16];
  const float* res_b = (const float*)d_in[17];
  const float* dec_W1 = (const float*)d_in[18];
  const float* dec_b1 = (const float*)d_in[19];
  const float* dec_W2 = (const float*)d_in[20];
  const float* dec_b2 = (const float*)d_in[21];
  const float* eps = (const float*)d_in[22];

  int N = in_sizes[0] / DIN;   // 50000
  int E = in_sizes[1] / 2;     // 800000
  int Et = E + N;
  int NB = (N + 255) / 256;    // scan chunks (<= 256)

  float* ws = (float*)d_ws;
  size_t off = 0;
  float* xp = ws; off += (size_t)N * 256;
  unsigned short* xpb = (unsigned short*)xp;   // bf16 rows in place, stride 512 ushorts
  float* xp2 = xp;
  float* g2 = xp + (size_t)N * 64;
  float* zb = xp + (size_t)N * 128;
  float* rz = xp + (size_t)N * 192;
  unsigned short* rzb = (unsigned short*)zb;
  float* h1 = ws + off; off += (size_t)N * 128;
  float* a_src = ws + off; off += (size_t)2 * N;
  float* a_dst = ws + off; off += (size_t)2 * N;
  float* alpha = ws + off; off += (size_t)Et * 2;
  float* dinv = ws + off; off += N;
  float* P = ws + off; off += 128 * 128;
  float* PS = ws + off; off += 128 * 128;
  float* svec = ws + off; off += 128;
  float* tvec = ws + off; off += 128;
  float* W2f = ws + off; off += 128 * 64;
  float* c2 = ws + off; off += 64;
  float* Wmuf = ws + off; off += 64 * 64;
  float* cmu = ws + off; off += 64;
  float* Wlvf = ws + off; off += 64 * 64;
  float* clv = ws + off; off += 64;
  unsigned short* W1t = (unsigned short*)(ws + off); off += 16384;  // 4*256*32 bf16
  int* deg = (int*)(ws + off); off += N;
  int* offs = (int*)(ws + off); off += N;
  int* cursor = (int*)(ws + off); off += N;
  int* bsum = (int*)(ws + off); off += 256;
  int* csr = (int*)(ws + off); off += Et;

  float* recon = (float*)d_out;
  float* mu = recon + E;
  float* lv = mu + (size_t)N * LAT;

  // 0. prep W1 (independent, do early)
  prep_W1<<<(4 * 256 * 32 + 255) / 256, 256, 0, stream>>>(dec_W1, W1t);

  // 1. xp = x @ gat_W
  dim3 gA((N + 63) / 64, DIN / 64);
  gemm64<<<gA, 256, 0, stream>>>(x, gat_W, nullptr, xp, N, DIN, DIN);

  // 2. attention scores (last f32-xp consumer)
  attn_scores<<<(N + 3) / 4, 256, 0, stream>>>(xp, att_src, att_dst, a_src, a_dst, N);

  // 2b. convert xp rows to bf16 in place (halves the gather bytes)
  cvt_rows_inplace<<<(N + 3) / 4, 256, 0, stream>>>(xp, N);

  // 3. CSR build (parallel 3-phase scan)
  hipMemsetAsync(deg, 0, (size_t)N * sizeof(int), stream);
  deg_count<<<(Et + 255) / 256, 256, 0, stream>>>(ei, E, Et, deg);
  bsum_kernel<<<NB, 256, 0, stream>>>(deg, N, bsum);
  bscan_kernel<<<1, 256, 0, stream>>>(bsum, NB);
  scan_apply<<<NB, 256, 0, stream>>>(deg, bsum, N, offs, cursor, dinv);
  csr_fill<<<(Et + 255) / 256, 256, 0, stream>>>(ei, E, Et, cursor, csr);

  // 4. GAT softmax + aggregation (bf16 gather)
  gat_softmax<<<(N + 3) / 4, 256, 0, stream>>>(offs, deg, csr, a_src, a_dst, alpha, N);
  gat_aggregate_bf<<<(N + 3) / 4, 256, 0, stream>>>(offs, deg, csr, alpha, xpb, gat_bias, h1, N);

  // 5. BN1 folded into GCN weights
  bn_stats<128><<<128, 256, 0, stream>>>(h1, N, P, PS);
  bn_reduce<128><<<1, 128, 0, stream>>>(P, PS, 128, N, bn1_g, bn1_b, svec, tvec);
  fold_gcn<<<1, 256, 0, stream>>>(gcn_W, svec, tvec, W2f, c2);
  dim3 gB((N + 63) / 64, 1);
  gemm64<<<gB, 256, 0, stream>>>(h1, W2f, c2, xp2, N, 64, 128);

  // 6. GCN aggregation
  gcn_aggregate<<<(N + 3) / 4, 256, 0, stream>>>(offs, deg, csr, xp2, dinv, gcn_bias, g2, N);

  // 7. BN2 folded into mu/lv
  bn_stats<64><<<128, 256, 0, stream>>>(g2, N, P, PS);
  bn_reduce<64><<<1, 64, 0, stream>>>(P, PS, 128, N, bn2_g, bn2_b, svec, tvec);
  fold_mulv<<<1, 256, 0, stream>>>(mu_W, mu_b, lv_W, lv_b, svec, tvec, Wmuf, cmu, Wlvf, clv);
  gemm64<<<gB, 256, 0, stream>>>(g2, Wmuf, cmu, mu, N, 64, 64);
  gemm64<<<gB, 256, 0, stream>>>(g2, Wlvf, clv, lv, N, 64, 64);

  // 8. z, res_z, res_z → bf16
  reparam<<<(N * 64 + 255) / 256, 256, 0, stream>>>(mu, lv, eps, zb, N * 64);
  gemm64<<<gB, 256, 0, stream>>>(zb, res_W, res_b, rz, N, 64, 64);
  cvt_bf16<<<(N * 16 + 255) / 256, 256, 0, stream>>>(rz, rzb, N * 16);

  // 9. MFMA decoder (B in registers)
  decoder_mfma<<<(E + 63) / 64, 256, 0, stream>>>(ei, E, rzb, W1t, dec_b1, dec_W2, dec_b2, recon);
}

// Round 6
// 748.650 us; speedup vs baseline: 1.0041x; 1.0041x over previous
//
#include <hip/hip_runtime.h>
#include <math.h>

constexpr int DIN = 256;
constexpr int HID = 128;
constexpr int LAT = 64;

typedef short bfrag __attribute__((ext_vector_type(8)));   // 8 bf16 (4 VGPRs)
typedef float f32x4 __attribute__((ext_vector_type(4)));

__device__ __forceinline__ float4 ld4(const float* p) { return *reinterpret_cast<const float4*>(p); }
__device__ __forceinline__ void st4(float* p, float4 v) { *reinterpret_cast<float4*>(p) = v; }

__device__ __forceinline__ unsigned short f2bf(float f) {
  unsigned int u = __float_as_uint(f);
  unsigned int r = (u + 0x7FFFu + ((u >> 16) & 1u)) >> 16;  // RNE
  return (unsigned short)r;
}

__device__ __forceinline__ float bf2f(unsigned short u) {
  return __uint_as_float(((unsigned int)u) << 16);
}

// ---------------- generic f32 GEMM: C[M,N] = A[M,K] @ B[K,N] (+ crow[N]) ----------------
__global__ __launch_bounds__(256) void gemm64(const float* __restrict__ A, const float* __restrict__ B,
                                              const float* __restrict__ crow, float* __restrict__ C,
                                              int M, int N, int K) {
  __shared__ float As[32][68];
  __shared__ float Bs[32][68];
  int t = threadIdx.x;
  int m0 = blockIdx.x * 64, n0 = blockIdx.y * 64;
  int tm = t & 15, tn = t >> 4;
  float acc[4][4];
#pragma unroll
  for (int i = 0; i < 4; i++)
#pragma unroll
    for (int j = 0; j < 4; j++) acc[i][j] = 0.f;

  for (int kt = 0; kt < K; kt += 32) {
#pragma unroll
    for (int i = 0; i < 2; ++i) {
      int f4 = t + i * 256;
      int m = f4 >> 3;
      int k4 = (f4 & 7) << 2;
      int gm = m0 + m;
      float4 v = make_float4(0.f, 0.f, 0.f, 0.f);
      if (gm < M) v = ld4(A + (size_t)gm * K + kt + k4);
      As[k4 + 0][m] = v.x; As[k4 + 1][m] = v.y; As[k4 + 2][m] = v.z; As[k4 + 3][m] = v.w;
    }
#pragma unroll
    for (int i = 0; i < 2; ++i) {
      int f4 = t + i * 256;
      int k = f4 >> 4;
      int n4 = (f4 & 15) << 2;
      float4 v = ld4(B + (size_t)(kt + k) * N + n0 + n4);
      st4(&Bs[k][n4], v);
    }
    __syncthreads();
#pragma unroll
    for (int k = 0; k < 32; ++k) {
      float4 a = ld4(&As[k][tm << 2]);
      float4 b = ld4(&Bs[k][tn << 2]);
      float av[4] = {a.x, a.y, a.z, a.w};
      float bv[4] = {b.x, b.y, b.z, b.w};
#pragma unroll
      for (int i = 0; i < 4; i++)
#pragma unroll
        for (int j = 0; j < 4; j++) acc[i][j] = fmaf(av[i], bv[j], acc[i][j]);
    }
    __syncthreads();
  }
#pragma unroll
  for (int i = 0; i < 4; ++i) {
    int gm = m0 + (tm << 2) + i;
    if (gm < M) {
      int nb = n0 + (tn << 2);
      float4 v = make_float4(acc[i][0], acc[i][1], acc[i][2], acc[i][3]);
      if (crow) { v.x += crow[nb]; v.y += crow[nb + 1]; v.z += crow[nb + 2]; v.w += crow[nb + 3]; }
      st4(C + (size_t)gm * N + nb, v);
    }
  }
}

// ---------------- attention scores ----------------
__global__ __launch_bounds__(256) void attn_scores(const float* __restrict__ xp,
                                                   const float* __restrict__ att_src,
                                                   const float* __restrict__ att_dst,
                                                   float* __restrict__ a_src, float* __restrict__ a_dst, int N) {
  int wid = threadIdx.x >> 6, lane = threadIdx.x & 63;
  int n = blockIdx.x * 4 + wid;
  if (n >= N) return;
  int h = lane >> 5;
  int f4 = (lane & 31) << 2;
  float4 v = ld4(xp + (size_t)n * 256 + h * 128 + f4);
  float4 as = ld4(att_src + h * 128 + f4);
  float4 ad = ld4(att_dst + h * 128 + f4);
  float ps = v.x * as.x + v.y * as.y + v.z * as.z + v.w * as.w;
  float pd = v.x * ad.x + v.y * ad.y + v.z * ad.z + v.w * ad.w;
#pragma unroll
  for (int m = 16; m >= 1; m >>= 1) { ps += __shfl_xor(ps, m); pd += __shfl_xor(pd, m); }
  if ((lane & 31) == 0) { a_src[n * 2 + h] = ps; a_dst[n * 2 + h] = pd; }
}

// ---------------- in-place f32 row -> bf16 half-row convert (wave per row) ----------------
__global__ __launch_bounds__(256) void cvt_rows_inplace(float* __restrict__ xp, int N) {
  int wid = threadIdx.x >> 6, lane = threadIdx.x & 63;
  int n = blockIdx.x * 4 + wid;
  float4 v = make_float4(0.f, 0.f, 0.f, 0.f);
  float* row = xp + (size_t)n * 256;
  if (n < N) v = ld4(row + (lane << 2));
  __syncthreads();
  if (n < N) {
    ushort4 o;
    o.x = f2bf(v.x); o.y = f2bf(v.y); o.z = f2bf(v.z); o.w = f2bf(v.w);
    ((ushort4*)row)[lane] = o;
  }
}

// ---------------- CSR build ----------------
__global__ void deg_count(const int* __restrict__ ei, int E, int Et, int* __restrict__ deg) {
  int i = blockIdx.x * blockDim.x + threadIdx.x;
  if (i >= Et) return;
  int d = (i < E) ? ei[E + i] : (i - E);
  atomicAdd(&deg[d], 1);
}

__global__ __launch_bounds__(256) void bsum_kernel(const int* __restrict__ deg, int N, int* __restrict__ bsum) {
  int t = threadIdx.x;
  int i = blockIdx.x * 256 + t;
  int v = (i < N) ? deg[i] : 0;
#pragma unroll
  for (int m = 32; m >= 1; m >>= 1) v += __shfl_xor(v, m);
  __shared__ int sh[4];
  if ((t & 63) == 0) sh[t >> 6] = v;
  __syncthreads();
  if (t == 0) bsum[blockIdx.x] = sh[0] + sh[1] + sh[2] + sh[3];
}

__global__ __launch_bounds__(256) void bscan_kernel(int* __restrict__ bsum, int B) {
  __shared__ int sh[256];
  int t = threadIdx.x;
  int v = (t < B) ? bsum[t] : 0;
  sh[t] = v;
  __syncthreads();
  for (int d = 1; d < 256; d <<= 1) {
    int x = (t >= d) ? sh[t - d] : 0;
    __syncthreads();
    sh[t] += x;
    __syncthreads();
  }
  if (t < B) bsum[t] = sh[t] - v;
}

__global__ __launch_bounds__(256) void scan_apply(const int* __restrict__ deg, const int* __restrict__ bsum, int N,
                                                  int* __restrict__ offs, int* __restrict__ cursor,
                                                  float* __restrict__ dinv) {
  int t = threadIdx.x;
  int i = blockIdx.x * 256 + t;
  int v = (i < N) ? deg[i] : 0;
  __shared__ int sh[256];
  sh[t] = v;
  __syncthreads();
  for (int d = 1; d < 256; d <<= 1) {
    int x = (t >= d) ? sh[t - d] : 0;
    __syncthreads();
    sh[t] += x;
    __syncthreads();
  }
  if (i < N) {
    int off = bsum[blockIdx.x] + sh[t] - v;
    offs[i] = off;
    cursor[i] = off;
    dinv[i] = rsqrtf((float)v);   // deg >= 1 (self-loop)
  }
}

__global__ void csr_fill(const int* __restrict__ ei, int E, int Et, int* __restrict__ cursor, int* __restrict__ csr) {
  int i = blockIdx.x * blockDim.x + threadIdx.x;
  if (i >= Et) return;
  int s, d;
  if (i < E) { s = ei[i]; d = ei[E + i]; } else { s = i - E; d = i - E; }
  int pos = atomicAdd(&cursor[d], 1);
  csr[pos] = s;
}

// ---------------- GAT softmax per dst node (wave per node) ----------------
__global__ __launch_bounds__(256) void gat_softmax(const int* __restrict__ offs, const int* __restrict__ deg,
                                                   const int* __restrict__ csr, const float* __restrict__ a_src,
                                                   const float* __restrict__ a_dst, float* __restrict__ alpha, int N) {
  int wid = threadIdx.x >> 6, lane = threadIdx.x & 63;
  int n = blockIdx.x * 4 + wid;
  if (n >= N) return;
  int off = offs[n], dg = deg[n];
  float ad0 = a_dst[n * 2], ad1 = a_dst[n * 2 + 1];
  float m0 = -1e30f, m1 = -1e30f;
  for (int k = lane; k < dg; k += 64) {
    int s = csr[off + k];
    float e0 = a_src[s * 2] + ad0; e0 = e0 >= 0.f ? e0 : 0.2f * e0;
    float e1 = a_src[s * 2 + 1] + ad1; e1 = e1 >= 0.f ? e1 : 0.2f * e1;
    m0 = fmaxf(m0, e0); m1 = fmaxf(m1, e1);
  }
#pragma unroll
  for (int m = 32; m >= 1; m >>= 1) { m0 = fmaxf(m0, __shfl_xor(m0, m)); m1 = fmaxf(m1, __shfl_xor(m1, m)); }
  float s0 = 0.f, s1 = 0.f;
  float2* al2 = (float2*)alpha;
  for (int k = lane; k < dg; k += 64) {
    int s = csr[off + k];
    float e0 = a_src[s * 2] + ad0; e0 = e0 >= 0.f ? e0 : 0.2f * e0;
    float e1 = a_src[s * 2 + 1] + ad1; e1 = e1 >= 0.f ? e1 : 0.2f * e1;
    float x0 = __expf(e0 - m0), x1 = __expf(e1 - m1);
    al2[off + k] = make_float2(x0, x1);
    s0 += x0; s1 += x1;
  }
#pragma unroll
  for (int m = 32; m >= 1; m >>= 1) { s0 += __shfl_xor(s0, m); s1 += __shfl_xor(s1, m); }
  float r0 = 1.f / s0, r1 = 1.f / s1;
  for (int k = lane; k < dg; k += 64) {
    float2 v = al2[off + k];
    al2[off + k] = make_float2(v.x * r0, v.y * r1);
  }
}

// ---------------- GAT aggregation, bf16 gather (wave per node) ----------------
__global__ __launch_bounds__(256) void gat_aggregate_bf(const int* __restrict__ offs, const int* __restrict__ deg,
                                                        const int* __restrict__ csr, const float* __restrict__ alpha,
                                                        const unsigned short* __restrict__ xpb,
                                                        const float* __restrict__ bias,
                                                        float* __restrict__ h1, int N) {
  int wid = threadIdx.x >> 6, lane = threadIdx.x & 63;
  int n = blockIdx.x * 4 + wid;
  if (n >= N) return;
  int off = offs[n], dg = deg[n];
  float4 acc = make_float4(0.f, 0.f, 0.f, 0.f);
  int f4 = lane << 2;
  bool h0 = lane < 32;
  const float2* al2 = (const float2*)alpha;
  for (int k = 0; k < dg; ++k) {
    int s = csr[off + k];
    float2 al = al2[off + k];
    float a = h0 ? al.x : al.y;
    ushort4 u = ((const ushort4*)(xpb + (size_t)s * 512))[lane];
    acc.x = fmaf(bf2f(u.x), a, acc.x);
    acc.y = fmaf(bf2f(u.y), a, acc.y);
    acc.z = fmaf(bf2f(u.z), a, acc.z);
    acc.w = fmaf(bf2f(u.w), a, acc.w);
  }
  float ox = __shfl_down(acc.x, 32);
  float oy = __shfl_down(acc.y, 32);
  float oz = __shfl_down(acc.z, 32);
  float ow = __shfl_down(acc.w, 32);
  if (h0) {
    float4 b = ld4(bias + f4);
    float4 o;
    o.x = fmaxf(0.f, (acc.x + ox) * 0.5f + b.x);
    o.y = fmaxf(0.f, (acc.y + oy) * 0.5f + b.y);
    o.z = fmaxf(0.f, (acc.z + oz) * 0.5f + b.z);
    o.w = fmaxf(0.f, (acc.w + ow) * 0.5f + b.w);
    st4(h1 + (size_t)n * 128 + f4, o);
  }
}

// ---------------- BatchNorm stats ----------------
template <int C>
__global__ __launch_bounds__(256) void bn_stats(const float* __restrict__ h, int N, float* __restrict__ P,
                                                float* __restrict__ PS) {
  constexpr int R = 256 / C;
  __shared__ float sh[256], sh2[256];
  int t = threadIdx.x;
  int c = t % C, r = t / C;
  float s = 0.f, ss = 0.f;
  for (int n = blockIdx.x * R + r; n < N; n += gridDim.x * R) {
    float v = h[(size_t)n * C + c];
    s += v; ss += v * v;
  }
  sh[t] = s; sh2[t] = ss;
  __syncthreads();
  if (r == 0) {
#pragma unroll
    for (int i = 1; i < R; ++i) { s += sh[i * C + c]; ss += sh2[i * C + c]; }
    P[blockIdx.x * C + c] = s;
    PS[blockIdx.x * C + c] = ss;
  }
}

template <int C>
__global__ void bn_reduce(const float* __restrict__ P, const float* __restrict__ PS, int G, int N,
                          const float* __restrict__ g, const float* __restrict__ b,
                          float* __restrict__ svec, float* __restrict__ tvec) {
  int c = threadIdx.x;
  if (c >= C) return;
  float s = 0.f, ss = 0.f;
  for (int i = 0; i < G; ++i) { s += P[i * C + c]; ss += PS[i * C + c]; }
  float mean = s / N;
  float var = ss / N - mean * mean;
  float sc = g[c] * rsqrtf(var + 1e-5f);
  svec[c] = sc;
  tvec[c] = b[c] - mean * sc;
}

__global__ __launch_bounds__(256) void fold_gcn(const float* __restrict__ W, const float* __restrict__ svec,
                                                const float* __restrict__ tvec, float* __restrict__ Wf,
                                                float* __restrict__ cvec) {
  int t = threadIdx.x;
  for (int i = t; i < 128 * 64; i += 256) {
    int k = i >> 6;
    Wf[i] = svec[k] * W[i];
  }
  if (t < 64) {
    float c = 0.f;
    for (int k = 0; k < 128; ++k) c += tvec[k] * W[k * 64 + t];
    cvec[t] = c;
  }
}

__global__ __launch_bounds__(256) void fold_mulv(const float* __restrict__ Wmu, const float* __restrict__ mub,
                                                 const float* __restrict__ Wlv, const float* __restrict__ lvb,
                                                 const float* __restrict__ svec, const float* __restrict__ tvec,
                                                 float* __restrict__ Wmuf, float* __restrict__ cmu,
                                                 float* __restrict__ Wlvf, float* __restrict__ clv) {
  int t = threadIdx.x;
  for (int i = t; i < 4096; i += 256) {
    int k = i >> 6;
    Wmuf[i] = svec[k] * Wmu[i];
    Wlvf[i] = svec[k] * Wlv[i];
  }
  if (t < 64) {
    float cm = mub[t], cl = lvb[t];
    for (int k = 0; k < 64; ++k) { cm += tvec[k] * Wmu[k * 64 + t]; cl += tvec[k] * Wlv[k * 64 + t]; }
    cmu[t] = cm; clv[t] = cl;
  }
}

// ---------------- GCN aggregation ----------------
__global__ __launch_bounds__(256) void gcn_aggregate(const int* __restrict__ offs, const int* __restrict__ deg,
                                                     const int* __restrict__ csr, const float* __restrict__ xp2,
                                                     const float* __restrict__ dinv, const float* __restrict__ bias,
                                                     float* __restrict__ g2, int N) {
  int wid = threadIdx.x >> 6, lane = threadIdx.x & 63;
  int n = blockIdx.x * 4 + wid;
  if (n >= N) return;
  int off = offs[n], dg = deg[n];
  float acc = 0.f;
  for (int k = 0; k < dg; ++k) {
    int s = csr[off + k];
    acc = fmaf(xp2[(size_t)s * 64 + lane], dinv[s], acc);
  }
  float v = acc * dinv[n] + bias[lane];
  g2[(size_t)n * 64 + lane] = fmaxf(v, 0.f);
}

// ---------------- reparameterize ----------------
__global__ void reparam(const float* __restrict__ mu, const float* __restrict__ lv,
                        const float* __restrict__ eps, float* __restrict__ z, int total) {
  int i = blockIdx.x * blockDim.x + threadIdx.x;
  if (i >= total) return;
  z[i] = fmaf(eps[i], __expf(0.5f * lv[i]), mu[i]);
}

// ---------------- bf16 conversion of res_z ----------------
__global__ void cvt_bf16(const float* __restrict__ in, unsigned short* __restrict__ out, int n4) {
  int i = blockIdx.x * blockDim.x + threadIdx.x;
  if (i >= n4) return;
  float4 v = ((const float4*)in)[i];
  ushort4 o;
  o.x = f2bf(v.x); o.y = f2bf(v.y); o.z = f2bf(v.z); o.w = f2bf(v.w);
  ((ushort4*)out)[i] = o;
}

// ---------------- prep W1 → bf16 decoder-ready layout [4 kt][256 j][32 k] (unpadded) ----------------
__global__ void prep_W1(const float* __restrict__ W1, unsigned short* __restrict__ W1t) {
  int i = blockIdx.x * blockDim.x + threadIdx.x;
  if (i >= 4 * 256 * 32) return;
  int kt = i >> 13;            // / 8192
  int rem = i & 8191;
  int j = rem >> 5;            // / 32
  int kp = rem & 31;
  W1t[i] = f2bf(W1[(size_t)(kt * 32 + kp) * 256 + j]);
}

// ---------------- MFMA decoder: persistent multi-tile, B in registers, pipelined A ----------------
// grid-stride over tiles of 64 edges. B fragments (W1) loaded ONCE per block (amortized).
// A double-buffered in LDS; next tile's gather issued into VGPRs BEFORE current tile's
// MFMA+epilogue (latency hides under compute), ds_write after the barrier.
__global__ __launch_bounds__(256) void decoder_mfma(const int* __restrict__ ei, int E, int ntiles,
                                                    const unsigned short* __restrict__ rzb,
                                                    const unsigned short* __restrict__ W1t,
                                                    const float* __restrict__ b1, const float* __restrict__ W2,
                                                    const float* __restrict__ b2, float* __restrict__ recon) {
  __shared__ unsigned short Als[2][64 * 128];   // 2 x 16 KB
  __shared__ float red[4][64];
  int t = threadIdx.x;
  int wv = t >> 6, l = t & 63;
  int lg = l >> 4, ll = l & 15;

  // ---- B fragments in registers (once per block) ----
  bfrag breg[4][4];
#pragma unroll
  for (int kt = 0; kt < 4; ++kt)
#pragma unroll
    for (int fn = 0; fn < 4; ++fn)
      breg[kt][fn] = *(const bfrag*)(W1t + kt * 8192 + (wv * 64 + fn * 16 + ll) * 32 + lg * 8);

  float bj[4], wj[4];
#pragma unroll
  for (int fn = 0; fn < 4; ++fn) {
    int j = wv * 64 + fn * 16 + ll;
    bj[fn] = b1[j];
    wj[fn] = W2[j];
  }
  float bb2 = b2[0];

  // ---- stage-role constants (per thread) ----
  int se = t >> 2;                // edge slot in tile
  int part = (t >> 1) & 1;        // 0: src node (k 0..63), 1: dst node (k 64..127)
  int half = t & 1;               // 64B half of the 128B row-part
  int swz = (se & 7) << 4;
  int bo0 = part * 128 + half * 64;
  const int* eidx = part ? (ei + E) : ei;

  int tile = blockIdx.x;
  if (tile >= ntiles) return;
  uint4 sreg[4];
  {
    int eg = min(tile * 64 + se, E - 1);
    const uint4* g = (const uint4*)(rzb + (size_t)eidx[eg] * 64 + half * 32);
#pragma unroll
    for (int c = 0; c < 4; ++c) sreg[c] = g[c];
  }
#pragma unroll
  for (int c = 0; c < 4; ++c)
    *(uint4*)&Als[0][se * 128 + (((bo0 + c * 16) ^ swz) >> 1)] = sreg[c];
  __syncthreads();

  int p = 0;
  for (; tile < ntiles; tile += gridDim.x) {
    int ntile = tile + gridDim.x;
    bool hn = ntile < ntiles;
    // issue next tile's gather EARLY (hides under MFMA + epilogue)
    if (hn) {
      int eg = min(ntile * 64 + se, E - 1);
      const uint4* g = (const uint4*)(rzb + (size_t)eidx[eg] * 64 + half * 32);
#pragma unroll
      for (int c = 0; c < 4; ++c) sreg[c] = g[c];
    }

    f32x4 acc[4][4];
#pragma unroll
    for (int a = 0; a < 4; ++a)
#pragma unroll
      for (int b = 0; b < 4; ++b) acc[a][b] = (f32x4){0.f, 0.f, 0.f, 0.f};

#pragma unroll
    for (int kt = 0; kt < 4; ++kt) {
      bfrag af[4];
#pragma unroll
      for (int fm = 0; fm < 4; ++fm) {
        int e = fm * 16 + ll;
        int bo = kt * 64 + lg * 16;
        af[fm] = *(const bfrag*)&Als[p][e * 128 + ((bo ^ ((e & 7) << 4)) >> 1)];
      }
#pragma unroll
      for (int fn = 0; fn < 4; ++fn)
#pragma unroll
        for (int fm = 0; fm < 4; ++fm)
          acc[fm][fn] = __builtin_amdgcn_mfma_f32_16x16x32_bf16(af[fm], breg[kt][fn], acc[fm][fn], 0, 0, 0);
    }

    // ---- epilogue: relu + W2 dot, 16-lane reduce, cross-wave via LDS ----
#pragma unroll
    for (int fm = 0; fm < 4; ++fm) {
      float pr[4] = {0.f, 0.f, 0.f, 0.f};
#pragma unroll
      for (int fn = 0; fn < 4; ++fn) {
#pragma unroll
        for (int r = 0; r < 4; ++r)
          pr[r] = fmaf(fmaxf(acc[fm][fn][r] + bj[fn], 0.f), wj[fn], pr[r]);
      }
#pragma unroll
      for (int m = 8; m >= 1; m >>= 1) {
#pragma unroll
        for (int r = 0; r < 4; ++r) pr[r] += __shfl_xor(pr[r], m);
      }
      if (ll == 0) {
#pragma unroll
        for (int r = 0; r < 4; ++r) red[wv][fm * 16 + lg * 4 + r] = pr[r];
      }
    }
    __syncthreads();   // A: red ready; Als[p] reads complete
    if (t < 64) {
      int eg = tile * 64 + t;
      if (eg < E) recon[eg] = red[0][t] + red[1][t] + red[2][t] + red[3][t] + bb2;
    }
    if (hn) {
#pragma unroll
      for (int c = 0; c < 4; ++c)
        *(uint4*)&Als[p ^ 1][se * 128 + (((bo0 + c * 16) ^ swz) >> 1)] = sreg[c];
    }
    __syncthreads();   // B: Als[p^1] staged; red safe to overwrite
    p ^= 1;
  }
}

extern "C" void kernel_launch(void* const* d_in, const int* in_sizes, int n_in,
                              void* d_out, int out_size, void* d_ws, size_t ws_size,
                              hipStream_t stream) {
  const float* x = (const float*)d_in[0];
  const int* ei = (const int*)d_in[1];
  const float* gat_W = (const float*)d_in[2];
  const float* att_src = (const float*)d_in[3];
  const float* att_dst = (const float*)d_in[4];
  const float* gat_bias = (const float*)d_in[5];
  const float* bn1_g = (const float*)d_in[6];
  const float* bn1_b = (const float*)d_in[7];
  const float* gcn_W = (const float*)d_in[8];
  const float* gcn_bias = (const float*)d_in[9];
  const float* bn2_g = (const float*)d_in[10];
  const float* bn2_b = (const float*)d_in[11];
  const float* mu_W = (const float*)d_in[12];
  const float* mu_b = (const float*)d_in[13];
  const float* lv_W = (const float*)d_in[14];
  const float* lv_b = (const float*)d_in[15];
  const float* res_W = (const float*)d_in[16];
  const float* res_b = (const float*)d_in[17];
  const float* dec_W1 = (const float*)d_in[18];
  const float* dec_b1 = (const float*)d_in[19];
  const float* dec_W2 = (const float*)d_in[20];
  const float* dec_b2 = (const float*)d_in[21];
  const float* eps = (const float*)d_in[22];

  int N = in_sizes[0] / DIN;   // 50000
  int E = in_sizes[1] / 2;     // 800000
  int Et = E + N;
  int NB = (N + 255) / 256;    // scan chunks (<= 256)

  float* ws = (float*)d_ws;
  size_t off = 0;
  float* xp = ws; off += (size_t)N * 256;
  unsigned short* xpb = (unsigned short*)xp;   // bf16 rows in place, stride 512 ushorts
  float* xp2 = xp;
  float* g2 = xp + (size_t)N * 64;
  float* zb = xp + (size_t)N * 128;
  float* rz = xp + (size_t)N * 192;
  unsigned short* rzb = (unsigned short*)zb;
  float* h1 = ws + off; off += (size_t)N * 128;
  float* a_src = ws + off; off += (size_t)2 * N;
  float* a_dst = ws + off; off += (size_t)2 * N;
  float* alpha = ws + off; off += (size_t)Et * 2;
  float* dinv = ws + off; off += N;
  float* P = ws + off; off += 128 * 128;
  float* PS = ws + off; off += 128 * 128;
  float* svec = ws + off; off += 128;
  float* tvec = ws + off; off += 128;
  float* W2f = ws + off; off += 128 * 64;
  float* c2 = ws + off; off += 64;
  float* Wmuf = ws + off; off += 64 * 64;
  float* cmu = ws + off; off += 64;
  float* Wlvf = ws + off; off += 64 * 64;
  float* clv = ws + off; off += 64;
  unsigned short* W1t = (unsigned short*)(ws + off); off += 16384;  // 4*256*32 bf16
  int* deg = (int*)(ws + off); off += N;
  int* offs = (int*)(ws + off); off += N;
  int* cursor = (int*)(ws + off); off += N;
  int* bsum = (int*)(ws + off); off += 256;
  int* csr = (int*)(ws + off); off += Et;

  float* recon = (float*)d_out;
  float* mu = recon + E;
  float* lv = mu + (size_t)N * LAT;

  // 0. prep W1 (independent, do early)
  prep_W1<<<(4 * 256 * 32 + 255) / 256, 256, 0, stream>>>(dec_W1, W1t);

  // 1. xp = x @ gat_W
  dim3 gA((N + 63) / 64, DIN / 64);
  gemm64<<<gA, 256, 0, stream>>>(x, gat_W, nullptr, xp, N, DIN, DIN);

  // 2. attention scores (last f32-xp consumer)
  attn_scores<<<(N + 3) / 4, 256, 0, stream>>>(xp, att_src, att_dst, a_src, a_dst, N);

  // 2b. convert xp rows to bf16 in place (halves the gather bytes)
  cvt_rows_inplace<<<(N + 3) / 4, 256, 0, stream>>>(xp, N);

  // 3. CSR build (parallel 3-phase scan)
  hipMemsetAsync(deg, 0, (size_t)N * sizeof(int), stream);
  deg_count<<<(Et + 255) / 256, 256, 0, stream>>>(ei, E, Et, deg);
  bsum_kernel<<<NB, 256, 0, stream>>>(deg, N, bsum);
  bscan_kernel<<<1, 256, 0, stream>>>(bsum, NB);
  scan_apply<<<NB, 256, 0, stream>>>(deg, bsum, N, offs, cursor, dinv);
  csr_fill<<<(Et + 255) / 256, 256, 0, stream>>>(ei, E, Et, cursor, csr);

  // 4. GAT softmax + aggregation (bf16 gather)
  gat_softmax<<<(N + 3) / 4, 256, 0, stream>>>(offs, deg, csr, a_src, a_dst, alpha, N);
  gat_aggregate_bf<<<(N + 3) / 4, 256, 0, stream>>>(offs, deg, csr, alpha, xpb, gat_bias, h1, N);

  // 5. BN1 folded into GCN weights
  bn_stats<128><<<128, 256, 0, stream>>>(h1, N, P, PS);
  bn_reduce<128><<<1, 128, 0, stream>>>(P, PS, 128, N, bn1_g, bn1_b, svec, tvec);
  fold_gcn<<<1, 256, 0, stream>>>(gcn_W, svec, tvec, W2f, c2);
  dim3 gB((N + 63) / 64, 1);
  gemm64<<<gB, 256, 0, stream>>>(h1, W2f, c2, xp2, N, 64, 128);

  // 6. GCN aggregation
  gcn_aggregate<<<(N + 3) / 4, 256, 0, stream>>>(offs, deg, csr, xp2, dinv, gcn_bias, g2, N);

  // 7. BN2 folded into mu/lv
  bn_stats<64><<<128, 256, 0, stream>>>(g2, N, P, PS);
  bn_reduce<64><<<1, 64, 0, stream>>>(P, PS, 128, N, bn2_g, bn2_b, svec, tvec);
  fold_mulv<<<1, 256, 0, stream>>>(mu_W, mu_b, lv_W, lv_b, svec, tvec, Wmuf, cmu, Wlvf, clv);
  gemm64<<<gB, 256, 0, stream>>>(g2, Wmuf, cmu, mu, N, 64, 64);
  gemm64<<<gB, 256, 0, stream>>>(g2, Wlvf, clv, lv, N, 64, 64);

  // 8. z, res_z, res_z → bf16
  reparam<<<(N * 64 + 255) / 256, 256, 0, stream>>>(mu, lv, eps, zb, N * 64);
  gemm64<<<gB, 256, 0, stream>>>(zb, res_W, res_b, rz, N, 64, 64);
  cvt_bf16<<<(N * 16 + 255) / 256, 256, 0, stream>>>(rz, rzb, N * 16);

  // 9. MFMA decoder (persistent, pipelined)
  int ntiles = (E + 63) / 64;
  int dgrid = ntiles < 1024 ? ntiles : 1024;
  decoder_mfma<<<dgrid, 256, 0, stream>>>(ei, E, ntiles, rzb, W1t, dec_b1, dec_W2, dec_b2, recon);
}

// Round 7
// 684.102 us; speedup vs baseline: 1.0989x; 1.0944x over previous
//
#include <hip/hip_runtime.h>
#include <math.h>

constexpr int DIN = 256;
constexpr int HID = 128;
constexpr int LAT = 64;

typedef short bfrag __attribute__((ext_vector_type(8)));   // 8 bf16 (4 VGPRs)
typedef float f32x4 __attribute__((ext_vector_type(4)));

__device__ __forceinline__ float4 ld4(const float* p) { return *reinterpret_cast<const float4*>(p); }
__device__ __forceinline__ void st4(float* p, float4 v) { *reinterpret_cast<float4*>(p) = v; }

__device__ __forceinline__ unsigned short f2bf(float f) {
  unsigned int u = __float_as_uint(f);
  unsigned int r = (u + 0x7FFFu + ((u >> 16) & 1u)) >> 16;  // RNE
  return (unsigned short)r;
}

__device__ __forceinline__ float bf2f(unsigned short u) {
  return __uint_as_float(((unsigned int)u) << 16);
}

// ---------------- generic f32 GEMM: C[M,N] = A[M,K] @ B[K,N] (+ crow[N]) ----------------
__global__ __launch_bounds__(256) void gemm64(const float* __restrict__ A, const float* __restrict__ B,
                                              const float* __restrict__ crow, float* __restrict__ C,
                                              int M, int N, int K) {
  __shared__ float As[32][68];
  __shared__ float Bs[32][68];
  int t = threadIdx.x;
  int m0 = blockIdx.x * 64, n0 = blockIdx.y * 64;
  int tm = t & 15, tn = t >> 4;
  float acc[4][4];
#pragma unroll
  for (int i = 0; i < 4; i++)
#pragma unroll
    for (int j = 0; j < 4; j++) acc[i][j] = 0.f;

  for (int kt = 0; kt < K; kt += 32) {
#pragma unroll
    for (int i = 0; i < 2; ++i) {
      int f4 = t + i * 256;
      int m = f4 >> 3;
      int k4 = (f4 & 7) << 2;
      int gm = m0 + m;
      float4 v = make_float4(0.f, 0.f, 0.f, 0.f);
      if (gm < M) v = ld4(A + (size_t)gm * K + kt + k4);
      As[k4 + 0][m] = v.x; As[k4 + 1][m] = v.y; As[k4 + 2][m] = v.z; As[k4 + 3][m] = v.w;
    }
#pragma unroll
    for (int i = 0; i < 2; ++i) {
      int f4 = t + i * 256;
      int k = f4 >> 4;
      int n4 = (f4 & 15) << 2;
      float4 v = ld4(B + (size_t)(kt + k) * N + n0 + n4);
      st4(&Bs[k][n4], v);
    }
    __syncthreads();
#pragma unroll
    for (int k = 0; k < 32; ++k) {
      float4 a = ld4(&As[k][tm << 2]);
      float4 b = ld4(&Bs[k][tn << 2]);
      float av[4] = {a.x, a.y, a.z, a.w};
      float bv[4] = {b.x, b.y, b.z, b.w};
#pragma unroll
      for (int i = 0; i < 4; i++)
#pragma unroll
        for (int j = 0; j < 4; j++) acc[i][j] = fmaf(av[i], bv[j], acc[i][j]);
    }
    __syncthreads();
  }
#pragma unroll
  for (int i = 0; i < 4; ++i) {
    int gm = m0 + (tm << 2) + i;
    if (gm < M) {
      int nb = n0 + (tn << 2);
      float4 v = make_float4(acc[i][0], acc[i][1], acc[i][2], acc[i][3]);
      if (crow) { v.x += crow[nb]; v.y += crow[nb + 1]; v.z += crow[nb + 2]; v.w += crow[nb + 3]; }
      st4(C + (size_t)gm * N + nb, v);
    }
  }
}

// ---------------- MFMA GEMM: xpb[M,256](bf16, stride 512) = xb[M,256](bf16) @ Wtb^T ----------------
// Wtb is [256 cols][256 k] bf16 (pre-transposed). grid = (4 colgroups FAST, 782 row tiles)
// so the 4 blocks sharing an A-tile run adjacently -> L2 hits. Tile 64x64, 4 waves, K=256.
__global__ __launch_bounds__(256) void gemm_xp_mfma(const unsigned short* __restrict__ xb,
                                                    const unsigned short* __restrict__ Wtb,
                                                    unsigned short* __restrict__ xpb, int M) {
  __shared__ unsigned short Als[64 * 256];  // 32 KB, rows swizzled
  __shared__ unsigned short Bls[64 * 256];  // 32 KB, cols swizzled
  int t = threadIdx.x;
  int wv = t >> 6, l = t & 63, lg = l >> 4, ll = l & 15;
  int cg = blockIdx.x;            // col group (fast dim)
  int rt = blockIdx.y;            // row tile

  // stage A: thread t -> row t>>2, 128B segment t&3
  {
    int row = t >> 2, seg = t & 3;
    int gr = min(rt * 64 + row, M - 1);
    const uint4* src = (const uint4*)(xb + (size_t)gr * 256 + seg * 64);
    int swz = (row & 7) << 4;
#pragma unroll
    for (int c = 0; c < 8; ++c) {
      int bo = seg * 128 + c * 16;
      *(uint4*)((char*)Als + row * 512 + (bo ^ swz)) = src[c];
    }
  }
  // stage B: col slice [cg*64, cg*64+64)
  {
    int col = t >> 2, seg = t & 3;
    const uint4* src = (const uint4*)(Wtb + (size_t)(cg * 64 + col) * 256 + seg * 64);
    int swz = (col & 7) << 4;
#pragma unroll
    for (int c = 0; c < 8; ++c) {
      int bo = seg * 128 + c * 16;
      *(uint4*)((char*)Bls + col * 512 + (bo ^ swz)) = src[c];
    }
  }
  __syncthreads();

  f32x4 acc[4];
#pragma unroll
  for (int i = 0; i < 4; ++i) acc[i] = (f32x4){0.f, 0.f, 0.f, 0.f};

#pragma unroll
  for (int kt = 0; kt < 8; ++kt) {
    int ar = wv * 16 + ll;
    bfrag af = *(const bfrag*)((char*)Als + ar * 512 + ((kt * 64 + lg * 16) ^ ((ar & 7) << 4)));
#pragma unroll
    for (int fn = 0; fn < 4; ++fn) {
      int bc = fn * 16 + ll;
      bfrag bf = *(const bfrag*)((char*)Bls + bc * 512 + ((kt * 64 + lg * 16) ^ ((bc & 7) << 4)));
      acc[fn] = __builtin_amdgcn_mfma_f32_16x16x32_bf16(af, bf, acc[fn], 0, 0, 0);
    }
  }

  // write bf16: row = rt*64 + wv*16 + lg*4 + r, col = cg*64 + fn*16 + ll
#pragma unroll
  for (int fn = 0; fn < 4; ++fn) {
#pragma unroll
    for (int r = 0; r < 4; ++r) {
      int row = rt * 64 + wv * 16 + lg * 4 + r;
      if (row < M) xpb[(size_t)row * 512 + cg * 64 + fn * 16 + ll] = f2bf(acc[fn][r]);
    }
  }
}

// ---------------- attention scores (bf16 xp) ----------------
__global__ __launch_bounds__(256) void attn_scores_bf(const unsigned short* __restrict__ xpb,
                                                      const float* __restrict__ att_src,
                                                      const float* __restrict__ att_dst,
                                                      float* __restrict__ a_src, float* __restrict__ a_dst, int N) {
  int wid = threadIdx.x >> 6, lane = threadIdx.x & 63;
  int n = blockIdx.x * 4 + wid;
  if (n >= N) return;
  int h = lane >> 5;
  int f4 = (lane & 31) << 2;
  ushort4 u = *(const ushort4*)(xpb + (size_t)n * 512 + lane * 4);
  float4 as = ld4(att_src + h * 128 + f4);
  float4 ad = ld4(att_dst + h * 128 + f4);
  float vx = bf2f(u.x), vy = bf2f(u.y), vz = bf2f(u.z), vw = bf2f(u.w);
  float ps = vx * as.x + vy * as.y + vz * as.z + vw * as.w;
  float pd = vx * ad.x + vy * ad.y + vz * ad.z + vw * ad.w;
#pragma unroll
  for (int m = 16; m >= 1; m >>= 1) { ps += __shfl_xor(ps, m); pd += __shfl_xor(pd, m); }
  if ((lane & 31) == 0) { a_src[n * 2 + h] = ps; a_dst[n * 2 + h] = pd; }
}

// ---------------- CSR build ----------------
__global__ void deg_count(const int* __restrict__ ei, int E, int Et, int* __restrict__ deg) {
  int i = blockIdx.x * blockDim.x + threadIdx.x;
  if (i >= Et) return;
  int d = (i < E) ? ei[E + i] : (i - E);
  atomicAdd(&deg[d], 1);
}

__global__ __launch_bounds__(256) void bsum_kernel(const int* __restrict__ deg, int N, int* __restrict__ bsum) {
  int t = threadIdx.x;
  int i = blockIdx.x * 256 + t;
  int v = (i < N) ? deg[i] : 0;
#pragma unroll
  for (int m = 32; m >= 1; m >>= 1) v += __shfl_xor(v, m);
  __shared__ int sh[4];
  if ((t & 63) == 0) sh[t >> 6] = v;
  __syncthreads();
  if (t == 0) bsum[blockIdx.x] = sh[0] + sh[1] + sh[2] + sh[3];
}

__global__ __launch_bounds__(256) void bscan_kernel(int* __restrict__ bsum, int B) {
  __shared__ int sh[256];
  int t = threadIdx.x;
  int v = (t < B) ? bsum[t] : 0;
  sh[t] = v;
  __syncthreads();
  for (int d = 1; d < 256; d <<= 1) {
    int x = (t >= d) ? sh[t - d] : 0;
    __syncthreads();
    sh[t] += x;
    __syncthreads();
  }
  if (t < B) bsum[t] = sh[t] - v;
}

__global__ __launch_bounds__(256) void scan_apply(const int* __restrict__ deg, const int* __restrict__ bsum, int N,
                                                  int* __restrict__ offs, int* __restrict__ cursor,
                                                  float* __restrict__ dinv) {
  int t = threadIdx.x;
  int i = blockIdx.x * 256 + t;
  int v = (i < N) ? deg[i] : 0;
  __shared__ int sh[256];
  sh[t] = v;
  __syncthreads();
  for (int d = 1; d < 256; d <<= 1) {
    int x = (t >= d) ? sh[t - d] : 0;
    __syncthreads();
    sh[t] += x;
    __syncthreads();
  }
  if (i < N) {
    int off = bsum[blockIdx.x] + sh[t] - v;
    offs[i] = off;
    cursor[i] = off;
    dinv[i] = rsqrtf((float)v);   // deg >= 1 (self-loop)
  }
}

__global__ void csr_fill(const int* __restrict__ ei, int E, int Et, int* __restrict__ cursor, int* __restrict__ csr) {
  int i = blockIdx.x * blockDim.x + threadIdx.x;
  if (i >= Et) return;
  int s, d;
  if (i < E) { s = ei[i]; d = ei[E + i]; } else { s = i - E; d = i - E; }
  int pos = atomicAdd(&cursor[d], 1);
  csr[pos] = s;
}

// ---------------- GAT softmax per dst node (wave per node) ----------------
__global__ __launch_bounds__(256) void gat_softmax(const int* __restrict__ offs, const int* __restrict__ deg,
                                                   const int* __restrict__ csr, const float* __restrict__ a_src,
                                                   const float* __restrict__ a_dst, float* __restrict__ alpha, int N) {
  int wid = threadIdx.x >> 6, lane = threadIdx.x & 63;
  int n = blockIdx.x * 4 + wid;
  if (n >= N) return;
  int off = offs[n], dg = deg[n];
  float ad0 = a_dst[n * 2], ad1 = a_dst[n * 2 + 1];
  float m0 = -1e30f, m1 = -1e30f;
  for (int k = lane; k < dg; k += 64) {
    int s = csr[off + k];
    float e0 = a_src[s * 2] + ad0; e0 = e0 >= 0.f ? e0 : 0.2f * e0;
    float e1 = a_src[s * 2 + 1] + ad1; e1 = e1 >= 0.f ? e1 : 0.2f * e1;
    m0 = fmaxf(m0, e0); m1 = fmaxf(m1, e1);
  }
#pragma unroll
  for (int m = 32; m >= 1; m >>= 1) { m0 = fmaxf(m0, __shfl_xor(m0, m)); m1 = fmaxf(m1, __shfl_xor(m1, m)); }
  float s0 = 0.f, s1 = 0.f;
  float2* al2 = (float2*)alpha;
  for (int k = lane; k < dg; k += 64) {
    int s = csr[off + k];
    float e0 = a_src[s * 2] + ad0; e0 = e0 >= 0.f ? e0 : 0.2f * e0;
    float e1 = a_src[s * 2 + 1] + ad1; e1 = e1 >= 0.f ? e1 : 0.2f * e1;
    float x0 = __expf(e0 - m0), x1 = __expf(e1 - m1);
    al2[off + k] = make_float2(x0, x1);
    s0 += x0; s1 += x1;
  }
#pragma unroll
  for (int m = 32; m >= 1; m >>= 1) { s0 += __shfl_xor(s0, m); s1 += __shfl_xor(s1, m); }
  float r0 = 1.f / s0, r1 = 1.f / s1;
  for (int k = lane; k < dg; k += 64) {
    float2 v = al2[off + k];
    al2[off + k] = make_float2(v.x * r0, v.y * r1);
  }
}

// ---------------- GAT aggregation, bf16 gather (wave per node) ----------------
__global__ __launch_bounds__(256) void gat_aggregate_bf(const int* __restrict__ offs, const int* __restrict__ deg,
                                                        const int* __restrict__ csr, const float* __restrict__ alpha,
                                                        const unsigned short* __restrict__ xpb,
                                                        const float* __restrict__ bias,
                                                        float* __restrict__ h1, int N) {
  int wid = threadIdx.x >> 6, lane = threadIdx.x & 63;
  int n = blockIdx.x * 4 + wid;
  if (n >= N) return;
  int off = offs[n], dg = deg[n];
  float4 acc = make_float4(0.f, 0.f, 0.f, 0.f);
  int f4 = lane << 2;
  bool h0 = lane < 32;
  const float2* al2 = (const float2*)alpha;
  for (int k = 0; k < dg; ++k) {
    int s = csr[off + k];
    float2 al = al2[off + k];
    float a = h0 ? al.x : al.y;
    ushort4 u = ((const ushort4*)(xpb + (size_t)s * 512))[lane];
    acc.x = fmaf(bf2f(u.x), a, acc.x);
    acc.y = fmaf(bf2f(u.y), a, acc.y);
    acc.z = fmaf(bf2f(u.z), a, acc.z);
    acc.w = fmaf(bf2f(u.w), a, acc.w);
  }
  float ox = __shfl_down(acc.x, 32);
  float oy = __shfl_down(acc.y, 32);
  float oz = __shfl_down(acc.z, 32);
  float ow = __shfl_down(acc.w, 32);
  if (h0) {
    float4 b = ld4(bias + f4);
    float4 o;
    o.x = fmaxf(0.f, (acc.x + ox) * 0.5f + b.x);
    o.y = fmaxf(0.f, (acc.y + oy) * 0.5f + b.y);
    o.z = fmaxf(0.f, (acc.z + oz) * 0.5f + b.z);
    o.w = fmaxf(0.f, (acc.w + ow) * 0.5f + b.w);
    st4(h1 + (size_t)n * 128 + f4, o);
  }
}

// ---------------- BatchNorm stats ----------------
template <int C>
__global__ __launch_bounds__(256) void bn_stats(const float* __restrict__ h, int N, float* __restrict__ P,
                                                float* __restrict__ PS) {
  constexpr int R = 256 / C;
  __shared__ float sh[256], sh2[256];
  int t = threadIdx.x;
  int c = t % C, r = t / C;
  float s = 0.f, ss = 0.f;
  for (int n = blockIdx.x * R + r; n < N; n += gridDim.x * R) {
    float v = h[(size_t)n * C + c];
    s += v; ss += v * v;
  }
  sh[t] = s; sh2[t] = ss;
  __syncthreads();
  if (r == 0) {
#pragma unroll
    for (int i = 1; i < R; ++i) { s += sh[i * C + c]; ss += sh2[i * C + c]; }
    P[blockIdx.x * C + c] = s;
    PS[blockIdx.x * C + c] = ss;
  }
}

template <int C>
__global__ void bn_reduce(const float* __restrict__ P, const float* __restrict__ PS, int G, int N,
                          const float* __restrict__ g, const float* __restrict__ b,
                          float* __restrict__ svec, float* __restrict__ tvec) {
  int c = threadIdx.x;
  if (c >= C) return;
  float s = 0.f, ss = 0.f;
  for (int i = 0; i < G; ++i) { s += P[i * C + c]; ss += PS[i * C + c]; }
  float mean = s / N;
  float var = ss / N - mean * mean;
  float sc = g[c] * rsqrtf(var + 1e-5f);
  svec[c] = sc;
  tvec[c] = b[c] - mean * sc;
}

__global__ __launch_bounds__(256) void fold_gcn(const float* __restrict__ W, const float* __restrict__ svec,
                                                const float* __restrict__ tvec, float* __restrict__ Wf,
                                                float* __restrict__ cvec) {
  int t = threadIdx.x;
  for (int i = t; i < 128 * 64; i += 256) {
    int k = i >> 6;
    Wf[i] = svec[k] * W[i];
  }
  if (t < 64) {
    float c = 0.f;
    for (int k = 0; k < 128; ++k) c += tvec[k] * W[k * 64 + t];
    cvec[t] = c;
  }
}

__global__ __launch_bounds__(256) void fold_mulv(const float* __restrict__ Wmu, const float* __restrict__ mub,
                                                 const float* __restrict__ Wlv, const float* __restrict__ lvb,
                                                 const float* __restrict__ svec, const float* __restrict__ tvec,
                                                 float* __restrict__ Wmuf, float* __restrict__ cmu,
                                                 float* __restrict__ Wlvf, float* __restrict__ clv) {
  int t = threadIdx.x;
  for (int i = t; i < 4096; i += 256) {
    int k = i >> 6;
    Wmuf[i] = svec[k] * Wmu[i];
    Wlvf[i] = svec[k] * Wlv[i];
  }
  if (t < 64) {
    float cm = mub[t], cl = lvb[t];
    for (int k = 0; k < 64; ++k) { cm += tvec[k] * Wmu[k * 64 + t]; cl += tvec[k] * Wlv[k * 64 + t]; }
    cmu[t] = cm; clv[t] = cl;
  }
}

// ---------------- GCN aggregation ----------------
__global__ __launch_bounds__(256) void gcn_aggregate(const int* __restrict__ offs, const int* __restrict__ deg,
                                                     const int* __restrict__ csr, const float* __restrict__ xp2,
                                                     const float* __restrict__ dinv, const float* __restrict__ bias,
                                                     float* __restrict__ g2, int N) {
  int wid = threadIdx.x >> 6, lane = threadIdx.x & 63;
  int n = blockIdx.x * 4 + wid;
  if (n >= N) return;
  int off = offs[n], dg = deg[n];
  float acc = 0.f;
  for (int k = 0; k < dg; ++k) {
    int s = csr[off + k];
    acc = fmaf(xp2[(size_t)s * 64 + lane], dinv[s], acc);
  }
  float v = acc * dinv[n] + bias[lane];
  g2[(size_t)n * 64 + lane] = fmaxf(v, 0.f);
}

// ---------------- reparameterize ----------------
__global__ void reparam(const float* __restrict__ mu, const float* __restrict__ lv,
                        const float* __restrict__ eps, float* __restrict__ z, int total) {
  int i = blockIdx.x * blockDim.x + threadIdx.x;
  if (i >= total) return;
  z[i] = fmaf(eps[i], __expf(0.5f * lv[i]), mu[i]);
}

// ---------------- f32 -> bf16 packed convert ----------------
__global__ void cvt_bf16(const float* __restrict__ in, unsigned short* __restrict__ out, int n4) {
  int i = blockIdx.x * blockDim.x + threadIdx.x;
  if (i >= n4) return;
  float4 v = ((const float4*)in)[i];
  ushort4 o;
  o.x = f2bf(v.x); o.y = f2bf(v.y); o.z = f2bf(v.z); o.w = f2bf(v.w);
  ((ushort4*)out)[i] = o;
}

// ---------------- prep gat_W -> transposed bf16 Wtb[col][k] ----------------
__global__ void prep_gatW(const float* __restrict__ W, unsigned short* __restrict__ Wtb) {
  int i = blockIdx.x * blockDim.x + threadIdx.x;
  if (i >= 256 * 256) return;
  int col = i >> 8, k = i & 255;
  Wtb[i] = f2bf(W[k * 256 + col]);
}

// ---------------- prep W1 → bf16 decoder layout [4 kt][256 j][40 kp] (padded) ----------------
__global__ void prep_W1(const float* __restrict__ W1, unsigned short* __restrict__ W1t) {
  int i = blockIdx.x * blockDim.x + threadIdx.x;
  if (i >= 4 * 256 * 40) return;
  int kt = i / 10240;
  int rem = i - kt * 10240;
  int j = rem / 40;
  int kp = rem - j * 40;
  float v = (kp < 32) ? W1[(size_t)(kt * 32 + kp) * 256 + j] : 0.f;
  W1t[i] = f2bf(v);
}

// ---------------- MFMA decoder (round-4 variant: B staged per k-tile in LDS) ----------------
__global__ __launch_bounds__(256) void decoder_mfma(const int* __restrict__ ei, int E,
                                                    const unsigned short* __restrict__ rzb,
                                                    const unsigned short* __restrict__ W1t,
                                                    const float* __restrict__ b1, const float* __restrict__ W2,
                                                    const float* __restrict__ b2, float* __restrict__ recon) {
  __shared__ unsigned short Als[64 * 128];   // 16 KB
  __shared__ unsigned short Bls[256 * 40];   // 20 KB
  __shared__ float red[4][64];
  int t = threadIdx.x;
  int wv = t >> 6, l = t & 63;
  int lg = l >> 4, ll = l & 15;
  int e0 = blockIdx.x * 64;

  // ---- stage A: gather e_emb rows (bf16), swizzled ----
  {
    int e = t >> 2;
    int part = (t >> 1) & 1;
    int half = t & 1;
    int eg = e0 + e;
    if (eg >= E) eg = E - 1;
    int r = (part == 0) ? ei[eg] : ei[E + eg];
    const uint4* gsrc = (const uint4*)(rzb + (size_t)r * 64 + half * 32);
    int bo0 = part * 128 + half * 64;
    int swz = (e & 7) << 4;
#pragma unroll
    for (int c = 0; c < 4; ++c) {
      uint4 v = gsrc[c];
      int bo = bo0 + c * 16;
      *(uint4*)&Als[e * 128 + ((bo ^ swz) >> 1)] = v;
    }
  }

  f32x4 acc[4][4];
#pragma unroll
  for (int a = 0; a < 4; ++a)
#pragma unroll
    for (int b = 0; b < 4; ++b) acc[a][b] = (f32x4){0.f, 0.f, 0.f, 0.f};

  for (int kt = 0; kt < 4; ++kt) {
    __syncthreads();
    {
      const uint4* gsrc = (const uint4*)(W1t + kt * 10240);
      uint4* ldst = (uint4*)Bls;
#pragma unroll
      for (int i = 0; i < 5; ++i) ldst[t + i * 256] = gsrc[t + i * 256];
    }
    __syncthreads();

    bfrag af[4];
#pragma unroll
    for (int fm = 0; fm < 4; ++fm) {
      int e = fm * 16 + ll;
      int bo = kt * 64 + lg * 16;
      af[fm] = *(const bfrag*)&Als[e * 128 + ((bo ^ ((e & 7) << 4)) >> 1)];
    }
#pragma unroll
    for (int fn = 0; fn < 4; ++fn) {
      int j = wv * 64 + fn * 16 + ll;
      bfrag bf = *(const bfrag*)&Bls[j * 40 + lg * 8];
#pragma unroll
      for (int fm = 0; fm < 4; ++fm)
        acc[fm][fn] = __builtin_amdgcn_mfma_f32_16x16x32_bf16(af[fm], bf, acc[fm][fn], 0, 0, 0);
    }
  }

  float bj[4], wj[4];
#pragma unroll
  for (int fn = 0; fn < 4; ++fn) {
    int j = wv * 64 + fn * 16 + ll;
    bj[fn] = b1[j];
    wj[fn] = W2[j];
  }
#pragma unroll
  for (int fm = 0; fm < 4; ++fm) {
    float pr[4] = {0.f, 0.f, 0.f, 0.f};
#pragma unroll
    for (int fn = 0; fn < 4; ++fn) {
#pragma unroll
      for (int r = 0; r < 4; ++r)
        pr[r] = fmaf(fmaxf(acc[fm][fn][r] + bj[fn], 0.f), wj[fn], pr[r]);
    }
#pragma unroll
    for (int m = 8; m >= 1; m >>= 1) {
#pragma unroll
      for (int r = 0; r < 4; ++r) pr[r] += __shfl_xor(pr[r], m);
    }
    if (ll == 0) {
#pragma unroll
      for (int r = 0; r < 4; ++r) red[wv][fm * 16 + lg * 4 + r] = pr[r];
    }
  }
  __syncthreads();
  if (t < 64) {
    int eg = e0 + t;
    if (eg < E) recon[eg] = red[0][t] + red[1][t] + red[2][t] + red[3][t] + b2[0];
  }
}

extern "C" void kernel_launch(void* const* d_in, const int* in_sizes, int n_in,
                              void* d_out, int out_size, void* d_ws, size_t ws_size,
                              hipStream_t stream) {
  const float* x = (const float*)d_in[0];
  const int* ei = (const int*)d_in[1];
  const float* gat_W = (const float*)d_in[2];
  const float* att_src = (const float*)d_in[3];
  const float* att_dst = (const float*)d_in[4];
  const float* gat_bias = (const float*)d_in[5];
  const float* bn1_g = (const float*)d_in[6];
  const float* bn1_b = (const float*)d_in[7];
  const float* gcn_W = (const float*)d_in[8];
  const float* gcn_bias = (const float*)d_in[9];
  const float* bn2_g = (const float*)d_in[10];
  const float* bn2_b = (const float*)d_in[11];
  const float* mu_W = (const float*)d_in[12];
  const float* mu_b = (const float*)d_in[13];
  const float* lv_W = (const float*)d_in[14];
  const float* lv_b = (const float*)d_in[15];
  const float* res_W = (const float*)d_in[16];
  const float* res_b = (const float*)d_in[17];
  const float* dec_W1 = (const float*)d_in[18];
  const float* dec_b1 = (const float*)d_in[19];
  const float* dec_W2 = (const float*)d_in[20];
  const float* dec_b2 = (const float*)d_in[21];
  const float* eps = (const float*)d_in[22];

  int N = in_sizes[0] / DIN;   // 50000
  int E = in_sizes[1] / 2;     // 800000
  int Et = E + N;
  int NB = (N + 255) / 256;    // scan chunks (<= 256)

  float* ws = (float*)d_ws;
  size_t off = 0;
  float* xp = ws; off += (size_t)N * 256;
  unsigned short* xpb = (unsigned short*)xp;   // bf16 xp rows, stride 512 ushorts
  float* xp2 = xp;
  float* g2 = xp + (size_t)N * 64;
  float* zb = xp + (size_t)N * 128;
  float* rz = xp + (size_t)N * 192;
  unsigned short* rzb = (unsigned short*)zb;
  float* h1 = ws + off; off += (size_t)N * 128;
  unsigned short* xb = (unsigned short*)h1;    // bf16 x (dead once gat_aggregate writes h1)
  float* a_src = ws + off; off += (size_t)2 * N;
  float* a_dst = ws + off; off += (size_t)2 * N;
  float* alpha = ws + off; off += (size_t)Et * 2;
  float* dinv = ws + off; off += N;
  float* P = ws + off; off += 128 * 128;
  float* PS = ws + off; off += 128 * 128;
  float* svec = ws + off; off += 128;
  float* tvec = ws + off; off += 128;
  float* W2f = ws + off; off += 128 * 64;
  float* c2 = ws + off; off += 64;
  float* Wmuf = ws + off; off += 64 * 64;
  float* cmu = ws + off; off += 64;
  float* Wlvf = ws + off; off += 64 * 64;
  float* clv = ws + off; off += 64;
  unsigned short* W1t = (unsigned short*)(ws + off); off += 20480;   // 4*256*40 bf16
  unsigned short* Wtb = (unsigned short*)(ws + off); off += 32768;   // 256*256 bf16
  int* deg = (int*)(ws + off); off += N;
  int* offs = (int*)(ws + off); off += N;
  int* cursor = (int*)(ws + off); off += N;
  int* bsum = (int*)(ws + off); off += 256;
  int* csr = (int*)(ws + off); off += Et;

  float* recon = (float*)d_out;
  float* mu = recon + E;
  float* lv = mu + (size_t)N * LAT;

  // 0. weight preps (independent, do early)
  prep_W1<<<(4 * 256 * 40 + 255) / 256, 256, 0, stream>>>(dec_W1, W1t);
  prep_gatW<<<(256 * 256 + 255) / 256, 256, 0, stream>>>(gat_W, Wtb);

  // 1. x -> bf16, then xp = x @ gat_W via MFMA (writes bf16 xpb directly)
  cvt_bf16<<<(N * 64 + 255) / 256, 256, 0, stream>>>(x, xb, N * 64);
  dim3 gX(4, (N + 63) / 64);
  gemm_xp_mfma<<<gX, 256, 0, stream>>>(xb, Wtb, xpb, N);

  // 2. attention scores (bf16 xp)
  attn_scores_bf<<<(N + 3) / 4, 256, 0, stream>>>(xpb, att_src, att_dst, a_src, a_dst, N);

  // 3. CSR build (parallel 3-phase scan)
  hipMemsetAsync(deg, 0, (size_t)N * sizeof(int), stream);
  deg_count<<<(Et + 255) / 256, 256, 0, stream>>>(ei, E, Et, deg);
  bsum_kernel<<<NB, 256, 0, stream>>>(deg, N, bsum);
  bscan_kernel<<<1, 256, 0, stream>>>(bsum, NB);
  scan_apply<<<NB, 256, 0, stream>>>(deg, bsum, N, offs, cursor, dinv);
  csr_fill<<<(Et + 255) / 256, 256, 0, stream>>>(ei, E, Et, cursor, csr);

  // 4. GAT softmax + aggregation (bf16 gather)
  gat_softmax<<<(N + 3) / 4, 256, 0, stream>>>(offs, deg, csr, a_src, a_dst, alpha, N);
  gat_aggregate_bf<<<(N + 3) / 4, 256, 0, stream>>>(offs, deg, csr, alpha, xpb, gat_bias, h1, N);

  // 5. BN1 folded into GCN weights
  bn_stats<128><<<128, 256, 0, stream>>>(h1, N, P, PS);
  bn_reduce<128><<<1, 128, 0, stream>>>(P, PS, 128, N, bn1_g, bn1_b, svec, tvec);
  fold_gcn<<<1, 256, 0, stream>>>(gcn_W, svec, tvec, W2f, c2);
  dim3 gB((N + 63) / 64, 1);
  gemm64<<<gB, 256, 0, stream>>>(h1, W2f, c2, xp2, N, 64, 128);

  // 6. GCN aggregation
  gcn_aggregate<<<(N + 3) / 4, 256, 0, stream>>>(offs, deg, csr, xp2, dinv, gcn_bias, g2, N);

  // 7. BN2 folded into mu/lv
  bn_stats<64><<<128, 256, 0, stream>>>(g2, N, P, PS);
  bn_reduce<64><<<1, 64, 0, stream>>>(P, PS, 128, N, bn2_g, bn2_b, svec, tvec);
  fold_mulv<<<1, 256, 0, stream>>>(mu_W, mu_b, lv_W, lv_b, svec, tvec, Wmuf, cmu, Wlvf, clv);
  gemm64<<<gB, 256, 0, stream>>>(g2, Wmuf, cmu, mu, N, 64, 64);
  gemm64<<<gB, 256, 0, stream>>>(g2, Wlvf, clv, lv, N, 64, 64);

  // 8. z, res_z, res_z -> bf16
  reparam<<<(N * 64 + 255) / 256, 256, 0, stream>>>(mu, lv, eps, zb, N * 64);
  gemm64<<<gB, 256, 0, stream>>>(zb, res_W, res_b, rz, N, 64, 64);
  cvt_bf16<<<(N * 16 + 255) / 256, 256, 0, stream>>>(rz, rzb, N * 16);

  // 9. MFMA decoder (round-4 structure)
  decoder_mfma<<<(E + 63) / 64, 256, 0, stream>>>(ei, E, rzb, W1t, dec_b1, dec_W2, dec_b2, recon);
}

// Round 8
// 669.477 us; speedup vs baseline: 1.1229x; 1.0218x over previous
//
#include <hip/hip_runtime.h>
#include <math.h>

constexpr int DIN = 256;
constexpr int HID = 128;
constexpr int LAT = 64;

typedef short bfrag __attribute__((ext_vector_type(8)));   // 8 bf16 (4 VGPRs)
typedef float f32x4 __attribute__((ext_vector_type(4)));

__device__ __forceinline__ float4 ld4(const float* p) { return *reinterpret_cast<const float4*>(p); }
__device__ __forceinline__ void st4(float* p, float4 v) { *reinterpret_cast<float4*>(p) = v; }

__device__ __forceinline__ unsigned short f2bf(float f) {
  unsigned int u = __float_as_uint(f);
  unsigned int r = (u + 0x7FFFu + ((u >> 16) & 1u)) >> 16;  // RNE
  return (unsigned short)r;
}

__device__ __forceinline__ float bf2f(unsigned short u) {
  return __uint_as_float(((unsigned int)u) << 16);
}

// ---------------- generic f32 GEMM: C[M,N] = A[M,K] @ B[K,N] (+ crow[N]) ----------------
__global__ __launch_bounds__(256) void gemm64(const float* __restrict__ A, const float* __restrict__ B,
                                              const float* __restrict__ crow, float* __restrict__ C,
                                              int M, int N, int K) {
  __shared__ float As[32][68];
  __shared__ float Bs[32][68];
  int t = threadIdx.x;
  int m0 = blockIdx.x * 64, n0 = blockIdx.y * 64;
  int tm = t & 15, tn = t >> 4;
  float acc[4][4];
#pragma unroll
  for (int i = 0; i < 4; i++)
#pragma unroll
    for (int j = 0; j < 4; j++) acc[i][j] = 0.f;

  for (int kt = 0; kt < K; kt += 32) {
#pragma unroll
    for (int i = 0; i < 2; ++i) {
      int f4 = t + i * 256;
      int m = f4 >> 3;
      int k4 = (f4 & 7) << 2;
      int gm = m0 + m;
      float4 v = make_float4(0.f, 0.f, 0.f, 0.f);
      if (gm < M) v = ld4(A + (size_t)gm * K + kt + k4);
      As[k4 + 0][m] = v.x; As[k4 + 1][m] = v.y; As[k4 + 2][m] = v.z; As[k4 + 3][m] = v.w;
    }
#pragma unroll
    for (int i = 0; i < 2; ++i) {
      int f4 = t + i * 256;
      int k = f4 >> 4;
      int n4 = (f4 & 15) << 2;
      float4 v = ld4(B + (size_t)(kt + k) * N + n0 + n4);
      st4(&Bs[k][n4], v);
    }
    __syncthreads();
#pragma unroll
    for (int k = 0; k < 32; ++k) {
      float4 a = ld4(&As[k][tm << 2]);
      float4 b = ld4(&Bs[k][tn << 2]);
      float av[4] = {a.x, a.y, a.z, a.w};
      float bv[4] = {b.x, b.y, b.z, b.w};
#pragma unroll
      for (int i = 0; i < 4; i++)
#pragma unroll
        for (int j = 0; j < 4; j++) acc[i][j] = fmaf(av[i], bv[j], acc[i][j]);
    }
    __syncthreads();
  }
#pragma unroll
  for (int i = 0; i < 4; ++i) {
    int gm = m0 + (tm << 2) + i;
    if (gm < M) {
      int nb = n0 + (tn << 2);
      float4 v = make_float4(acc[i][0], acc[i][1], acc[i][2], acc[i][3]);
      if (crow) { v.x += crow[nb]; v.y += crow[nb + 1]; v.z += crow[nb + 2]; v.w += crow[nb + 3]; }
      st4(C + (size_t)gm * N + nb, v);
    }
  }
}

// ---------------- f32 GEMM with bf16 output: Cb[M,N](bf16) = A[M,K] @ B[K,N] + crow ----------------
__global__ __launch_bounds__(256) void gemm64b(const float* __restrict__ A, const float* __restrict__ B,
                                               const float* __restrict__ crow, unsigned short* __restrict__ Cb,
                                               int M, int N, int K) {
  __shared__ float As[32][68];
  __shared__ float Bs[32][68];
  int t = threadIdx.x;
  int m0 = blockIdx.x * 64, n0 = blockIdx.y * 64;
  int tm = t & 15, tn = t >> 4;
  float acc[4][4];
#pragma unroll
  for (int i = 0; i < 4; i++)
#pragma unroll
    for (int j = 0; j < 4; j++) acc[i][j] = 0.f;

  for (int kt = 0; kt < K; kt += 32) {
#pragma unroll
    for (int i = 0; i < 2; ++i) {
      int f4 = t + i * 256;
      int m = f4 >> 3;
      int k4 = (f4 & 7) << 2;
      int gm = m0 + m;
      float4 v = make_float4(0.f, 0.f, 0.f, 0.f);
      if (gm < M) v = ld4(A + (size_t)gm * K + kt + k4);
      As[k4 + 0][m] = v.x; As[k4 + 1][m] = v.y; As[k4 + 2][m] = v.z; As[k4 + 3][m] = v.w;
    }
#pragma unroll
    for (int i = 0; i < 2; ++i) {
      int f4 = t + i * 256;
      int k = f4 >> 4;
      int n4 = (f4 & 15) << 2;
      float4 v = ld4(B + (size_t)(kt + k) * N + n0 + n4);
      st4(&Bs[k][n4], v);
    }
    __syncthreads();
#pragma unroll
    for (int k = 0; k < 32; ++k) {
      float4 a = ld4(&As[k][tm << 2]);
      float4 b = ld4(&Bs[k][tn << 2]);
      float av[4] = {a.x, a.y, a.z, a.w};
      float bv[4] = {b.x, b.y, b.z, b.w};
#pragma unroll
      for (int i = 0; i < 4; i++)
#pragma unroll
        for (int j = 0; j < 4; j++) acc[i][j] = fmaf(av[i], bv[j], acc[i][j]);
    }
    __syncthreads();
  }
#pragma unroll
  for (int i = 0; i < 4; ++i) {
    int gm = m0 + (tm << 2) + i;
    if (gm < M) {
      int nb = n0 + (tn << 2);
      ushort4 o;
      o.x = f2bf(acc[i][0] + crow[nb]);
      o.y = f2bf(acc[i][1] + crow[nb + 1]);
      o.z = f2bf(acc[i][2] + crow[nb + 2]);
      o.w = f2bf(acc[i][3] + crow[nb + 3]);
      *(ushort4*)(Cb + (size_t)gm * N + nb) = o;
    }
  }
}

// ---------------- MFMA GEMM: xpb[M,256](bf16, stride 512) = xb[M,256](bf16) @ Wtb^T ----------------
__global__ __launch_bounds__(256) void gemm_xp_mfma(const unsigned short* __restrict__ xb,
                                                    const unsigned short* __restrict__ Wtb,
                                                    unsigned short* __restrict__ xpb, int M) {
  __shared__ unsigned short Als[64 * 256];  // 32 KB, rows swizzled
  __shared__ unsigned short Bls[64 * 256];  // 32 KB, cols swizzled
  int t = threadIdx.x;
  int wv = t >> 6, l = t & 63, lg = l >> 4, ll = l & 15;
  int cg = blockIdx.x;            // col group (fast dim)
  int rt = blockIdx.y;            // row tile

  {
    int row = t >> 2, seg = t & 3;
    int gr = min(rt * 64 + row, M - 1);
    const uint4* src = (const uint4*)(xb + (size_t)gr * 256 + seg * 64);
    int swz = (row & 7) << 4;
#pragma unroll
    for (int c = 0; c < 8; ++c) {
      int bo = seg * 128 + c * 16;
      *(uint4*)((char*)Als + row * 512 + (bo ^ swz)) = src[c];
    }
  }
  {
    int col = t >> 2, seg = t & 3;
    const uint4* src = (const uint4*)(Wtb + (size_t)(cg * 64 + col) * 256 + seg * 64);
    int swz = (col & 7) << 4;
#pragma unroll
    for (int c = 0; c < 8; ++c) {
      int bo = seg * 128 + c * 16;
      *(uint4*)((char*)Bls + col * 512 + (bo ^ swz)) = src[c];
    }
  }
  __syncthreads();

  f32x4 acc[4];
#pragma unroll
  for (int i = 0; i < 4; ++i) acc[i] = (f32x4){0.f, 0.f, 0.f, 0.f};

#pragma unroll
  for (int kt = 0; kt < 8; ++kt) {
    int ar = wv * 16 + ll;
    bfrag af = *(const bfrag*)((char*)Als + ar * 512 + ((kt * 64 + lg * 16) ^ ((ar & 7) << 4)));
#pragma unroll
    for (int fn = 0; fn < 4; ++fn) {
      int bc = fn * 16 + ll;
      bfrag bf = *(const bfrag*)((char*)Bls + bc * 512 + ((kt * 64 + lg * 16) ^ ((bc & 7) << 4)));
      acc[fn] = __builtin_amdgcn_mfma_f32_16x16x32_bf16(af, bf, acc[fn], 0, 0, 0);
    }
  }

#pragma unroll
  for (int fn = 0; fn < 4; ++fn) {
#pragma unroll
    for (int r = 0; r < 4; ++r) {
      int row = rt * 64 + wv * 16 + lg * 4 + r;
      if (row < M) xpb[(size_t)row * 512 + cg * 64 + fn * 16 + ll] = f2bf(acc[fn][r]);
    }
  }
}

// ---------------- attention scores (bf16 xp) ----------------
__global__ __launch_bounds__(256) void attn_scores_bf(const unsigned short* __restrict__ xpb,
                                                      const float* __restrict__ att_src,
                                                      const float* __restrict__ att_dst,
                                                      float* __restrict__ a_src, float* __restrict__ a_dst, int N) {
  int wid = threadIdx.x >> 6, lane = threadIdx.x & 63;
  int n = blockIdx.x * 4 + wid;
  if (n >= N) return;
  int h = lane >> 5;
  int f4 = (lane & 31) << 2;
  ushort4 u = *(const ushort4*)(xpb + (size_t)n * 512 + lane * 4);
  float4 as = ld4(att_src + h * 128 + f4);
  float4 ad = ld4(att_dst + h * 128 + f4);
  float vx = bf2f(u.x), vy = bf2f(u.y), vz = bf2f(u.z), vw = bf2f(u.w);
  float ps = vx * as.x + vy * as.y + vz * as.z + vw * as.w;
  float pd = vx * ad.x + vy * ad.y + vz * ad.z + vw * ad.w;
#pragma unroll
  for (int m = 16; m >= 1; m >>= 1) { ps += __shfl_xor(ps, m); pd += __shfl_xor(pd, m); }
  if ((lane & 31) == 0) { a_src[n * 2 + h] = ps; a_dst[n * 2 + h] = pd; }
}

// ---------------- CSR build ----------------
__global__ void deg_count(const int* __restrict__ ei, int E, int Et, int* __restrict__ deg) {
  int i = blockIdx.x * blockDim.x + threadIdx.x;
  if (i >= Et) return;
  int d = (i < E) ? ei[E + i] : (i - E);
  atomicAdd(&deg[d], 1);
}

__global__ __launch_bounds__(256) void bsum_kernel(const int* __restrict__ deg, int N, int* __restrict__ bsum) {
  int t = threadIdx.x;
  int i = blockIdx.x * 256 + t;
  int v = (i < N) ? deg[i] : 0;
#pragma unroll
  for (int m = 32; m >= 1; m >>= 1) v += __shfl_xor(v, m);
  __shared__ int sh[4];
  if ((t & 63) == 0) sh[t >> 6] = v;
  __syncthreads();
  if (t == 0) bsum[blockIdx.x] = sh[0] + sh[1] + sh[2] + sh[3];
}

__global__ __launch_bounds__(256) void bscan_kernel(int* __restrict__ bsum, int B) {
  __shared__ int sh[256];
  int t = threadIdx.x;
  int v = (t < B) ? bsum[t] : 0;
  sh[t] = v;
  __syncthreads();
  for (int d = 1; d < 256; d <<= 1) {
    int x = (t >= d) ? sh[t - d] : 0;
    __syncthreads();
    sh[t] += x;
    __syncthreads();
  }
  if (t < B) bsum[t] = sh[t] - v;
}

__global__ __launch_bounds__(256) void scan_apply(const int* __restrict__ deg, const int* __restrict__ bsum, int N,
                                                  int* __restrict__ offs, int* __restrict__ cursor,
                                                  float* __restrict__ dinv) {
  int t = threadIdx.x;
  int i = blockIdx.x * 256 + t;
  int v = (i < N) ? deg[i] : 0;
  __shared__ int sh[256];
  sh[t] = v;
  __syncthreads();
  for (int d = 1; d < 256; d <<= 1) {
    int x = (t >= d) ? sh[t - d] : 0;
    __syncthreads();
    sh[t] += x;
    __syncthreads();
  }
  if (i < N) {
    int off = bsum[blockIdx.x] + sh[t] - v;
    offs[i] = off;
    cursor[i] = off;
    dinv[i] = rsqrtf((float)v);   // deg >= 1 (self-loop)
  }
}

__global__ void csr_fill(const int* __restrict__ ei, int E, int Et, int* __restrict__ cursor, int* __restrict__ csr) {
  int i = blockIdx.x * blockDim.x + threadIdx.x;
  if (i >= Et) return;
  int s, d;
  if (i < E) { s = ei[i]; d = ei[E + i]; } else { s = i - E; d = i - E; }
  int pos = atomicAdd(&cursor[d], 1);
  csr[pos] = s;
}

// ---------------- FUSED GAT: softmax + aggregation in one kernel (wave per node) ----------------
// Pass 1 (lane-strided): running max per head. Pass 2 (edge-serial): accumulate
// unnormalized exp-weighted xp rows and the exp-sums; normalize at the end
// (softmax normalization is linear in the numerator).
__global__ __launch_bounds__(256) void gat_fused(const int* __restrict__ offs, const int* __restrict__ deg,
                                                 const int* __restrict__ csr, const float* __restrict__ a_src,
                                                 const float* __restrict__ a_dst,
                                                 const unsigned short* __restrict__ xpb,
                                                 const float* __restrict__ bias,
                                                 float* __restrict__ h1, int N) {
  int wid = threadIdx.x >> 6, lane = threadIdx.x & 63;
  int n = blockIdx.x * 4 + wid;
  if (n >= N) return;
  int off = offs[n], dg = deg[n];
  float ad0 = a_dst[n * 2], ad1 = a_dst[n * 2 + 1];
  const float2* as2 = (const float2*)a_src;

  // pass 1: max
  float m0 = -1e30f, m1 = -1e30f;
  for (int k = lane; k < dg; k += 64) {
    int s = csr[off + k];
    float2 a = as2[s];
    float e0 = a.x + ad0; e0 = e0 >= 0.f ? e0 : 0.2f * e0;
    float e1 = a.y + ad1; e1 = e1 >= 0.f ? e1 : 0.2f * e1;
    m0 = fmaxf(m0, e0); m1 = fmaxf(m1, e1);
  }
#pragma unroll
  for (int m = 32; m >= 1; m >>= 1) { m0 = fmaxf(m0, __shfl_xor(m0, m)); m1 = fmaxf(m1, __shfl_xor(m1, m)); }

  // pass 2: fused exp + gather + accumulate
  float4 acc = make_float4(0.f, 0.f, 0.f, 0.f);
  float s0 = 0.f, s1 = 0.f;
  bool h0 = lane < 32;
  for (int k = 0; k < dg; ++k) {
    int s = csr[off + k];
    float2 a = as2[s];
    float e0 = a.x + ad0; e0 = e0 >= 0.f ? e0 : 0.2f * e0;
    float e1 = a.y + ad1; e1 = e1 >= 0.f ? e1 : 0.2f * e1;
    float x0 = __expf(e0 - m0), x1 = __expf(e1 - m1);
    s0 += x0; s1 += x1;
    float xa = h0 ? x0 : x1;
    ushort4 u = ((const ushort4*)(xpb + (size_t)s * 512))[lane];
    acc.x = fmaf(bf2f(u.x), xa, acc.x);
    acc.y = fmaf(bf2f(u.y), xa, acc.y);
    acc.z = fmaf(bf2f(u.z), xa, acc.z);
    acc.w = fmaf(bf2f(u.w), xa, acc.w);
  }
  float r = h0 ? (1.f / s0) : (1.f / s1);
  acc.x *= r; acc.y *= r; acc.z *= r; acc.w *= r;

  float ox = __shfl_down(acc.x, 32);
  float oy = __shfl_down(acc.y, 32);
  float oz = __shfl_down(acc.z, 32);
  float ow = __shfl_down(acc.w, 32);
  if (h0) {
    int f4 = lane << 2;
    float4 b = ld4(bias + f4);
    float4 o;
    o.x = fmaxf(0.f, (acc.x + ox) * 0.5f + b.x);
    o.y = fmaxf(0.f, (acc.y + oy) * 0.5f + b.y);
    o.z = fmaxf(0.f, (acc.z + oz) * 0.5f + b.z);
    o.w = fmaxf(0.f, (acc.w + ow) * 0.5f + b.w);
    st4(h1 + (size_t)n * 128 + f4, o);
  }
}

// ---------------- BatchNorm stats ----------------
template <int C>
__global__ __launch_bounds__(256) void bn_stats(const float* __restrict__ h, int N, float* __restrict__ P,
                                                float* __restrict__ PS) {
  constexpr int R = 256 / C;
  __shared__ float sh[256], sh2[256];
  int t = threadIdx.x;
  int c = t % C, r = t / C;
  float s = 0.f, ss = 0.f;
  for (int n = blockIdx.x * R + r; n < N; n += gridDim.x * R) {
    float v = h[(size_t)n * C + c];
    s += v; ss += v * v;
  }
  sh[t] = s; sh2[t] = ss;
  __syncthreads();
  if (r == 0) {
#pragma unroll
    for (int i = 1; i < R; ++i) { s += sh[i * C + c]; ss += sh2[i * C + c]; }
    P[blockIdx.x * C + c] = s;
    PS[blockIdx.x * C + c] = ss;
  }
}

template <int C>
__global__ void bn_reduce(const float* __restrict__ P, const float* __restrict__ PS, int G, int N,
                          const float* __restrict__ g, const float* __restrict__ b,
                          float* __restrict__ svec, float* __restrict__ tvec) {
  int c = threadIdx.x;
  if (c >= C) return;
  float s = 0.f, ss = 0.f;
  for (int i = 0; i < G; ++i) { s += P[i * C + c]; ss += PS[i * C + c]; }
  float mean = s / N;
  float var = ss / N - mean * mean;
  float sc = g[c] * rsqrtf(var + 1e-5f);
  svec[c] = sc;
  tvec[c] = b[c] - mean * sc;
}

__global__ __launch_bounds__(256) void fold_gcn(const float* __restrict__ W, const float* __restrict__ svec,
                                                const float* __restrict__ tvec, float* __restrict__ Wf,
                                                float* __restrict__ cvec) {
  int t = threadIdx.x;
  for (int i = t; i < 128 * 64; i += 256) {
    int k = i >> 6;
    Wf[i] = svec[k] * W[i];
  }
  if (t < 64) {
    float c = 0.f;
    for (int k = 0; k < 128; ++k) c += tvec[k] * W[k * 64 + t];
    cvec[t] = c;
  }
}

__global__ __launch_bounds__(256) void fold_mulv(const float* __restrict__ Wmu, const float* __restrict__ mub,
                                                 const float* __restrict__ Wlv, const float* __restrict__ lvb,
                                                 const float* __restrict__ svec, const float* __restrict__ tvec,
                                                 float* __restrict__ Wmuf, float* __restrict__ cmu,
                                                 float* __restrict__ Wlvf, float* __restrict__ clv) {
  int t = threadIdx.x;
  for (int i = t; i < 4096; i += 256) {
    int k = i >> 6;
    Wmuf[i] = svec[k] * Wmu[i];
    Wlvf[i] = svec[k] * Wlv[i];
  }
  if (t < 64) {
    float cm = mub[t], cl = lvb[t];
    for (int k = 0; k < 64; ++k) { cm += tvec[k] * Wmu[k * 64 + t]; cl += tvec[k] * Wlv[k * 64 + t]; }
    cmu[t] = cm; clv[t] = cl;
  }
}

// ---------------- GCN aggregation (bf16 xp2 gather) ----------------
__global__ __launch_bounds__(256) void gcn_aggregate_bf(const int* __restrict__ offs, const int* __restrict__ deg,
                                                        const int* __restrict__ csr,
                                                        const unsigned short* __restrict__ xpb2,
                                                        const float* __restrict__ dinv, const float* __restrict__ bias,
                                                        float* __restrict__ g2, int N) {
  int wid = threadIdx.x >> 6, lane = threadIdx.x & 63;
  int n = blockIdx.x * 4 + wid;
  if (n >= N) return;
  int off = offs[n], dg = deg[n];
  float acc = 0.f;
  for (int k = 0; k < dg; ++k) {
    int s = csr[off + k];
    acc = fmaf(bf2f(xpb2[(size_t)s * 64 + lane]), dinv[s], acc);
  }
  float v = acc * dinv[n] + bias[lane];
  g2[(size_t)n * 64 + lane] = fmaxf(v, 0.f);
}

// ---------------- reparameterize ----------------
__global__ void reparam(const float* __restrict__ mu, const float* __restrict__ lv,
                        const float* __restrict__ eps, float* __restrict__ z, int total) {
  int i = blockIdx.x * blockDim.x + threadIdx.x;
  if (i >= total) return;
  z[i] = fmaf(eps[i], __expf(0.5f * lv[i]), mu[i]);
}

// ---------------- f32 -> bf16 packed convert ----------------
__global__ void cvt_bf16(const float* __restrict__ in, unsigned short* __restrict__ out, int n4) {
  int i = blockIdx.x * blockDim.x + threadIdx.x;
  if (i >= n4) return;
  float4 v = ((const float4*)in)[i];
  ushort4 o;
  o.x = f2bf(v.x); o.y = f2bf(v.y); o.z = f2bf(v.z); o.w = f2bf(v.w);
  ((ushort4*)out)[i] = o;
}

// ---------------- prep gat_W -> transposed bf16 Wtb[col][k] ----------------
__global__ void prep_gatW(const float* __restrict__ W, unsigned short* __restrict__ Wtb) {
  int i = blockIdx.x * blockDim.x + threadIdx.x;
  if (i >= 256 * 256) return;
  int col = i >> 8, k = i & 255;
  Wtb[i] = f2bf(W[k * 256 + col]);
}

// ---------------- prep W1 → bf16 decoder layout [4 kt][256 j][40 kp] (padded) ----------------
__global__ void prep_W1(const float* __restrict__ W1, unsigned short* __restrict__ W1t) {
  int i = blockIdx.x * blockDim.x + threadIdx.x;
  if (i >= 4 * 256 * 40) return;
  int kt = i / 10240;
  int rem = i - kt * 10240;
  int j = rem / 40;
  int kp = rem - j * 40;
  float v = (kp < 32) ? W1[(size_t)(kt * 32 + kp) * 256 + j] : 0.f;
  W1t[i] = f2bf(v);
}

// ---------------- MFMA decoder (B staged per k-tile in LDS) ----------------
__global__ __launch_bounds__(256) void decoder_mfma(const int* __restrict__ ei, int E,
                                                    const unsigned short* __restrict__ rzb,
                                                    const unsigned short* __restrict__ W1t,
                                                    const float* __restrict__ b1, const float* __restrict__ W2,
                                                    const float* __restrict__ b2, float* __restrict__ recon) {
  __shared__ unsigned short Als[64 * 128];   // 16 KB
  __shared__ unsigned short Bls[256 * 40];   // 20 KB
  __shared__ float red[4][64];
  int t = threadIdx.x;
  int wv = t >> 6, l = t & 63;
  int lg = l >> 4, ll = l & 15;
  int e0 = blockIdx.x * 64;

  {
    int e = t >> 2;
    int part = (t >> 1) & 1;
    int half = t & 1;
    int eg = e0 + e;
    if (eg >= E) eg = E - 1;
    int r = (part == 0) ? ei[eg] : ei[E + eg];
    const uint4* gsrc = (const uint4*)(rzb + (size_t)r * 64 + half * 32);
    int bo0 = part * 128 + half * 64;
    int swz = (e & 7) << 4;
#pragma unroll
    for (int c = 0; c < 4; ++c) {
      uint4 v = gsrc[c];
      int bo = bo0 + c * 16;
      *(uint4*)&Als[e * 128 + ((bo ^ swz) >> 1)] = v;
    }
  }

  f32x4 acc[4][4];
#pragma unroll
  for (int a = 0; a < 4; ++a)
#pragma unroll
    for (int b = 0; b < 4; ++b) acc[a][b] = (f32x4){0.f, 0.f, 0.f, 0.f};

  for (int kt = 0; kt < 4; ++kt) {
    __syncthreads();
    {
      const uint4* gsrc = (const uint4*)(W1t + kt * 10240);
      uint4* ldst = (uint4*)Bls;
#pragma unroll
      for (int i = 0; i < 5; ++i) ldst[t + i * 256] = gsrc[t + i * 256];
    }
    __syncthreads();

    bfrag af[4];
#pragma unroll
    for (int fm = 0; fm < 4; ++fm) {
      int e = fm * 16 + ll;
      int bo = kt * 64 + lg * 16;
      af[fm] = *(const bfrag*)&Als[e * 128 + ((bo ^ ((e & 7) << 4)) >> 1)];
    }
#pragma unroll
    for (int fn = 0; fn < 4; ++fn) {
      int j = wv * 64 + fn * 16 + ll;
      bfrag bf = *(const bfrag*)&Bls[j * 40 + lg * 8];
#pragma unroll
      for (int fm = 0; fm < 4; ++fm)
        acc[fm][fn] = __builtin_amdgcn_mfma_f32_16x16x32_bf16(af[fm], bf, acc[fm][fn], 0, 0, 0);
    }
  }

  float bj[4], wj[4];
#pragma unroll
  for (int fn = 0; fn < 4; ++fn) {
    int j = wv * 64 + fn * 16 + ll;
    bj[fn] = b1[j];
    wj[fn] = W2[j];
  }
#pragma unroll
  for (int fm = 0; fm < 4; ++fm) {
    float pr[4] = {0.f, 0.f, 0.f, 0.f};
#pragma unroll
    for (int fn = 0; fn < 4; ++fn) {
#pragma unroll
      for (int r = 0; r < 4; ++r)
        pr[r] = fmaf(fmaxf(acc[fm][fn][r] + bj[fn], 0.f), wj[fn], pr[r]);
    }
#pragma unroll
    for (int m = 8; m >= 1; m >>= 1) {
#pragma unroll
      for (int r = 0; r < 4; ++r) pr[r] += __shfl_xor(pr[r], m);
    }
    if (ll == 0) {
#pragma unroll
      for (int r = 0; r < 4; ++r) red[wv][fm * 16 + lg * 4 + r] = pr[r];
    }
  }
  __syncthreads();
  if (t < 64) {
    int eg = e0 + t;
    if (eg < E) recon[eg] = red[0][t] + red[1][t] + red[2][t] + red[3][t] + b2[0];
  }
}

extern "C" void kernel_launch(void* const* d_in, const int* in_sizes, int n_in,
                              void* d_out, int out_size, void* d_ws, size_t ws_size,
                              hipStream_t stream) {
  const float* x = (const float*)d_in[0];
  const int* ei = (const int*)d_in[1];
  const float* gat_W = (const float*)d_in[2];
  const float* att_src = (const float*)d_in[3];
  const float* att_dst = (const float*)d_in[4];
  const float* gat_bias = (const float*)d_in[5];
  const float* bn1_g = (const float*)d_in[6];
  const float* bn1_b = (const float*)d_in[7];
  const float* gcn_W = (const float*)d_in[8];
  const float* gcn_bias = (const float*)d_in[9];
  const float* bn2_g = (const float*)d_in[10];
  const float* bn2_b = (const float*)d_in[11];
  const float* mu_W = (const float*)d_in[12];
  const float* mu_b = (const float*)d_in[13];
  const float* lv_W = (const float*)d_in[14];
  const float* lv_b = (const float*)d_in[15];
  const float* res_W = (const float*)d_in[16];
  const float* res_b = (const float*)d_in[17];
  const float* dec_W1 = (const float*)d_in[18];
  const float* dec_b1 = (const float*)d_in[19];
  const float* dec_W2 = (const float*)d_in[20];
  const float* dec_b2 = (const float*)d_in[21];
  const float* eps = (const float*)d_in[22];

  int N = in_sizes[0] / DIN;   // 50000
  int E = in_sizes[1] / 2;     // 800000
  int Et = E + N;
  int NB = (N + 255) / 256;    // scan chunks (<= 256)

  float* ws = (float*)d_ws;
  size_t off = 0;
  float* xp = ws; off += (size_t)N * 256;
  unsigned short* xpb = (unsigned short*)xp;    // bf16 xp rows, stride 512 ushorts
  unsigned short* xpb2 = (unsigned short*)xp;   // bf16 xp2 [N,64] (xpb dead by then)
  float* g2 = xp + (size_t)N * 64;
  float* zb = xp + (size_t)N * 128;
  float* rz = xp + (size_t)N * 192;
  unsigned short* rzb = (unsigned short*)rz;    // bf16 res_z [N,64], written by gemm64b
  float* h1 = ws + off; off += (size_t)N * 128;
  unsigned short* xb = (unsigned short*)h1;     // bf16 x (dead once gat_fused writes h1)
  float* a_src = ws + off; off += (size_t)2 * N;
  float* a_dst = ws + off; off += (size_t)2 * N;
  float* dinv = ws + off; off += N;
  float* P = ws + off; off += 128 * 128;
  float* PS = ws + off; off += 128 * 128;
  float* svec = ws + off; off += 128;
  float* tvec = ws + off; off += 128;
  float* W2f = ws + off; off += 128 * 64;
  float* c2 = ws + off; off += 64;
  float* Wmuf = ws + off; off += 64 * 64;
  float* cmu = ws + off; off += 64;
  float* Wlvf = ws + off; off += 64 * 64;
  float* clv = ws + off; off += 64;
  unsigned short* W1t = (unsigned short*)(ws + off); off += 20480;   // 4*256*40 bf16
  unsigned short* Wtb = (unsigned short*)(ws + off); off += 32768;   // 256*256 bf16
  int* deg = (int*)(ws + off); off += N;
  int* offs = (int*)(ws + off); off += N;
  int* cursor = (int*)(ws + off); off += N;
  int* bsum = (int*)(ws + off); off += 256;
  int* csr = (int*)(ws + off); off += Et;

  float* recon = (float*)d_out;
  float* mu = recon + E;
  float* lv = mu + (size_t)N * LAT;

  // 0. weight preps (independent, do early)
  prep_W1<<<(4 * 256 * 40 + 255) / 256, 256, 0, stream>>>(dec_W1, W1t);
  prep_gatW<<<(256 * 256 + 255) / 256, 256, 0, stream>>>(gat_W, Wtb);

  // 1. x -> bf16, then xp = x @ gat_W via MFMA (writes bf16 xpb directly)
  cvt_bf16<<<(N * 64 + 255) / 256, 256, 0, stream>>>(x, xb, N * 64);
  dim3 gX(4, (N + 63) / 64);
  gemm_xp_mfma<<<gX, 256, 0, stream>>>(xb, Wtb, xpb, N);

  // 2. attention scores (bf16 xp)
  attn_scores_bf<<<(N + 3) / 4, 256, 0, stream>>>(xpb, att_src, att_dst, a_src, a_dst, N);

  // 3. CSR build (parallel 3-phase scan)
  hipMemsetAsync(deg, 0, (size_t)N * sizeof(int), stream);
  deg_count<<<(Et + 255) / 256, 256, 0, stream>>>(ei, E, Et, deg);
  bsum_kernel<<<NB, 256, 0, stream>>>(deg, N, bsum);
  bscan_kernel<<<1, 256, 0, stream>>>(bsum, NB);
  scan_apply<<<NB, 256, 0, stream>>>(deg, bsum, N, offs, cursor, dinv);
  csr_fill<<<(Et + 255) / 256, 256, 0, stream>>>(ei, E, Et, cursor, csr);

  // 4. fused GAT softmax + aggregation
  gat_fused<<<(N + 3) / 4, 256, 0, stream>>>(offs, deg, csr, a_src, a_dst, xpb, gat_bias, h1, N);

  // 5. BN1 folded into GCN weights; xp2 (bf16) = h1 @ W2f + c2
  bn_stats<128><<<128, 256, 0, stream>>>(h1, N, P, PS);
  bn_reduce<128><<<1, 128, 0, stream>>>(P, PS, 128, N, bn1_g, bn1_b, svec, tvec);
  fold_gcn<<<1, 256, 0, stream>>>(gcn_W, svec, tvec, W2f, c2);
  dim3 gB((N + 63) / 64, 1);
  gemm64b<<<gB, 256, 0, stream>>>(h1, W2f, c2, xpb2, N, 64, 128);

  // 6. GCN aggregation (bf16 gather)
  gcn_aggregate_bf<<<(N + 3) / 4, 256, 0, stream>>>(offs, deg, csr, xpb2, dinv, gcn_bias, g2, N);

  // 7. BN2 folded into mu/lv
  bn_stats<64><<<128, 256, 0, stream>>>(g2, N, P, PS);
  bn_reduce<64><<<1, 64, 0, stream>>>(P, PS, 128, N, bn2_g, bn2_b, svec, tvec);
  fold_mulv<<<1, 256, 0, stream>>>(mu_W, mu_b, lv_W, lv_b, svec, tvec, Wmuf, cmu, Wlvf, clv);
  gemm64<<<gB, 256, 0, stream>>>(g2, Wmuf, cmu, mu, N, 64, 64);
  gemm64<<<gB, 256, 0, stream>>>(g2, Wlvf, clv, lv, N, 64, 64);

  // 8. z; res_z (bf16 directly)
  reparam<<<(N * 64 + 255) / 256, 256, 0, stream>>>(mu, lv, eps, zb, N * 64);
  gemm64b<<<gB, 256, 0, stream>>>(zb, res_W, res_b, rzb, N, 64, 64);

  // 9. MFMA decoder
  decoder_mfma<<<(E + 63) / 64, 256, 0, stream>>>(ei, E, rzb, W1t, dec_b1, dec_W2, dec_b2, recon);
}

// Round 9
// 667.537 us; speedup vs baseline: 1.1261x; 1.0029x over previous
//
#include <hip/hip_runtime.h>
#include <math.h>

constexpr int DIN = 256;
constexpr int HID = 128;
constexpr int LAT = 64;

typedef short bfrag __attribute__((ext_vector_type(8)));   // 8 bf16 (4 VGPRs)
typedef float f32x4 __attribute__((ext_vector_type(4)));

__device__ __forceinline__ float4 ld4(const float* p) { return *reinterpret_cast<const float4*>(p); }
__device__ __forceinline__ void st4(float* p, float4 v) { *reinterpret_cast<float4*>(p) = v; }

__device__ __forceinline__ unsigned short f2bf(float f) {
  unsigned int u = __float_as_uint(f);
  unsigned int r = (u + 0x7FFFu + ((u >> 16) & 1u)) >> 16;  // RNE
  return (unsigned short)r;
}

__device__ __forceinline__ float bf2f(unsigned short u) {
  return __uint_as_float(((unsigned int)u) << 16);
}

// ---------------- generic f32 GEMM: C[M,N] = A[M,K] @ B[K,N] (+ crow[N]) ----------------
__global__ __launch_bounds__(256) void gemm64(const float* __restrict__ A, const float* __restrict__ B,
                                              const float* __restrict__ crow, float* __restrict__ C,
                                              int M, int N, int K) {
  __shared__ float As[32][68];
  __shared__ float Bs[32][68];
  int t = threadIdx.x;
  int m0 = blockIdx.x * 64, n0 = blockIdx.y * 64;
  int tm = t & 15, tn = t >> 4;
  float acc[4][4];
#pragma unroll
  for (int i = 0; i < 4; i++)
#pragma unroll
    for (int j = 0; j < 4; j++) acc[i][j] = 0.f;

  for (int kt = 0; kt < K; kt += 32) {
#pragma unroll
    for (int i = 0; i < 2; ++i) {
      int f4 = t + i * 256;
      int m = f4 >> 3;
      int k4 = (f4 & 7) << 2;
      int gm = m0 + m;
      float4 v = make_float4(0.f, 0.f, 0.f, 0.f);
      if (gm < M) v = ld4(A + (size_t)gm * K + kt + k4);
      As[k4 + 0][m] = v.x; As[k4 + 1][m] = v.y; As[k4 + 2][m] = v.z; As[k4 + 3][m] = v.w;
    }
#pragma unroll
    for (int i = 0; i < 2; ++i) {
      int f4 = t + i * 256;
      int k = f4 >> 4;
      int n4 = (f4 & 15) << 2;
      float4 v = ld4(B + (size_t)(kt + k) * N + n0 + n4);
      st4(&Bs[k][n4], v);
    }
    __syncthreads();
#pragma unroll
    for (int k = 0; k < 32; ++k) {
      float4 a = ld4(&As[k][tm << 2]);
      float4 b = ld4(&Bs[k][tn << 2]);
      float av[4] = {a.x, a.y, a.z, a.w};
      float bv[4] = {b.x, b.y, b.z, b.w};
#pragma unroll
      for (int i = 0; i < 4; i++)
#pragma unroll
        for (int j = 0; j < 4; j++) acc[i][j] = fmaf(av[i], bv[j], acc[i][j]);
    }
    __syncthreads();
  }
#pragma unroll
  for (int i = 0; i < 4; ++i) {
    int gm = m0 + (tm << 2) + i;
    if (gm < M) {
      int nb = n0 + (tn << 2);
      float4 v = make_float4(acc[i][0], acc[i][1], acc[i][2], acc[i][3]);
      if (crow) { v.x += crow[nb]; v.y += crow[nb + 1]; v.z += crow[nb + 2]; v.w += crow[nb + 3]; }
      st4(C + (size_t)gm * N + nb, v);
    }
  }
}

// ---------------- f32 GEMM with bf16 output: Cb[M,N](bf16) = A[M,K] @ B[K,N] + crow ----------------
__global__ __launch_bounds__(256) void gemm64b(const float* __restrict__ A, const float* __restrict__ B,
                                               const float* __restrict__ crow, unsigned short* __restrict__ Cb,
                                               int M, int N, int K) {
  __shared__ float As[32][68];
  __shared__ float Bs[32][68];
  int t = threadIdx.x;
  int m0 = blockIdx.x * 64, n0 = blockIdx.y * 64;
  int tm = t & 15, tn = t >> 4;
  float acc[4][4];
#pragma unroll
  for (int i = 0; i < 4; i++)
#pragma unroll
    for (int j = 0; j < 4; j++) acc[i][j] = 0.f;

  for (int kt = 0; kt < K; kt += 32) {
#pragma unroll
    for (int i = 0; i < 2; ++i) {
      int f4 = t + i * 256;
      int m = f4 >> 3;
      int k4 = (f4 & 7) << 2;
      int gm = m0 + m;
      float4 v = make_float4(0.f, 0.f, 0.f, 0.f);
      if (gm < M) v = ld4(A + (size_t)gm * K + kt + k4);
      As[k4 + 0][m] = v.x; As[k4 + 1][m] = v.y; As[k4 + 2][m] = v.z; As[k4 + 3][m] = v.w;
    }
#pragma unroll
    for (int i = 0; i < 2; ++i) {
      int f4 = t + i * 256;
      int k = f4 >> 4;
      int n4 = (f4 & 15) << 2;
      float4 v = ld4(B + (size_t)(kt + k) * N + n0 + n4);
      st4(&Bs[k][n4], v);
    }
    __syncthreads();
#pragma unroll
    for (int k = 0; k < 32; ++k) {
      float4 a = ld4(&As[k][tm << 2]);
      float4 b = ld4(&Bs[k][tn << 2]);
      float av[4] = {a.x, a.y, a.z, a.w};
      float bv[4] = {b.x, b.y, b.z, b.w};
#pragma unroll
      for (int i = 0; i < 4; i++)
#pragma unroll
        for (int j = 0; j < 4; j++) acc[i][j] = fmaf(av[i], bv[j], acc[i][j]);
    }
    __syncthreads();
  }
#pragma unroll
  for (int i = 0; i < 4; ++i) {
    int gm = m0 + (tm << 2) + i;
    if (gm < M) {
      int nb = n0 + (tn << 2);
      ushort4 o;
      o.x = f2bf(acc[i][0] + crow[nb]);
      o.y = f2bf(acc[i][1] + crow[nb + 1]);
      o.z = f2bf(acc[i][2] + crow[nb + 2]);
      o.w = f2bf(acc[i][3] + crow[nb + 3]);
      *(ushort4*)(Cb + (size_t)gm * N + nb) = o;
    }
  }
}

// ---------------- MFMA GEMM: xpb[M,256](bf16, stride 512) = x[M,256](f32) @ Wtb^T ----------------
// Reads f32 x directly; converts to bf16 in-register during LDS staging (no separate cvt pass).
__global__ __launch_bounds__(256) void gemm_xp_mfma(const float* __restrict__ xf,
                                                    const unsigned short* __restrict__ Wtb,
                                                    unsigned short* __restrict__ xpb, int M) {
  __shared__ unsigned short Als[64 * 256];  // 32 KB, rows swizzled
  __shared__ unsigned short Bls[64 * 256];  // 32 KB, cols swizzled
  int t = threadIdx.x;
  int wv = t >> 6, l = t & 63, lg = l >> 4, ll = l & 15;
  int cg = blockIdx.x;            // col group (fast dim)
  int rt = blockIdx.y;            // row tile

  // stage A: f32 load + cvt + swizzled bf16 store
  {
    int row = t >> 2, seg = t & 3;
    int gr = min(rt * 64 + row, M - 1);
    const float4* src = (const float4*)(xf + (size_t)gr * 256 + seg * 64);
    int swz = (row & 7) << 4;
#pragma unroll
    for (int c = 0; c < 8; ++c) {
      float4 a = src[2 * c], b = src[2 * c + 1];
      uint4 v;
      v.x = (unsigned)f2bf(a.x) | ((unsigned)f2bf(a.y) << 16);
      v.y = (unsigned)f2bf(a.z) | ((unsigned)f2bf(a.w) << 16);
      v.z = (unsigned)f2bf(b.x) | ((unsigned)f2bf(b.y) << 16);
      v.w = (unsigned)f2bf(b.z) | ((unsigned)f2bf(b.w) << 16);
      int bo = seg * 128 + c * 16;
      *(uint4*)((char*)Als + row * 512 + (bo ^ swz)) = v;
    }
  }
  {
    int col = t >> 2, seg = t & 3;
    const uint4* src = (const uint4*)(Wtb + (size_t)(cg * 64 + col) * 256 + seg * 64);
    int swz = (col & 7) << 4;
#pragma unroll
    for (int c = 0; c < 8; ++c) {
      int bo = seg * 128 + c * 16;
      *(uint4*)((char*)Bls + col * 512 + (bo ^ swz)) = src[c];
    }
  }
  __syncthreads();

  f32x4 acc[4];
#pragma unroll
  for (int i = 0; i < 4; ++i) acc[i] = (f32x4){0.f, 0.f, 0.f, 0.f};

#pragma unroll
  for (int kt = 0; kt < 8; ++kt) {
    int ar = wv * 16 + ll;
    bfrag af = *(const bfrag*)((char*)Als + ar * 512 + ((kt * 64 + lg * 16) ^ ((ar & 7) << 4)));
#pragma unroll
    for (int fn = 0; fn < 4; ++fn) {
      int bc = fn * 16 + ll;
      bfrag bf = *(const bfrag*)((char*)Bls + bc * 512 + ((kt * 64 + lg * 16) ^ ((bc & 7) << 4)));
      acc[fn] = __builtin_amdgcn_mfma_f32_16x16x32_bf16(af, bf, acc[fn], 0, 0, 0);
    }
  }

#pragma unroll
  for (int fn = 0; fn < 4; ++fn) {
#pragma unroll
    for (int r = 0; r < 4; ++r) {
      int row = rt * 64 + wv * 16 + lg * 4 + r;
      if (row < M) xpb[(size_t)row * 512 + cg * 64 + fn * 16 + ll] = f2bf(acc[fn][r]);
    }
  }
}

// ---------------- attention scores (bf16 xp) ----------------
__global__ __launch_bounds__(256) void attn_scores_bf(const unsigned short* __restrict__ xpb,
                                                      const float* __restrict__ att_src,
                                                      const float* __restrict__ att_dst,
                                                      float* __restrict__ a_src, float* __restrict__ a_dst, int N) {
  int wid = threadIdx.x >> 6, lane = threadIdx.x & 63;
  int n = blockIdx.x * 4 + wid;
  if (n >= N) return;
  int h = lane >> 5;
  int f4 = (lane & 31) << 2;
  ushort4 u = *(const ushort4*)(xpb + (size_t)n * 512 + lane * 4);
  float4 as = ld4(att_src + h * 128 + f4);
  float4 ad = ld4(att_dst + h * 128 + f4);
  float vx = bf2f(u.x), vy = bf2f(u.y), vz = bf2f(u.z), vw = bf2f(u.w);
  float ps = vx * as.x + vy * as.y + vz * as.z + vw * as.w;
  float pd = vx * ad.x + vy * ad.y + vz * ad.z + vw * ad.w;
#pragma unroll
  for (int m = 16; m >= 1; m >>= 1) { ps += __shfl_xor(ps, m); pd += __shfl_xor(pd, m); }
  if ((lane & 31) == 0) { a_src[n * 2 + h] = ps; a_dst[n * 2 + h] = pd; }
}

// ---------------- CSR build ----------------
__global__ void deg_count(const int* __restrict__ ei, int E, int Et, int* __restrict__ deg) {
  int i = blockIdx.x * blockDim.x + threadIdx.x;
  if (i >= Et) return;
  int d = (i < E) ? ei[E + i] : (i - E);
  atomicAdd(&deg[d], 1);
}

__global__ __launch_bounds__(256) void bsum_kernel(const int* __restrict__ deg, int N, int* __restrict__ bsum) {
  int t = threadIdx.x;
  int i = blockIdx.x * 256 + t;
  int v = (i < N) ? deg[i] : 0;
#pragma unroll
  for (int m = 32; m >= 1; m >>= 1) v += __shfl_xor(v, m);
  __shared__ int sh[4];
  if ((t & 63) == 0) sh[t >> 6] = v;
  __syncthreads();
  if (t == 0) bsum[blockIdx.x] = sh[0] + sh[1] + sh[2] + sh[3];
}

__global__ __launch_bounds__(256) void bscan_kernel(int* __restrict__ bsum, int B) {
  __shared__ int sh[256];
  int t = threadIdx.x;
  int v = (t < B) ? bsum[t] : 0;
  sh[t] = v;
  __syncthreads();
  for (int d = 1; d < 256; d <<= 1) {
    int x = (t >= d) ? sh[t - d] : 0;
    __syncthreads();
    sh[t] += x;
    __syncthreads();
  }
  if (t < B) bsum[t] = sh[t] - v;
}

__global__ __launch_bounds__(256) void scan_apply(const int* __restrict__ deg, const int* __restrict__ bsum, int N,
                                                  int* __restrict__ offs, int* __restrict__ cursor,
                                                  float* __restrict__ dinv) {
  int t = threadIdx.x;
  int i = blockIdx.x * 256 + t;
  int v = (i < N) ? deg[i] : 0;
  __shared__ int sh[256];
  sh[t] = v;
  __syncthreads();
  for (int d = 1; d < 256; d <<= 1) {
    int x = (t >= d) ? sh[t - d] : 0;
    __syncthreads();
    sh[t] += x;
    __syncthreads();
  }
  if (i < N) {
    int off = bsum[blockIdx.x] + sh[t] - v;
    offs[i] = off;
    cursor[i] = off;
    dinv[i] = rsqrtf((float)v);   // deg >= 1 (self-loop)
  }
}

__global__ void csr_fill(const int* __restrict__ ei, int E, int Et, int* __restrict__ cursor, int* __restrict__ csr) {
  int i = blockIdx.x * blockDim.x + threadIdx.x;
  if (i >= Et) return;
  int s, d;
  if (i < E) { s = ei[i]; d = ei[E + i]; } else { s = i - E; d = i - E; }
  int pos = atomicAdd(&cursor[d], 1);
  csr[pos] = s;
}

// ---------------- FUSED GAT, no-max softmax (wave per node) ----------------
// exp(e) without max-subtraction: e = a_src+a_dst ~ N(0,2) here, so no f32
// overflow (safe to e~88); softmax is shift-invariant so the result is identical.
// Single edge-serial pass: accumulate exp-weighted xp rows + exp-sums, divide at end.
__global__ __launch_bounds__(256) void gat_fused(const int* __restrict__ offs, const int* __restrict__ deg,
                                                 const int* __restrict__ csr, const float* __restrict__ a_src,
                                                 const float* __restrict__ a_dst,
                                                 const unsigned short* __restrict__ xpb,
                                                 const float* __restrict__ bias,
                                                 float* __restrict__ h1, int N) {
  int wid = threadIdx.x >> 6, lane = threadIdx.x & 63;
  int n = blockIdx.x * 4 + wid;
  if (n >= N) return;
  int off = offs[n], dg = deg[n];
  float ad0 = a_dst[n * 2], ad1 = a_dst[n * 2 + 1];
  const float2* as2 = (const float2*)a_src;

  float4 acc = make_float4(0.f, 0.f, 0.f, 0.f);
  float s0 = 0.f, s1 = 0.f;
  bool h0 = lane < 32;
  for (int k = 0; k < dg; ++k) {
    int s = csr[off + k];
    float2 a = as2[s];
    float e0 = a.x + ad0; e0 = e0 >= 0.f ? e0 : 0.2f * e0;
    float e1 = a.y + ad1; e1 = e1 >= 0.f ? e1 : 0.2f * e1;
    float x0 = __expf(e0), x1 = __expf(e1);
    s0 += x0; s1 += x1;
    float xa = h0 ? x0 : x1;
    ushort4 u = ((const ushort4*)(xpb + (size_t)s * 512))[lane];
    acc.x = fmaf(bf2f(u.x), xa, acc.x);
    acc.y = fmaf(bf2f(u.y), xa, acc.y);
    acc.z = fmaf(bf2f(u.z), xa, acc.z);
    acc.w = fmaf(bf2f(u.w), xa, acc.w);
  }
  float r = h0 ? (1.f / s0) : (1.f / s1);
  acc.x *= r; acc.y *= r; acc.z *= r; acc.w *= r;

  float ox = __shfl_down(acc.x, 32);
  float oy = __shfl_down(acc.y, 32);
  float oz = __shfl_down(acc.z, 32);
  float ow = __shfl_down(acc.w, 32);
  if (h0) {
    int f4 = lane << 2;
    float4 b = ld4(bias + f4);
    float4 o;
    o.x = fmaxf(0.f, (acc.x + ox) * 0.5f + b.x);
    o.y = fmaxf(0.f, (acc.y + oy) * 0.5f + b.y);
    o.z = fmaxf(0.f, (acc.z + oz) * 0.5f + b.z);
    o.w = fmaxf(0.f, (acc.w + ow) * 0.5f + b.w);
    st4(h1 + (size_t)n * 128 + f4, o);
  }
}

// ---------------- BatchNorm stats ----------------
template <int C>
__global__ __launch_bounds__(256) void bn_stats(const float* __restrict__ h, int N, float* __restrict__ P,
                                                float* __restrict__ PS) {
  constexpr int R = 256 / C;
  __shared__ float sh[256], sh2[256];
  int t = threadIdx.x;
  int c = t % C, r = t / C;
  float s = 0.f, ss = 0.f;
  for (int n = blockIdx.x * R + r; n < N; n += gridDim.x * R) {
    float v = h[(size_t)n * C + c];
    s += v; ss += v * v;
  }
  sh[t] = s; sh2[t] = ss;
  __syncthreads();
  if (r == 0) {
#pragma unroll
    for (int i = 1; i < R; ++i) { s += sh[i * C + c]; ss += sh2[i * C + c]; }
    P[blockIdx.x * C + c] = s;
    PS[blockIdx.x * C + c] = ss;
  }
}

template <int C>
__global__ void bn_reduce(const float* __restrict__ P, const float* __restrict__ PS, int G, int N,
                          const float* __restrict__ g, const float* __restrict__ b,
                          float* __restrict__ svec, float* __restrict__ tvec) {
  int c = threadIdx.x;
  if (c >= C) return;
  float s = 0.f, ss = 0.f;
  for (int i = 0; i < G; ++i) { s += P[i * C + c]; ss += PS[i * C + c]; }
  float mean = s / N;
  float var = ss / N - mean * mean;
  float sc = g[c] * rsqrtf(var + 1e-5f);
  svec[c] = sc;
  tvec[c] = b[c] - mean * sc;
}

__global__ __launch_bounds__(256) void fold_gcn(const float* __restrict__ W, const float* __restrict__ svec,
                                                const float* __restrict__ tvec, float* __restrict__ Wf,
                                                float* __restrict__ cvec) {
  int t = threadIdx.x;
  for (int i = t; i < 128 * 64; i += 256) {
    int k = i >> 6;
    Wf[i] = svec[k] * W[i];
  }
  if (t < 64) {
    float c = 0.f;
    for (int k = 0; k < 128; ++k) c += tvec[k] * W[k * 64 + t];
    cvec[t] = c;
  }
}

__global__ __launch_bounds__(256) void fold_mulv(const float* __restrict__ Wmu, const float* __restrict__ mub,
                                                 const float* __restrict__ Wlv, const float* __restrict__ lvb,
                                                 const float* __restrict__ svec, const float* __restrict__ tvec,
                                                 float* __restrict__ Wmuf, float* __restrict__ cmu,
                                                 float* __restrict__ Wlvf, float* __restrict__ clv) {
  int t = threadIdx.x;
  for (int i = t; i < 4096; i += 256) {
    int k = i >> 6;
    Wmuf[i] = svec[k] * Wmu[i];
    Wlvf[i] = svec[k] * Wlv[i];
  }
  if (t < 64) {
    float cm = mub[t], cl = lvb[t];
    for (int k = 0; k < 64; ++k) { cm += tvec[k] * Wmu[k * 64 + t]; cl += tvec[k] * Wlv[k * 64 + t]; }
    cmu[t] = cm; clv[t] = cl;
  }
}

// ---------------- GCN aggregation (bf16 xp2 gather) ----------------
__global__ __launch_bounds__(256) void gcn_aggregate_bf(const int* __restrict__ offs, const int* __restrict__ deg,
                                                        const int* __restrict__ csr,
                                                        const unsigned short* __restrict__ xpb2,
                                                        const float* __restrict__ dinv, const float* __restrict__ bias,
                                                        float* __restrict__ g2, int N) {
  int wid = threadIdx.x >> 6, lane = threadIdx.x & 63;
  int n = blockIdx.x * 4 + wid;
  if (n >= N) return;
  int off = offs[n], dg = deg[n];
  float acc = 0.f;
  for (int k = 0; k < dg; ++k) {
    int s = csr[off + k];
    acc = fmaf(bf2f(xpb2[(size_t)s * 64 + lane]), dinv[s], acc);
  }
  float v = acc * dinv[n] + bias[lane];
  g2[(size_t)n * 64 + lane] = fmaxf(v, 0.f);
}

// ---------------- reparameterize ----------------
__global__ void reparam(const float* __restrict__ mu, const float* __restrict__ lv,
                        const float* __restrict__ eps, float* __restrict__ z, int total) {
  int i = blockIdx.x * blockDim.x + threadIdx.x;
  if (i >= total) return;
  z[i] = fmaf(eps[i], __expf(0.5f * lv[i]), mu[i]);
}

// ---------------- prep gat_W -> transposed bf16 Wtb[col][k] ----------------
__global__ void prep_gatW(const float* __restrict__ W, unsigned short* __restrict__ Wtb) {
  int i = blockIdx.x * blockDim.x + threadIdx.x;
  if (i >= 256 * 256) return;
  int col = i >> 8, k = i & 255;
  Wtb[i] = f2bf(W[k * 256 + col]);
}

// ---------------- prep W1 → bf16 decoder layout [4 kt][256 j][40 kp] (padded) ----------------
__global__ void prep_W1(const float* __restrict__ W1, unsigned short* __restrict__ W1t) {
  int i = blockIdx.x * blockDim.x + threadIdx.x;
  if (i >= 4 * 256 * 40) return;
  int kt = i / 10240;
  int rem = i - kt * 10240;
  int j = rem / 40;
  int kp = rem - j * 40;
  float v = (kp < 32) ? W1[(size_t)(kt * 32 + kp) * 256 + j] : 0.f;
  W1t[i] = f2bf(v);
}

// ---------------- MFMA decoder: 128 edges/block, 8 waves ----------------
// wave wv: edge-half wv>>2 (64 edges), j-quadrant wv&3 (64 j). B staged per k-tile in
// LDS, shared by both edge halves (amortized 2x vs 64-edge blocks). A swizzled as before.
__global__ __launch_bounds__(512) void decoder_mfma(const int* __restrict__ ei, int E,
                                                    const unsigned short* __restrict__ rzb,
                                                    const unsigned short* __restrict__ W1t,
                                                    const float* __restrict__ b1, const float* __restrict__ W2,
                                                    const float* __restrict__ b2, float* __restrict__ recon) {
  __shared__ unsigned short Als[128 * 128];  // 32 KB
  __shared__ unsigned short Bls[256 * 40];   // 20 KB
  __shared__ float red[8][64];               // 2 KB
  int t = threadIdx.x;
  int wv = t >> 6, l = t & 63;
  int lg = l >> 4, ll = l & 15;
  int we = wv >> 2;        // edge half
  int wj = wv & 3;         // j quadrant
  int e0 = blockIdx.x * 128;

  // ---- stage A: gather 128 e_emb rows (bf16), swizzled ----
  {
    int e = t >> 2;
    int part = (t >> 1) & 1;
    int half = t & 1;
    int eg = e0 + e;
    if (eg >= E) eg = E - 1;
    int r = (part == 0) ? ei[eg] : ei[E + eg];
    const uint4* gsrc = (const uint4*)(rzb + (size_t)r * 64 + half * 32);
    int bo0 = part * 128 + half * 64;
    int swz = (e & 7) << 4;
#pragma unroll
    for (int c = 0; c < 4; ++c) {
      uint4 v = gsrc[c];
      int bo = bo0 + c * 16;
      *(uint4*)&Als[e * 128 + ((bo ^ swz) >> 1)] = v;
    }
  }

  f32x4 acc[4][4];
#pragma unroll
  for (int a = 0; a < 4; ++a)
#pragma unroll
    for (int b = 0; b < 4; ++b) acc[a][b] = (f32x4){0.f, 0.f, 0.f, 0.f};

  for (int kt = 0; kt < 4; ++kt) {
    __syncthreads();
    {
      const uint4* gsrc = (const uint4*)(W1t + kt * 10240);
      uint4* ldst = (uint4*)Bls;
      ldst[t] = gsrc[t];
      ldst[t + 512] = gsrc[t + 512];
      if (t < 256) ldst[t + 1024] = gsrc[t + 1024];
    }
    __syncthreads();

    bfrag af[4];
#pragma unroll
    for (int fm = 0; fm < 4; ++fm) {
      int e = we * 64 + fm * 16 + ll;
      int bo = kt * 64 + lg * 16;
      af[fm] = *(const bfrag*)&Als[e * 128 + ((bo ^ ((e & 7) << 4)) >> 1)];
    }
#pragma unroll
    for (int fn = 0; fn < 4; ++fn) {
      int j = wj * 64 + fn * 16 + ll;
      bfrag bf = *(const bfrag*)&Bls[j * 40 + lg * 8];
#pragma unroll
      for (int fm = 0; fm < 4; ++fm)
        acc[fm][fn] = __builtin_amdgcn_mfma_f32_16x16x32_bf16(af[fm], bf, acc[fm][fn], 0, 0, 0);
    }
  }

  // ---- epilogue: relu + W2 dot, 16-lane reduce, cross-wave via LDS ----
  float bj[4], wj4[4];
#pragma unroll
  for (int fn = 0; fn < 4; ++fn) {
    int j = wj * 64 + fn * 16 + ll;
    bj[fn] = b1[j];
    wj4[fn] = W2[j];
  }
#pragma unroll
  for (int fm = 0; fm < 4; ++fm) {
    float pr[4] = {0.f, 0.f, 0.f, 0.f};
#pragma unroll
    for (int fn = 0; fn < 4; ++fn) {
#pragma unroll
      for (int r = 0; r < 4; ++r)
        pr[r] = fmaf(fmaxf(acc[fm][fn][r] + bj[fn], 0.f), wj4[fn], pr[r]);
    }
#pragma unroll
    for (int m = 8; m >= 1; m >>= 1) {
#pragma unroll
      for (int r = 0; r < 4; ++r) pr[r] += __shfl_xor(pr[r], m);
    }
    if (ll == 0) {
#pragma unroll
      for (int r = 0; r < 4; ++r) red[wv][fm * 16 + lg * 4 + r] = pr[r];
    }
  }
  __syncthreads();
  if (t < 128) {
    int eg = e0 + t;
    int h = t >> 6, i = t & 63;
    if (eg < E)
      recon[eg] = red[h * 4 + 0][i] + red[h * 4 + 1][i] + red[h * 4 + 2][i] + red[h * 4 + 3][i] + b2[0];
  }
}

extern "C" void kernel_launch(void* const* d_in, const int* in_sizes, int n_in,
                              void* d_out, int out_size, void* d_ws, size_t ws_size,
                              hipStream_t stream) {
  const float* x = (const float*)d_in[0];
  const int* ei = (const int*)d_in[1];
  const float* gat_W = (const float*)d_in[2];
  const float* att_src = (const float*)d_in[3];
  const float* att_dst = (const float*)d_in[4];
  const float* gat_bias = (const float*)d_in[5];
  const float* bn1_g = (const float*)d_in[6];
  const float* bn1_b = (const float*)d_in[7];
  const float* gcn_W = (const float*)d_in[8];
  const float* gcn_bias = (const float*)d_in[9];
  const float* bn2_g = (const float*)d_in[10];
  const float* bn2_b = (const float*)d_in[11];
  const float* mu_W = (const float*)d_in[12];
  const float* mu_b = (const float*)d_in[13];
  const float* lv_W = (const float*)d_in[14];
  const float* lv_b = (const float*)d_in[15];
  const float* res_W = (const float*)d_in[16];
  const float* res_b = (const float*)d_in[17];
  const float* dec_W1 = (const float*)d_in[18];
  const float* dec_b1 = (const float*)d_in[19];
  const float* dec_W2 = (const float*)d_in[20];
  const float* dec_b2 = (const float*)d_in[21];
  const float* eps = (const float*)d_in[22];

  int N = in_sizes[0] / DIN;   // 50000
  int E = in_sizes[1] / 2;     // 800000
  int Et = E + N;
  int NB = (N + 255) / 256;    // scan chunks (<= 256)

  float* ws = (float*)d_ws;
  size_t off = 0;
  float* xp = ws; off += (size_t)N * 256;
  unsigned short* xpb = (unsigned short*)xp;    // bf16 xp rows, stride 512 ushorts
  unsigned short* xpb2 = (unsigned short*)xp;   // bf16 xp2 [N,64] (xpb dead by then)
  float* g2 = xp + (size_t)N * 64;
  float* zb = xp + (size_t)N * 128;
  float* rz = xp + (size_t)N * 192;
  unsigned short* rzb = (unsigned short*)rz;    // bf16 res_z [N,64], written by gemm64b
  float* h1 = ws + off; off += (size_t)N * 128;
  float* a_src = ws + off; off += (size_t)2 * N;
  float* a_dst = ws + off; off += (size_t)2 * N;
  float* dinv = ws + off; off += N;
  float* P = ws + off; off += 128 * 128;
  float* PS = ws + off; off += 128 * 128;
  float* svec = ws + off; off += 128;
  float* tvec = ws + off; off += 128;
  float* W2f = ws + off; off += 128 * 64;
  float* c2 = ws + off; off += 64;
  float* Wmuf = ws + off; off += 64 * 64;
  float* cmu = ws + off; off += 64;
  float* Wlvf = ws + off; off += 64 * 64;
  float* clv = ws + off; off += 64;
  unsigned short* W1t = (unsigned short*)(ws + off); off += 20480;   // 4*256*40 bf16
  unsigned short* Wtb = (unsigned short*)(ws + off); off += 32768;   // 256*256 bf16
  int* deg = (int*)(ws + off); off += N;
  int* offs = (int*)(ws + off); off += N;
  int* cursor = (int*)(ws + off); off += N;
  int* bsum = (int*)(ws + off); off += 256;
  int* csr = (int*)(ws + off); off += Et;

  float* recon = (float*)d_out;
  float* mu = recon + E;
  float* lv = mu + (size_t)N * LAT;

  // 0. weight preps (independent, do early)
  prep_W1<<<(4 * 256 * 40 + 255) / 256, 256, 0, stream>>>(dec_W1, W1t);
  prep_gatW<<<(256 * 256 + 255) / 256, 256, 0, stream>>>(gat_W, Wtb);

  // 1. xp = x @ gat_W via MFMA (f32 read, bf16 convert in staging, bf16 xpb out)
  dim3 gX(4, (N + 63) / 64);
  gemm_xp_mfma<<<gX, 256, 0, stream>>>(x, Wtb, xpb, N);

  // 2. attention scores (bf16 xp)
  attn_scores_bf<<<(N + 3) / 4, 256, 0, stream>>>(xpb, att_src, att_dst, a_src, a_dst, N);

  // 3. CSR build (parallel 3-phase scan)
  hipMemsetAsync(deg, 0, (size_t)N * sizeof(int), stream);
  deg_count<<<(Et + 255) / 256, 256, 0, stream>>>(ei, E, Et, deg);
  bsum_kernel<<<NB, 256, 0, stream>>>(deg, N, bsum);
  bscan_kernel<<<1, 256, 0, stream>>>(bsum, NB);
  scan_apply<<<NB, 256, 0, stream>>>(deg, bsum, N, offs, cursor, dinv);
  csr_fill<<<(Et + 255) / 256, 256, 0, stream>>>(ei, E, Et, cursor, csr);

  // 4. fused GAT softmax + aggregation (single pass, no-max exp)
  gat_fused<<<(N + 3) / 4, 256, 0, stream>>>(offs, deg, csr, a_src, a_dst, xpb, gat_bias, h1, N);

  // 5. BN1 folded into GCN weights; xp2 (bf16) = h1 @ W2f + c2
  bn_stats<128><<<128, 256, 0, stream>>>(h1, N, P, PS);
  bn_reduce<128><<<1, 128, 0, stream>>>(P, PS, 128, N, bn1_g, bn1_b, svec, tvec);
  fold_gcn<<<1, 256, 0, stream>>>(gcn_W, svec, tvec, W2f, c2);
  dim3 gB((N + 63) / 64, 1);
  gemm64b<<<gB, 256, 0, stream>>>(h1, W2f, c2, xpb2, N, 64, 128);

  // 6. GCN aggregation (bf16 gather)
  gcn_aggregate_bf<<<(N + 3) / 4, 256, 0, stream>>>(offs, deg, csr, xpb2, dinv, gcn_bias, g2, N);

  // 7. BN2 folded into mu/lv
  bn_stats<64><<<128, 256, 0, stream>>>(g2, N, P, PS);
  bn_reduce<64><<<1, 64, 0, stream>>>(P, PS, 128, N, bn2_g, bn2_b, svec, tvec);
  fold_mulv<<<1, 256, 0, stream>>>(mu_W, mu_b, lv_W, lv_b, svec, tvec, Wmuf, cmu, Wlvf, clv);
  gemm64<<<gB, 256, 0, stream>>>(g2, Wmuf, cmu, mu, N, 64, 64);
  gemm64<<<gB, 256, 0, stream>>>(g2, Wlvf, clv, lv, N, 64, 64);

  // 8. z; res_z (bf16 directly)
  reparam<<<(N * 64 + 255) / 256, 256, 0, stream>>>(mu, lv, eps, zb, N * 64);
  gemm64b<<<gB, 256, 0, stream>>>(zb, res_W, res_b, rzb, N, 64, 64);

  // 9. MFMA decoder (128 edges/block, 8 waves)
  decoder_mfma<<<(E + 127) / 128, 512, 0, stream>>>(ei, E, rzb, W1t, dec_b1, dec_W2, dec_b2, recon);
}

// Round 10
// 574.498 us; speedup vs baseline: 1.3085x; 1.1619x over previous
//
#include <hip/hip_runtime.h>
#include <math.h>

constexpr int DIN = 256;
constexpr int HID = 128;
constexpr int LAT = 64;

typedef short bfrag __attribute__((ext_vector_type(8)));   // 8 bf16 (4 VGPRs)
typedef float f32x4 __attribute__((ext_vector_type(4)));

__device__ __forceinline__ float4 ld4(const float* p) { return *reinterpret_cast<const float4*>(p); }
__device__ __forceinline__ void st4(float* p, float4 v) { *reinterpret_cast<float4*>(p) = v; }

__device__ __forceinline__ unsigned short f2bf(float f) {
  unsigned int u = __float_as_uint(f);
  unsigned int r = (u + 0x7FFFu + ((u >> 16) & 1u)) >> 16;  // RNE
  return (unsigned short)r;
}

__device__ __forceinline__ float bf2f(unsigned short u) {
  return __uint_as_float(((unsigned int)u) << 16);
}

// ---------------- generic f32 GEMM: C[M,N] = A[M,K] @ B[K,N] (+ crow[N]) ----------------
__global__ __launch_bounds__(256) void gemm64(const float* __restrict__ A, const float* __restrict__ B,
                                              const float* __restrict__ crow, float* __restrict__ C,
                                              int M, int N, int K) {
  __shared__ float As[32][68];
  __shared__ float Bs[32][68];
  int t = threadIdx.x;
  int m0 = blockIdx.x * 64, n0 = blockIdx.y * 64;
  int tm = t & 15, tn = t >> 4;
  float acc[4][4];
#pragma unroll
  for (int i = 0; i < 4; i++)
#pragma unroll
    for (int j = 0; j < 4; j++) acc[i][j] = 0.f;

  for (int kt = 0; kt < K; kt += 32) {
#pragma unroll
    for (int i = 0; i < 2; ++i) {
      int f4 = t + i * 256;
      int m = f4 >> 3;
      int k4 = (f4 & 7) << 2;
      int gm = m0 + m;
      float4 v = make_float4(0.f, 0.f, 0.f, 0.f);
      if (gm < M) v = ld4(A + (size_t)gm * K + kt + k4);
      As[k4 + 0][m] = v.x; As[k4 + 1][m] = v.y; As[k4 + 2][m] = v.z; As[k4 + 3][m] = v.w;
    }
#pragma unroll
    for (int i = 0; i < 2; ++i) {
      int f4 = t + i * 256;
      int k = f4 >> 4;
      int n4 = (f4 & 15) << 2;
      float4 v = ld4(B + (size_t)(kt + k) * N + n0 + n4);
      st4(&Bs[k][n4], v);
    }
    __syncthreads();
#pragma unroll
    for (int k = 0; k < 32; ++k) {
      float4 a = ld4(&As[k][tm << 2]);
      float4 b = ld4(&Bs[k][tn << 2]);
      float av[4] = {a.x, a.y, a.z, a.w};
      float bv[4] = {b.x, b.y, b.z, b.w};
#pragma unroll
      for (int i = 0; i < 4; i++)
#pragma unroll
        for (int j = 0; j < 4; j++) acc[i][j] = fmaf(av[i], bv[j], acc[i][j]);
    }
    __syncthreads();
  }
#pragma unroll
  for (int i = 0; i < 4; ++i) {
    int gm = m0 + (tm << 2) + i;
    if (gm < M) {
      int nb = n0 + (tn << 2);
      float4 v = make_float4(acc[i][0], acc[i][1], acc[i][2], acc[i][3]);
      if (crow) { v.x += crow[nb]; v.y += crow[nb + 1]; v.z += crow[nb + 2]; v.w += crow[nb + 3]; }
      st4(C + (size_t)gm * N + nb, v);
    }
  }
}

// ---------------- f32 GEMM with bf16 output ----------------
__global__ __launch_bounds__(256) void gemm64b(const float* __restrict__ A, const float* __restrict__ B,
                                               const float* __restrict__ crow, unsigned short* __restrict__ Cb,
                                               int M, int N, int K) {
  __shared__ float As[32][68];
  __shared__ float Bs[32][68];
  int t = threadIdx.x;
  int m0 = blockIdx.x * 64, n0 = blockIdx.y * 64;
  int tm = t & 15, tn = t >> 4;
  float acc[4][4];
#pragma unroll
  for (int i = 0; i < 4; i++)
#pragma unroll
    for (int j = 0; j < 4; j++) acc[i][j] = 0.f;

  for (int kt = 0; kt < K; kt += 32) {
#pragma unroll
    for (int i = 0; i < 2; ++i) {
      int f4 = t + i * 256;
      int m = f4 >> 3;
      int k4 = (f4 & 7) << 2;
      int gm = m0 + m;
      float4 v = make_float4(0.f, 0.f, 0.f, 0.f);
      if (gm < M) v = ld4(A + (size_t)gm * K + kt + k4);
      As[k4 + 0][m] = v.x; As[k4 + 1][m] = v.y; As[k4 + 2][m] = v.z; As[k4 + 3][m] = v.w;
    }
#pragma unroll
    for (int i = 0; i < 2; ++i) {
      int f4 = t + i * 256;
      int k = f4 >> 4;
      int n4 = (f4 & 15) << 2;
      float4 v = ld4(B + (size_t)(kt + k) * N + n0 + n4);
      st4(&Bs[k][n4], v);
    }
    __syncthreads();
#pragma unroll
    for (int k = 0; k < 32; ++k) {
      float4 a = ld4(&As[k][tm << 2]);
      float4 b = ld4(&Bs[k][tn << 2]);
      float av[4] = {a.x, a.y, a.z, a.w};
      float bv[4] = {b.x, b.y, b.z, b.w};
#pragma unroll
      for (int i = 0; i < 4; i++)
#pragma unroll
        for (int j = 0; j < 4; j++) acc[i][j] = fmaf(av[i], bv[j], acc[i][j]);
    }
    __syncthreads();
  }
#pragma unroll
  for (int i = 0; i < 4; ++i) {
    int gm = m0 + (tm << 2) + i;
    if (gm < M) {
      int nb = n0 + (tn << 2);
      ushort4 o;
      o.x = f2bf(acc[i][0] + crow[nb]);
      o.y = f2bf(acc[i][1] + crow[nb + 1]);
      o.z = f2bf(acc[i][2] + crow[nb + 2]);
      o.w = f2bf(acc[i][3] + crow[nb + 3]);
      *(ushort4*)(Cb + (size_t)gm * N + nb) = o;
    }
  }
}

// ---------------- MFMA GEMM: xpb = x(f32) @ Wtb^T, bf16 out ----------------
__global__ __launch_bounds__(256) void gemm_xp_mfma(const float* __restrict__ xf,
                                                    const unsigned short* __restrict__ Wtb,
                                                    unsigned short* __restrict__ xpb, int M) {
  __shared__ unsigned short Als[64 * 256];
  __shared__ unsigned short Bls[64 * 256];
  int t = threadIdx.x;
  int wv = t >> 6, l = t & 63, lg = l >> 4, ll = l & 15;
  int cg = blockIdx.x;
  int rt = blockIdx.y;

  {
    int row = t >> 2, seg = t & 3;
    int gr = min(rt * 64 + row, M - 1);
    const float4* src = (const float4*)(xf + (size_t)gr * 256 + seg * 64);
    int swz = (row & 7) << 4;
#pragma unroll
    for (int c = 0; c < 8; ++c) {
      float4 a = src[2 * c], b = src[2 * c + 1];
      uint4 v;
      v.x = (unsigned)f2bf(a.x) | ((unsigned)f2bf(a.y) << 16);
      v.y = (unsigned)f2bf(a.z) | ((unsigned)f2bf(a.w) << 16);
      v.z = (unsigned)f2bf(b.x) | ((unsigned)f2bf(b.y) << 16);
      v.w = (unsigned)f2bf(b.z) | ((unsigned)f2bf(b.w) << 16);
      int bo = seg * 128 + c * 16;
      *(uint4*)((char*)Als + row * 512 + (bo ^ swz)) = v;
    }
  }
  {
    int col = t >> 2, seg = t & 3;
    const uint4* src = (const uint4*)(Wtb + (size_t)(cg * 64 + col) * 256 + seg * 64);
    int swz = (col & 7) << 4;
#pragma unroll
    for (int c = 0; c < 8; ++c) {
      int bo = seg * 128 + c * 16;
      *(uint4*)((char*)Bls + col * 512 + (bo ^ swz)) = src[c];
    }
  }
  __syncthreads();

  f32x4 acc[4];
#pragma unroll
  for (int i = 0; i < 4; ++i) acc[i] = (f32x4){0.f, 0.f, 0.f, 0.f};

#pragma unroll
  for (int kt = 0; kt < 8; ++kt) {
    int ar = wv * 16 + ll;
    bfrag af = *(const bfrag*)((char*)Als + ar * 512 + ((kt * 64 + lg * 16) ^ ((ar & 7) << 4)));
#pragma unroll
    for (int fn = 0; fn < 4; ++fn) {
      int bc = fn * 16 + ll;
      bfrag bf = *(const bfrag*)((char*)Bls + bc * 512 + ((kt * 64 + lg * 16) ^ ((bc & 7) << 4)));
      acc[fn] = __builtin_amdgcn_mfma_f32_16x16x32_bf16(af, bf, acc[fn], 0, 0, 0);
    }
  }

#pragma unroll
  for (int fn = 0; fn < 4; ++fn) {
#pragma unroll
    for (int r = 0; r < 4; ++r) {
      int row = rt * 64 + wv * 16 + lg * 4 + r;
      if (row < M) xpb[(size_t)row * 512 + cg * 64 + fn * 16 + ll] = f2bf(acc[fn][r]);
    }
  }
}

// ---------------- attention scores (bf16 xp) ----------------
__global__ __launch_bounds__(256) void attn_scores_bf(const unsigned short* __restrict__ xpb,
                                                      const float* __restrict__ att_src,
                                                      const float* __restrict__ att_dst,
                                                      float* __restrict__ a_src, float* __restrict__ a_dst, int N) {
  int wid = threadIdx.x >> 6, lane = threadIdx.x & 63;
  int n = blockIdx.x * 4 + wid;
  if (n >= N) return;
  int h = lane >> 5;
  int f4 = (lane & 31) << 2;
  ushort4 u = *(const ushort4*)(xpb + (size_t)n * 512 + lane * 4);
  float4 as = ld4(att_src + h * 128 + f4);
  float4 ad = ld4(att_dst + h * 128 + f4);
  float vx = bf2f(u.x), vy = bf2f(u.y), vz = bf2f(u.z), vw = bf2f(u.w);
  float ps = vx * as.x + vy * as.y + vz * as.z + vw * as.w;
  float pd = vx * ad.x + vy * ad.y + vz * ad.z + vw * ad.w;
#pragma unroll
  for (int m = 16; m >= 1; m >>= 1) { ps += __shfl_xor(ps, m); pd += __shfl_xor(pd, m); }
  if ((lane & 31) == 0) { a_src[n * 2 + h] = ps; a_dst[n * 2 + h] = pd; }
}

// ---------------- CSR build ----------------
__global__ void deg_count(const int* __restrict__ ei, int E, int Et, int* __restrict__ deg) {
  int i = blockIdx.x * blockDim.x + threadIdx.x;
  if (i >= Et) return;
  int d = (i < E) ? ei[E + i] : (i - E);
  atomicAdd(&deg[d], 1);
}

__global__ __launch_bounds__(256) void bsum_kernel(const int* __restrict__ deg, int N, int* __restrict__ bsum) {
  int t = threadIdx.x;
  int i = blockIdx.x * 256 + t;
  int v = (i < N) ? deg[i] : 0;
#pragma unroll
  for (int m = 32; m >= 1; m >>= 1) v += __shfl_xor(v, m);
  __shared__ int sh[4];
  if ((t & 63) == 0) sh[t >> 6] = v;
  __syncthreads();
  if (t == 0) bsum[blockIdx.x] = sh[0] + sh[1] + sh[2] + sh[3];
}

__global__ __launch_bounds__(256) void bscan_kernel(int* __restrict__ bsum, int B) {
  __shared__ int sh[256];
  int t = threadIdx.x;
  int v = (t < B) ? bsum[t] : 0;
  sh[t] = v;
  __syncthreads();
  for (int d = 1; d < 256; d <<= 1) {
    int x = (t >= d) ? sh[t - d] : 0;
    __syncthreads();
    sh[t] += x;
    __syncthreads();
  }
  if (t < B) bsum[t] = sh[t] - v;
}

__global__ __launch_bounds__(256) void scan_apply(const int* __restrict__ deg, const int* __restrict__ bsum, int N,
                                                  int* __restrict__ offs, int* __restrict__ cursor,
                                                  float* __restrict__ dinv) {
  int t = threadIdx.x;
  int i = blockIdx.x * 256 + t;
  int v = (i < N) ? deg[i] : 0;
  __shared__ int sh[256];
  sh[t] = v;
  __syncthreads();
  for (int d = 1; d < 256; d <<= 1) {
    int x = (t >= d) ? sh[t - d] : 0;
    __syncthreads();
    sh[t] += x;
    __syncthreads();
  }
  if (i < N) {
    int off = bsum[blockIdx.x] + sh[t] - v;
    offs[i] = off;
    cursor[i] = off;
    dinv[i] = rsqrtf((float)v);   // deg >= 1 (self-loop)
  }
}

__global__ void csr_fill(const int* __restrict__ ei, int E, int Et, int* __restrict__ cursor, int* __restrict__ csr) {
  int i = blockIdx.x * blockDim.x + threadIdx.x;
  if (i >= Et) return;
  int s, d;
  if (i < E) { s = ei[i]; d = ei[E + i]; } else { s = i - E; d = i - E; }
  int pos = atomicAdd(&cursor[d], 1);
  csr[pos] = s;
}

// ---------------- FUSED GAT, no-max softmax, 4-way unrolled gather (wave per node) ----------------
// 4 CSR entries loaded up-front (independent) -> 4 score loads + 4 row gathers in
// flight simultaneously -> 4x memory-level parallelism vs the serial dependent chain.
__global__ __launch_bounds__(256) void gat_fused(const int* __restrict__ offs, const int* __restrict__ deg,
                                                 const int* __restrict__ csr, const float* __restrict__ a_src,
                                                 const float* __restrict__ a_dst,
                                                 const unsigned short* __restrict__ xpb,
                                                 const float* __restrict__ bias,
                                                 float* __restrict__ h1, int N) {
  int wid = threadIdx.x >> 6, lane = threadIdx.x & 63;
  int n = blockIdx.x * 4 + wid;
  if (n >= N) return;
  int off = offs[n], dg = deg[n];
  float ad0 = a_dst[n * 2], ad1 = a_dst[n * 2 + 1];
  const float2* as2 = (const float2*)a_src;

  float4 acc = make_float4(0.f, 0.f, 0.f, 0.f);
  float s0 = 0.f, s1 = 0.f;
  bool h0 = lane < 32;

#define GAT_STEP(aa, uu)                                         \
  {                                                              \
    float e0 = (aa).x + ad0; e0 = e0 >= 0.f ? e0 : 0.2f * e0;    \
    float e1 = (aa).y + ad1; e1 = e1 >= 0.f ? e1 : 0.2f * e1;    \
    float x0 = __expf(e0), x1 = __expf(e1);                      \
    s0 += x0; s1 += x1;                                          \
    float xa = h0 ? x0 : x1;                                     \
    acc.x = fmaf(bf2f((uu).x), xa, acc.x);                       \
    acc.y = fmaf(bf2f((uu).y), xa, acc.y);                       \
    acc.z = fmaf(bf2f((uu).z), xa, acc.z);                       \
    acc.w = fmaf(bf2f((uu).w), xa, acc.w);                       \
  }

  int k = 0;
  for (; k + 4 <= dg; k += 4) {
    int sa = csr[off + k], sb = csr[off + k + 1], sc = csr[off + k + 2], sd = csr[off + k + 3];
    float2 aa = as2[sa], ab = as2[sb], ac = as2[sc], ad = as2[sd];
    ushort4 ua = ((const ushort4*)(xpb + (size_t)sa * 512))[lane];
    ushort4 ub = ((const ushort4*)(xpb + (size_t)sb * 512))[lane];
    ushort4 uc = ((const ushort4*)(xpb + (size_t)sc * 512))[lane];
    ushort4 ud = ((const ushort4*)(xpb + (size_t)sd * 512))[lane];
    GAT_STEP(aa, ua); GAT_STEP(ab, ub); GAT_STEP(ac, uc); GAT_STEP(ad, ud);
  }
  for (; k < dg; ++k) {
    int s = csr[off + k];
    float2 a = as2[s];
    ushort4 u = ((const ushort4*)(xpb + (size_t)s * 512))[lane];
    GAT_STEP(a, u);
  }
#undef GAT_STEP

  float r = h0 ? (1.f / s0) : (1.f / s1);
  acc.x *= r; acc.y *= r; acc.z *= r; acc.w *= r;

  float ox = __shfl_down(acc.x, 32);
  float oy = __shfl_down(acc.y, 32);
  float oz = __shfl_down(acc.z, 32);
  float ow = __shfl_down(acc.w, 32);
  if (h0) {
    int f4 = lane << 2;
    float4 b = ld4(bias + f4);
    float4 o;
    o.x = fmaxf(0.f, (acc.x + ox) * 0.5f + b.x);
    o.y = fmaxf(0.f, (acc.y + oy) * 0.5f + b.y);
    o.z = fmaxf(0.f, (acc.z + oz) * 0.5f + b.z);
    o.w = fmaxf(0.f, (acc.w + ow) * 0.5f + b.w);
    st4(h1 + (size_t)n * 128 + f4, o);
  }
}

// ---------------- BatchNorm stats ----------------
template <int C>
__global__ __launch_bounds__(256) void bn_stats(const float* __restrict__ h, int N, float* __restrict__ P,
                                                float* __restrict__ PS) {
  constexpr int R = 256 / C;
  __shared__ float sh[256], sh2[256];
  int t = threadIdx.x;
  int c = t % C, r = t / C;
  float s = 0.f, ss = 0.f;
  for (int n = blockIdx.x * R + r; n < N; n += gridDim.x * R) {
    float v = h[(size_t)n * C + c];
    s += v; ss += v * v;
  }
  sh[t] = s; sh2[t] = ss;
  __syncthreads();
  if (r == 0) {
#pragma unroll
    for (int i = 1; i < R; ++i) { s += sh[i * C + c]; ss += sh2[i * C + c]; }
    P[blockIdx.x * C + c] = s;
    PS[blockIdx.x * C + c] = ss;
  }
}

// ---------------- fused BN1 reduce + fold into GCN weights (1 block) ----------------
__global__ __launch_bounds__(256) void bn_fold_gcn(const float* __restrict__ P, const float* __restrict__ PS,
                                                   int G, int N, const float* __restrict__ g,
                                                   const float* __restrict__ b, const float* __restrict__ W,
                                                   float* __restrict__ Wf, float* __restrict__ cvec) {
  __shared__ float ssv[128], stv[128];
  int t = threadIdx.x;
  if (t < 128) {
    float s = 0.f, ss = 0.f;
    for (int i = 0; i < G; ++i) { s += P[i * 128 + t]; ss += PS[i * 128 + t]; }
    float mean = s / N;
    float var = ss / N - mean * mean;
    float sc = g[t] * rsqrtf(var + 1e-5f);
    ssv[t] = sc;
    stv[t] = b[t] - mean * sc;
  }
  __syncthreads();
  for (int i = t; i < 128 * 64; i += 256) {
    int k = i >> 6;
    Wf[i] = ssv[k] * W[i];
  }
  if (t < 64) {
    float c = 0.f;
    for (int k = 0; k < 128; ++k) c += stv[k] * W[k * 64 + t];
    cvec[t] = c;
  }
}

// ---------------- fused BN2 reduce + fold into mu/lv weights (1 block) ----------------
__global__ __launch_bounds__(256) void bn_fold_mulv(const float* __restrict__ P, const float* __restrict__ PS,
                                                    int G, int N, const float* __restrict__ g,
                                                    const float* __restrict__ b,
                                                    const float* __restrict__ Wmu, const float* __restrict__ mub,
                                                    const float* __restrict__ Wlv, const float* __restrict__ lvb,
                                                    float* __restrict__ Wmuf, float* __restrict__ cmu,
                                                    float* __restrict__ Wlvf, float* __restrict__ clv) {
  __shared__ float ssv[64], stv[64];
  int t = threadIdx.x;
  if (t < 64) {
    float s = 0.f, ss = 0.f;
    for (int i = 0; i < G; ++i) { s += P[i * 64 + t]; ss += PS[i * 64 + t]; }
    float mean = s / N;
    float var = ss / N - mean * mean;
    float sc = g[t] * rsqrtf(var + 1e-5f);
    ssv[t] = sc;
    stv[t] = b[t] - mean * sc;
  }
  __syncthreads();
  for (int i = t; i < 4096; i += 256) {
    int k = i >> 6;
    Wmuf[i] = ssv[k] * Wmu[i];
    Wlvf[i] = ssv[k] * Wlv[i];
  }
  if (t < 64) {
    float cm = mub[t], cl = lvb[t];
    for (int k = 0; k < 64; ++k) { cm += stv[k] * Wmu[k * 64 + t]; cl += stv[k] * Wlv[k * 64 + t]; }
    cmu[t] = cm; clv[t] = cl;
  }
}

// ---------------- GCN aggregation (bf16 gather, 4-way unrolled) ----------------
__global__ __launch_bounds__(256) void gcn_aggregate_bf(const int* __restrict__ offs, const int* __restrict__ deg,
                                                        const int* __restrict__ csr,
                                                        const unsigned short* __restrict__ xpb2,
                                                        const float* __restrict__ dinv, const float* __restrict__ bias,
                                                        float* __restrict__ g2, int N) {
  int wid = threadIdx.x >> 6, lane = threadIdx.x & 63;
  int n = blockIdx.x * 4 + wid;
  if (n >= N) return;
  int off = offs[n], dg = deg[n];
  float acc = 0.f;
  int k = 0;
  for (; k + 4 <= dg; k += 4) {
    int sa = csr[off + k], sb = csr[off + k + 1], sc = csr[off + k + 2], sd = csr[off + k + 3];
    float da = dinv[sa], db = dinv[sb], dc = dinv[sc], dd = dinv[sd];
    unsigned short ua = xpb2[(size_t)sa * 64 + lane];
    unsigned short ub = xpb2[(size_t)sb * 64 + lane];
    unsigned short uc = xpb2[(size_t)sc * 64 + lane];
    unsigned short ud = xpb2[(size_t)sd * 64 + lane];
    acc = fmaf(bf2f(ua), da, acc);
    acc = fmaf(bf2f(ub), db, acc);
    acc = fmaf(bf2f(uc), dc, acc);
    acc = fmaf(bf2f(ud), dd, acc);
  }
  for (; k < dg; ++k) {
    int s = csr[off + k];
    acc = fmaf(bf2f(xpb2[(size_t)s * 64 + lane]), dinv[s], acc);
  }
  float v = acc * dinv[n] + bias[lane];
  g2[(size_t)n * 64 + lane] = fmaxf(v, 0.f);
}

// ---------------- reparameterize ----------------
__global__ void reparam(const float* __restrict__ mu, const float* __restrict__ lv,
                        const float* __restrict__ eps, float* __restrict__ z, int total) {
  int i = blockIdx.x * blockDim.x + threadIdx.x;
  if (i >= total) return;
  z[i] = fmaf(eps[i], __expf(0.5f * lv[i]), mu[i]);
}

// ---------------- prep gat_W -> transposed bf16 Wtb[col][k] ----------------
__global__ void prep_gatW(const float* __restrict__ W, unsigned short* __restrict__ Wtb) {
  int i = blockIdx.x * blockDim.x + threadIdx.x;
  if (i >= 256 * 256) return;
  int col = i >> 8, k = i & 255;
  Wtb[i] = f2bf(W[k * 256 + col]);
}

// ---------------- prep W1 → bf16 decoder layout [4 kt][256 j][40 kp] (padded) ----------------
__global__ void prep_W1(const float* __restrict__ W1, unsigned short* __restrict__ W1t) {
  int i = blockIdx.x * blockDim.x + threadIdx.x;
  if (i >= 4 * 256 * 40) return;
  int kt = i / 10240;
  int rem = i - kt * 10240;
  int j = rem / 40;
  int kp = rem - j * 40;
  float v = (kp < 32) ? W1[(size_t)(kt * 32 + kp) * 256 + j] : 0.f;
  W1t[i] = f2bf(v);
}

// ---------------- MFMA decoder (round-7 best: 64 edges, 4 waves, B per-kt in LDS) ----------------
__global__ __launch_bounds__(256) void decoder_mfma(const int* __restrict__ ei, int E,
                                                    const unsigned short* __restrict__ rzb,
                                                    const unsigned short* __restrict__ W1t,
                                                    const float* __restrict__ b1, const float* __restrict__ W2,
                                                    const float* __restrict__ b2, float* __restrict__ recon) {
  __shared__ unsigned short Als[64 * 128];   // 16 KB
  __shared__ unsigned short Bls[256 * 40];   // 20 KB
  __shared__ float red[4][64];
  int t = threadIdx.x;
  int wv = t >> 6, l = t & 63;
  int lg = l >> 4, ll = l & 15;
  int e0 = blockIdx.x * 64;

  {
    int e = t >> 2;
    int part = (t >> 1) & 1;
    int half = t & 1;
    int eg = e0 + e;
    if (eg >= E) eg = E - 1;
    int r = (part == 0) ? ei[eg] : ei[E + eg];
    const uint4* gsrc = (const uint4*)(rzb + (size_t)r * 64 + half * 32);
    int bo0 = part * 128 + half * 64;
    int swz = (e & 7) << 4;
#pragma unroll
    for (int c = 0; c < 4; ++c) {
      uint4 v = gsrc[c];
      int bo = bo0 + c * 16;
      *(uint4*)&Als[e * 128 + ((bo ^ swz) >> 1)] = v;
    }
  }

  f32x4 acc[4][4];
#pragma unroll
  for (int a = 0; a < 4; ++a)
#pragma unroll
    for (int b = 0; b < 4; ++b) acc[a][b] = (f32x4){0.f, 0.f, 0.f, 0.f};

  for (int kt = 0; kt < 4; ++kt) {
    __syncthreads();
    {
      const uint4* gsrc = (const uint4*)(W1t + kt * 10240);
      uint4* ldst = (uint4*)Bls;
#pragma unroll
      for (int i = 0; i < 5; ++i) ldst[t + i * 256] = gsrc[t + i * 256];
    }
    __syncthreads();

    bfrag af[4];
#pragma unroll
    for (int fm = 0; fm < 4; ++fm) {
      int e = fm * 16 + ll;
      int bo = kt * 64 + lg * 16;
      af[fm] = *(const bfrag*)&Als[e * 128 + ((bo ^ ((e & 7) << 4)) >> 1)];
    }
#pragma unroll
    for (int fn = 0; fn < 4; ++fn) {
      int j = wv * 64 + fn * 16 + ll;
      bfrag bf = *(const bfrag*)&Bls[j * 40 + lg * 8];
#pragma unroll
      for (int fm = 0; fm < 4; ++fm)
        acc[fm][fn] = __builtin_amdgcn_mfma_f32_16x16x32_bf16(af[fm], bf, acc[fm][fn], 0, 0, 0);
    }
  }

  float bj[4], wj[4];
#pragma unroll
  for (int fn = 0; fn < 4; ++fn) {
    int j = wv * 64 + fn * 16 + ll;
    bj[fn] = b1[j];
    wj[fn] = W2[j];
  }
#pragma unroll
  for (int fm = 0; fm < 4; ++fm) {
    float pr[4] = {0.f, 0.f, 0.f, 0.f};
#pragma unroll
    for (int fn = 0; fn < 4; ++fn) {
#pragma unroll
      for (int r = 0; r < 4; ++r)
        pr[r] = fmaf(fmaxf(acc[fm][fn][r] + bj[fn], 0.f), wj[fn], pr[r]);
    }
#pragma unroll
    for (int m = 8; m >= 1; m >>= 1) {
#pragma unroll
      for (int r = 0; r < 4; ++r) pr[r] += __shfl_xor(pr[r], m);
    }
    if (ll == 0) {
#pragma unroll
      for (int r = 0; r < 4; ++r) red[wv][fm * 16 + lg * 4 + r] = pr[r];
    }
  }
  __syncthreads();
  if (t < 64) {
    int eg = e0 + t;
    if (eg < E) recon[eg] = red[0][t] + red[1][t] + red[2][t] + red[3][t] + b2[0];
  }
}

extern "C" void kernel_launch(void* const* d_in, const int* in_sizes, int n_in,
                              void* d_out, int out_size, void* d_ws, size_t ws_size,
                              hipStream_t stream) {
  const float* x = (const float*)d_in[0];
  const int* ei = (const int*)d_in[1];
  const float* gat_W = (const float*)d_in[2];
  const float* att_src = (const float*)d_in[3];
  const float* att_dst = (const float*)d_in[4];
  const float* gat_bias = (const float*)d_in[5];
  const float* bn1_g = (const float*)d_in[6];
  const float* bn1_b = (const float*)d_in[7];
  const float* gcn_W = (const float*)d_in[8];
  const float* gcn_bias = (const float*)d_in[9];
  const float* bn2_g = (const float*)d_in[10];
  const float* bn2_b = (const float*)d_in[11];
  const float* mu_W = (const float*)d_in[12];
  const float* mu_b = (const float*)d_in[13];
  const float* lv_W = (const float*)d_in[14];
  const float* lv_b = (const float*)d_in[15];
  const float* res_W = (const float*)d_in[16];
  const float* res_b = (const float*)d_in[17];
  const float* dec_W1 = (const float*)d_in[18];
  const float* dec_b1 = (const float*)d_in[19];
  const float* dec_W2 = (const float*)d_in[20];
  const float* dec_b2 = (const float*)d_in[21];
  const float* eps = (const float*)d_in[22];

  int N = in_sizes[0] / DIN;   // 50000
  int E = in_sizes[1] / 2;     // 800000
  int Et = E + N;
  int NB = (N + 255) / 256;    // scan chunks (<= 256)

  float* ws = (float*)d_ws;
  size_t off = 0;
  float* xp = ws; off += (size_t)N * 256;
  unsigned short* xpb = (unsigned short*)xp;    // bf16 xp rows, stride 512 ushorts
  unsigned short* xpb2 = (unsigned short*)xp;   // bf16 xp2 [N,64] (xpb dead by then)
  float* g2 = xp + (size_t)N * 64;
  float* zb = xp + (size_t)N * 128;
  float* rz = xp + (size_t)N * 192;
  unsigned short* rzb = (unsigned short*)rz;    // bf16 res_z [N,64], written by gemm64b
  float* h1 = ws + off; off += (size_t)N * 128;
  float* a_src = ws + off; off += (size_t)2 * N;
  float* a_dst = ws + off; off += (size_t)2 * N;
  float* dinv = ws + off; off += N;
  float* P = ws + off; off += 128 * 128;
  float* PS = ws + off; off += 128 * 128;
  float* W2f = ws + off; off += 128 * 64;
  float* c2 = ws + off; off += 64;
  float* Wmuf = ws + off; off += 64 * 64;
  float* cmu = ws + off; off += 64;
  float* Wlvf = ws + off; off += 64 * 64;
  float* clv = ws + off; off += 64;
  unsigned short* W1t = (unsigned short*)(ws + off); off += 20480;   // 4*256*40 bf16
  unsigned short* Wtb = (unsigned short*)(ws + off); off += 32768;   // 256*256 bf16
  int* deg = (int*)(ws + off); off += N;
  int* offs = (int*)(ws + off); off += N;
  int* cursor = (int*)(ws + off); off += N;
  int* bsum = (int*)(ws + off); off += 256;
  int* csr = (int*)(ws + off); off += Et;

  float* recon = (float*)d_out;
  float* mu = recon + E;
  float* lv = mu + (size_t)N * LAT;

  // 0. weight preps (independent, do early)
  prep_W1<<<(4 * 256 * 40 + 255) / 256, 256, 0, stream>>>(dec_W1, W1t);
  prep_gatW<<<(256 * 256 + 255) / 256, 256, 0, stream>>>(gat_W, Wtb);

  // 1. xp = x @ gat_W via MFMA (f32 read, bf16 convert in staging, bf16 xpb out)
  dim3 gX(4, (N + 63) / 64);
  gemm_xp_mfma<<<gX, 256, 0, stream>>>(x, Wtb, xpb, N);

  // 2. attention scores (bf16 xp)
  attn_scores_bf<<<(N + 3) / 4, 256, 0, stream>>>(xpb, att_src, att_dst, a_src, a_dst, N);

  // 3. CSR build (parallel 3-phase scan)
  hipMemsetAsync(deg, 0, (size_t)N * sizeof(int), stream);
  deg_count<<<(Et + 255) / 256, 256, 0, stream>>>(ei, E, Et, deg);
  bsum_kernel<<<NB, 256, 0, stream>>>(deg, N, bsum);
  bscan_kernel<<<1, 256, 0, stream>>>(bsum, NB);
  scan_apply<<<NB, 256, 0, stream>>>(deg, bsum, N, offs, cursor, dinv);
  csr_fill<<<(Et + 255) / 256, 256, 0, stream>>>(ei, E, Et, cursor, csr);

  // 4. fused GAT softmax + aggregation (single pass, no-max exp, 4-way MLP unroll)
  gat_fused<<<(N + 3) / 4, 256, 0, stream>>>(offs, deg, csr, a_src, a_dst, xpb, gat_bias, h1, N);

  // 5. BN1 reduce+fold fused; xp2 (bf16) = h1 @ W2f + c2
  bn_stats<128><<<128, 256, 0, stream>>>(h1, N, P, PS);
  bn_fold_gcn<<<1, 256, 0, stream>>>(P, PS, 128, N, bn1_g, bn1_b, gcn_W, W2f, c2);
  dim3 gB((N + 63) / 64, 1);
  gemm64b<<<gB, 256, 0, stream>>>(h1, W2f, c2, xpb2, N, 64, 128);

  // 6. GCN aggregation (bf16 gather, 4-way MLP unroll)
  gcn_aggregate_bf<<<(N + 3) / 4, 256, 0, stream>>>(offs, deg, csr, xpb2, dinv, gcn_bias, g2, N);

  // 7. BN2 reduce+fold fused; mu/lv GEMMs
  bn_stats<64><<<128, 256, 0, stream>>>(g2, N, P, PS);
  bn_fold_mulv<<<1, 256, 0, stream>>>(P, PS, 128, N, bn2_g, bn2_b, mu_W, mu_b, lv_W, lv_b,
                                      Wmuf, cmu, Wlvf, clv);
  gemm64<<<gB, 256, 0, stream>>>(g2, Wmuf, cmu, mu, N, 64, 64);
  gemm64<<<gB, 256, 0, stream>>>(g2, Wlvf, clv, lv, N, 64, 64);

  // 8. z; res_z (bf16 directly)
  reparam<<<(N * 64 + 255) / 256, 256, 0, stream>>>(mu, lv, eps, zb, N * 64);
  gemm64b<<<gB, 256, 0, stream>>>(zb, res_W, res_b, rzb, N, 64, 64);

  // 9. MFMA decoder (64 edges/block — best measured variant)
  decoder_mfma<<<(E + 63) / 64, 256, 0, stream>>>(ei, E, rzb, W1t, dec_b1, dec_W2, dec_b2, recon);
}

// Round 11
// 562.319 us; speedup vs baseline: 1.3368x; 1.0217x over previous
//
#include <hip/hip_runtime.h>
#include <math.h>

constexpr int DIN = 256;
constexpr int HID = 128;
constexpr int LAT = 64;

typedef short bfrag __attribute__((ext_vector_type(8)));   // 8 bf16 (4 VGPRs)
typedef float f32x4 __attribute__((ext_vector_type(4)));

__device__ __forceinline__ float4 ld4(const float* p) { return *reinterpret_cast<const float4*>(p); }
__device__ __forceinline__ void st4(float* p, float4 v) { *reinterpret_cast<float4*>(p) = v; }

__device__ __forceinline__ unsigned short f2bf(float f) {
  unsigned int u = __float_as_uint(f);
  unsigned int r = (u + 0x7FFFu + ((u >> 16) & 1u)) >> 16;  // RNE
  return (unsigned short)r;
}

__device__ __forceinline__ float bf2f(unsigned short u) {
  return __uint_as_float(((unsigned int)u) << 16);
}

// ---------------- f32 GEMM with bf16 output: Cb[M,N](bf16) = A[M,K] @ B[K,N] + crow ----------------
__global__ __launch_bounds__(256) void gemm64b(const float* __restrict__ A, const float* __restrict__ B,
                                               const float* __restrict__ crow, unsigned short* __restrict__ Cb,
                                               int M, int N, int K) {
  __shared__ float As[32][68];
  __shared__ float Bs[32][68];
  int t = threadIdx.x;
  int m0 = blockIdx.x * 64, n0 = blockIdx.y * 64;
  int tm = t & 15, tn = t >> 4;
  float acc[4][4];
#pragma unroll
  for (int i = 0; i < 4; i++)
#pragma unroll
    for (int j = 0; j < 4; j++) acc[i][j] = 0.f;

  for (int kt = 0; kt < K; kt += 32) {
#pragma unroll
    for (int i = 0; i < 2; ++i) {
      int f4 = t + i * 256;
      int m = f4 >> 3;
      int k4 = (f4 & 7) << 2;
      int gm = m0 + m;
      float4 v = make_float4(0.f, 0.f, 0.f, 0.f);
      if (gm < M) v = ld4(A + (size_t)gm * K + kt + k4);
      As[k4 + 0][m] = v.x; As[k4 + 1][m] = v.y; As[k4 + 2][m] = v.z; As[k4 + 3][m] = v.w;
    }
#pragma unroll
    for (int i = 0; i < 2; ++i) {
      int f4 = t + i * 256;
      int k = f4 >> 4;
      int n4 = (f4 & 15) << 2;
      float4 v = ld4(B + (size_t)(kt + k) * N + n0 + n4);
      st4(&Bs[k][n4], v);
    }
    __syncthreads();
#pragma unroll
    for (int k = 0; k < 32; ++k) {
      float4 a = ld4(&As[k][tm << 2]);
      float4 b = ld4(&Bs[k][tn << 2]);
      float av[4] = {a.x, a.y, a.z, a.w};
      float bv[4] = {b.x, b.y, b.z, b.w};
#pragma unroll
      for (int i = 0; i < 4; i++)
#pragma unroll
        for (int j = 0; j < 4; j++) acc[i][j] = fmaf(av[i], bv[j], acc[i][j]);
    }
    __syncthreads();
  }
#pragma unroll
  for (int i = 0; i < 4; ++i) {
    int gm = m0 + (tm << 2) + i;
    if (gm < M) {
      int nb = n0 + (tn << 2);
      ushort4 o;
      o.x = f2bf(acc[i][0] + crow[nb]);
      o.y = f2bf(acc[i][1] + crow[nb + 1]);
      o.z = f2bf(acc[i][2] + crow[nb + 2]);
      o.w = f2bf(acc[i][3] + crow[nb + 3]);
      *(ushort4*)(Cb + (size_t)gm * N + nb) = o;
    }
  }
}

// ---------------- MFMA GEMM: xpb = x(f32) @ Wtb^T, bf16 out; attn scores fused in epilogue ----------------
// Block (cg, rt): cols [cg*64, cg*64+64), rows [rt*64, ...). h = cg>>1 (cols 0-127 -> head 0).
// Epilogue computes partial <xp_row, att_src[h]> over the block's 64 cols and atomicAdds
// into a_src/a_dst (pre-zeroed).
__global__ __launch_bounds__(256) void gemm_xp_mfma(const float* __restrict__ xf,
                                                    const unsigned short* __restrict__ Wtb,
                                                    const float* __restrict__ att_src,
                                                    const float* __restrict__ att_dst,
                                                    unsigned short* __restrict__ xpb,
                                                    float* __restrict__ a_src, float* __restrict__ a_dst, int M) {
  __shared__ unsigned short Als[64 * 256];
  __shared__ unsigned short Bls[64 * 256];
  int t = threadIdx.x;
  int wv = t >> 6, l = t & 63, lg = l >> 4, ll = l & 15;
  int cg = blockIdx.x;
  int rt = blockIdx.y;

  {
    int row = t >> 2, seg = t & 3;
    int gr = min(rt * 64 + row, M - 1);
    const float4* src = (const float4*)(xf + (size_t)gr * 256 + seg * 64);
    int swz = (row & 7) << 4;
#pragma unroll
    for (int c = 0; c < 8; ++c) {
      float4 a = src[2 * c], b = src[2 * c + 1];
      uint4 v;
      v.x = (unsigned)f2bf(a.x) | ((unsigned)f2bf(a.y) << 16);
      v.y = (unsigned)f2bf(a.z) | ((unsigned)f2bf(a.w) << 16);
      v.z = (unsigned)f2bf(b.x) | ((unsigned)f2bf(b.y) << 16);
      v.w = (unsigned)f2bf(b.z) | ((unsigned)f2bf(b.w) << 16);
      int bo = seg * 128 + c * 16;
      *(uint4*)((char*)Als + row * 512 + (bo ^ swz)) = v;
    }
  }
  {
    int col = t >> 2, seg = t & 3;
    const uint4* src = (const uint4*)(Wtb + (size_t)(cg * 64 + col) * 256 + seg * 64);
    int swz = (col & 7) << 4;
#pragma unroll
    for (int c = 0; c < 8; ++c) {
      int bo = seg * 128 + c * 16;
      *(uint4*)((char*)Bls + col * 512 + (bo ^ swz)) = src[c];
    }
  }
  __syncthreads();

  f32x4 acc[4];
#pragma unroll
  for (int i = 0; i < 4; ++i) acc[i] = (f32x4){0.f, 0.f, 0.f, 0.f};

#pragma unroll
  for (int kt = 0; kt < 8; ++kt) {
    int ar = wv * 16 + ll;
    bfrag af = *(const bfrag*)((char*)Als + ar * 512 + ((kt * 64 + lg * 16) ^ ((ar & 7) << 4)));
#pragma unroll
    for (int fn = 0; fn < 4; ++fn) {
      int bc = fn * 16 + ll;
      bfrag bf = *(const bfrag*)((char*)Bls + bc * 512 + ((kt * 64 + lg * 16) ^ ((bc & 7) << 4)));
      acc[fn] = __builtin_amdgcn_mfma_f32_16x16x32_bf16(af, bf, acc[fn], 0, 0, 0);
    }
  }

#pragma unroll
  for (int fn = 0; fn < 4; ++fn) {
#pragma unroll
    for (int r = 0; r < 4; ++r) {
      int row = rt * 64 + wv * 16 + lg * 4 + r;
      if (row < M) xpb[(size_t)row * 512 + cg * 64 + fn * 16 + ll] = f2bf(acc[fn][r]);
    }
  }

  // ---- fused attention-score partials ----
  int h = cg >> 1;
  int c0 = (cg & 1) * 64;
  float asv[4], adv[4];
#pragma unroll
  for (int fn = 0; fn < 4; ++fn) {
    asv[fn] = att_src[h * 128 + c0 + fn * 16 + ll];
    adv[fn] = att_dst[h * 128 + c0 + fn * 16 + ll];
  }
  float ps[4] = {0.f, 0.f, 0.f, 0.f}, pd[4] = {0.f, 0.f, 0.f, 0.f};
#pragma unroll
  for (int fn = 0; fn < 4; ++fn)
#pragma unroll
    for (int r = 0; r < 4; ++r) {
      ps[r] = fmaf(acc[fn][r], asv[fn], ps[r]);
      pd[r] = fmaf(acc[fn][r], adv[fn], pd[r]);
    }
#pragma unroll
  for (int m = 8; m >= 1; m >>= 1) {
#pragma unroll
    for (int r = 0; r < 4; ++r) { ps[r] += __shfl_xor(ps[r], m); pd[r] += __shfl_xor(pd[r], m); }
  }
  if (ll == 0) {
#pragma unroll
    for (int r = 0; r < 4; ++r) {
      int row = rt * 64 + wv * 16 + lg * 4 + r;
      if (row < M) {
        atomicAdd(&a_src[row * 2 + h], ps[r]);
        atomicAdd(&a_dst[row * 2 + h], pd[r]);
      }
    }
  }
}

// ---------------- CSR build ----------------
__global__ void deg_count(const int* __restrict__ ei, int E, int Et, int* __restrict__ deg) {
  int i = blockIdx.x * blockDim.x + threadIdx.x;
  if (i >= Et) return;
  int d = (i < E) ? ei[E + i] : (i - E);
  atomicAdd(&deg[d], 1);
}

__global__ __launch_bounds__(256) void bsum_kernel(const int* __restrict__ deg, int N, int* __restrict__ bsum) {
  int t = threadIdx.x;
  int i = blockIdx.x * 256 + t;
  int v = (i < N) ? deg[i] : 0;
#pragma unroll
  for (int m = 32; m >= 1; m >>= 1) v += __shfl_xor(v, m);
  __shared__ int sh[4];
  if ((t & 63) == 0) sh[t >> 6] = v;
  __syncthreads();
  if (t == 0) bsum[blockIdx.x] = sh[0] + sh[1] + sh[2] + sh[3];
}

__global__ __launch_bounds__(256) void bscan_kernel(int* __restrict__ bsum, int B) {
  __shared__ int sh[256];
  int t = threadIdx.x;
  int v = (t < B) ? bsum[t] : 0;
  sh[t] = v;
  __syncthreads();
  for (int d = 1; d < 256; d <<= 1) {
    int x = (t >= d) ? sh[t - d] : 0;
    __syncthreads();
    sh[t] += x;
    __syncthreads();
  }
  if (t < B) bsum[t] = sh[t] - v;
}

__global__ __launch_bounds__(256) void scan_apply(const int* __restrict__ deg, const int* __restrict__ bsum, int N,
                                                  int* __restrict__ offs, int* __restrict__ cursor,
                                                  float* __restrict__ dinv) {
  int t = threadIdx.x;
  int i = blockIdx.x * 256 + t;
  int v = (i < N) ? deg[i] : 0;
  __shared__ int sh[256];
  sh[t] = v;
  __syncthreads();
  for (int d = 1; d < 256; d <<= 1) {
    int x = (t >= d) ? sh[t - d] : 0;
    __syncthreads();
    sh[t] += x;
    __syncthreads();
  }
  if (i < N) {
    int off = bsum[blockIdx.x] + sh[t] - v;
    offs[i] = off;
    cursor[i] = off;
    dinv[i] = rsqrtf((float)v);   // deg >= 1 (self-loop)
  }
}

__global__ void csr_fill(const int* __restrict__ ei, int E, int Et, int* __restrict__ cursor, int* __restrict__ csr) {
  int i = blockIdx.x * blockDim.x + threadIdx.x;
  if (i >= Et) return;
  int s, d;
  if (i < E) { s = ei[i]; d = ei[E + i]; } else { s = i - E; d = i - E; }
  int pos = atomicAdd(&cursor[d], 1);
  csr[pos] = s;
}

// ---------------- FUSED GAT, no-max softmax, 8-way unrolled gather (wave per node) ----------------
__global__ __launch_bounds__(256) void gat_fused(const int* __restrict__ offs, const int* __restrict__ deg,
                                                 const int* __restrict__ csr, const float* __restrict__ a_src,
                                                 const float* __restrict__ a_dst,
                                                 const unsigned short* __restrict__ xpb,
                                                 const float* __restrict__ bias,
                                                 float* __restrict__ h1, int N) {
  int wid = threadIdx.x >> 6, lane = threadIdx.x & 63;
  int n = blockIdx.x * 4 + wid;
  if (n >= N) return;
  int off = offs[n], dg = deg[n];
  float ad0 = a_dst[n * 2], ad1 = a_dst[n * 2 + 1];
  const float2* as2 = (const float2*)a_src;

  float4 acc = make_float4(0.f, 0.f, 0.f, 0.f);
  float s0 = 0.f, s1 = 0.f;
  bool h0 = lane < 32;

#define GAT_STEP(aa, uu)                                         \
  {                                                              \
    float e0 = (aa).x + ad0; e0 = e0 >= 0.f ? e0 : 0.2f * e0;    \
    float e1 = (aa).y + ad1; e1 = e1 >= 0.f ? e1 : 0.2f * e1;    \
    float x0 = __expf(e0), x1 = __expf(e1);                      \
    s0 += x0; s1 += x1;                                          \
    float xa = h0 ? x0 : x1;                                     \
    acc.x = fmaf(bf2f((uu).x), xa, acc.x);                       \
    acc.y = fmaf(bf2f((uu).y), xa, acc.y);                       \
    acc.z = fmaf(bf2f((uu).z), xa, acc.z);                       \
    acc.w = fmaf(bf2f((uu).w), xa, acc.w);                       \
  }

  int k = 0;
  for (; k + 8 <= dg; k += 8) {
    int s_[8];
#pragma unroll
    for (int q = 0; q < 8; ++q) s_[q] = csr[off + k + q];
    float2 a_[8];
    ushort4 u_[8];
#pragma unroll
    for (int q = 0; q < 8; ++q) a_[q] = as2[s_[q]];
#pragma unroll
    for (int q = 0; q < 8; ++q) u_[q] = ((const ushort4*)(xpb + (size_t)s_[q] * 512))[lane];
#pragma unroll
    for (int q = 0; q < 8; ++q) GAT_STEP(a_[q], u_[q]);
  }
  for (; k + 4 <= dg; k += 4) {
    int sa = csr[off + k], sb = csr[off + k + 1], sc = csr[off + k + 2], sd = csr[off + k + 3];
    float2 aa = as2[sa], ab = as2[sb], ac = as2[sc], ad = as2[sd];
    ushort4 ua = ((const ushort4*)(xpb + (size_t)sa * 512))[lane];
    ushort4 ub = ((const ushort4*)(xpb + (size_t)sb * 512))[lane];
    ushort4 uc = ((const ushort4*)(xpb + (size_t)sc * 512))[lane];
    ushort4 ud = ((const ushort4*)(xpb + (size_t)sd * 512))[lane];
    GAT_STEP(aa, ua); GAT_STEP(ab, ub); GAT_STEP(ac, uc); GAT_STEP(ad, ud);
  }
  for (; k < dg; ++k) {
    int s = csr[off + k];
    float2 a = as2[s];
    ushort4 u = ((const ushort4*)(xpb + (size_t)s * 512))[lane];
    GAT_STEP(a, u);
  }
#undef GAT_STEP

  float r = h0 ? (1.f / s0) : (1.f / s1);
  acc.x *= r; acc.y *= r; acc.z *= r; acc.w *= r;

  float ox = __shfl_down(acc.x, 32);
  float oy = __shfl_down(acc.y, 32);
  float oz = __shfl_down(acc.z, 32);
  float ow = __shfl_down(acc.w, 32);
  if (h0) {
    int f4 = lane << 2;
    float4 b = ld4(bias + f4);
    float4 o;
    o.x = fmaxf(0.f, (acc.x + ox) * 0.5f + b.x);
    o.y = fmaxf(0.f, (acc.y + oy) * 0.5f + b.y);
    o.z = fmaxf(0.f, (acc.z + oz) * 0.5f + b.z);
    o.w = fmaxf(0.f, (acc.w + ow) * 0.5f + b.w);
    st4(h1 + (size_t)n * 128 + f4, o);
  }
}

// ---------------- BatchNorm stats ----------------
template <int C>
__global__ __launch_bounds__(256) void bn_stats(const float* __restrict__ h, int N, float* __restrict__ P,
                                                float* __restrict__ PS) {
  constexpr int R = 256 / C;
  __shared__ float sh[256], sh2[256];
  int t = threadIdx.x;
  int c = t % C, r = t / C;
  float s = 0.f, ss = 0.f;
  for (int n = blockIdx.x * R + r; n < N; n += gridDim.x * R) {
    float v = h[(size_t)n * C + c];
    s += v; ss += v * v;
  }
  sh[t] = s; sh2[t] = ss;
  __syncthreads();
  if (r == 0) {
#pragma unroll
    for (int i = 1; i < R; ++i) { s += sh[i * C + c]; ss += sh2[i * C + c]; }
    P[blockIdx.x * C + c] = s;
    PS[blockIdx.x * C + c] = ss;
  }
}

// ---------------- fused BN1 reduce + fold into GCN weights (1 block) ----------------
__global__ __launch_bounds__(256) void bn_fold_gcn(const float* __restrict__ P, const float* __restrict__ PS,
                                                   int G, int N, const float* __restrict__ g,
                                                   const float* __restrict__ b, const float* __restrict__ W,
                                                   float* __restrict__ Wf, float* __restrict__ cvec) {
  __shared__ float ssv[128], stv[128];
  int t = threadIdx.x;
  if (t < 128) {
    float s = 0.f, ss = 0.f;
    for (int i = 0; i < G; ++i) { s += P[i * 128 + t]; ss += PS[i * 128 + t]; }
    float mean = s / N;
    float var = ss / N - mean * mean;
    float sc = g[t] * rsqrtf(var + 1e-5f);
    ssv[t] = sc;
    stv[t] = b[t] - mean * sc;
  }
  __syncthreads();
  for (int i = t; i < 128 * 64; i += 256) {
    int k = i >> 6;
    Wf[i] = ssv[k] * W[i];
  }
  if (t < 64) {
    float c = 0.f;
    for (int k = 0; k < 128; ++k) c += stv[k] * W[k * 64 + t];
    cvec[t] = c;
  }
}

// ---------------- fused BN2 reduce + fold into mu/lv weights (1 block) ----------------
__global__ __launch_bounds__(256) void bn_fold_mulv(const float* __restrict__ P, const float* __restrict__ PS,
                                                    int G, int N, const float* __restrict__ g,
                                                    const float* __restrict__ b,
                                                    const float* __restrict__ Wmu, const float* __restrict__ mub,
                                                    const float* __restrict__ Wlv, const float* __restrict__ lvb,
                                                    float* __restrict__ Wmuf, float* __restrict__ cmu,
                                                    float* __restrict__ Wlvf, float* __restrict__ clv) {
  __shared__ float ssv[64], stv[64];
  int t = threadIdx.x;
  if (t < 64) {
    float s = 0.f, ss = 0.f;
    for (int i = 0; i < G; ++i) { s += P[i * 64 + t]; ss += PS[i * 64 + t]; }
    float mean = s / N;
    float var = ss / N - mean * mean;
    float sc = g[t] * rsqrtf(var + 1e-5f);
    ssv[t] = sc;
    stv[t] = b[t] - mean * sc;
  }
  __syncthreads();
  for (int i = t; i < 4096; i += 256) {
    int k = i >> 6;
    Wmuf[i] = ssv[k] * Wmu[i];
    Wlvf[i] = ssv[k] * Wlv[i];
  }
  if (t < 64) {
    float cm = mub[t], cl = lvb[t];
    for (int k = 0; k < 64; ++k) { cm += stv[k] * Wmu[k * 64 + t]; cl += stv[k] * Wlv[k * 64 + t]; }
    cmu[t] = cm; clv[t] = cl;
  }
}

// ---------------- GCN aggregation (bf16 gather, 8-way unrolled) ----------------
__global__ __launch_bounds__(256) void gcn_aggregate_bf(const int* __restrict__ offs, const int* __restrict__ deg,
                                                        const int* __restrict__ csr,
                                                        const unsigned short* __restrict__ xpb2,
                                                        const float* __restrict__ dinv, const float* __restrict__ bias,
                                                        float* __restrict__ g2, int N) {
  int wid = threadIdx.x >> 6, lane = threadIdx.x & 63;
  int n = blockIdx.x * 4 + wid;
  if (n >= N) return;
  int off = offs[n], dg = deg[n];
  float acc = 0.f;
  int k = 0;
  for (; k + 8 <= dg; k += 8) {
    int s_[8];
#pragma unroll
    for (int q = 0; q < 8; ++q) s_[q] = csr[off + k + q];
    float d_[8];
    unsigned short u_[8];
#pragma unroll
    for (int q = 0; q < 8; ++q) d_[q] = dinv[s_[q]];
#pragma unroll
    for (int q = 0; q < 8; ++q) u_[q] = xpb2[(size_t)s_[q] * 64 + lane];
#pragma unroll
    for (int q = 0; q < 8; ++q) acc = fmaf(bf2f(u_[q]), d_[q], acc);
  }
  for (; k + 4 <= dg; k += 4) {
    int sa = csr[off + k], sb = csr[off + k + 1], sc = csr[off + k + 2], sd = csr[off + k + 3];
    float da = dinv[sa], db = dinv[sb], dc = dinv[sc], dd = dinv[sd];
    unsigned short ua = xpb2[(size_t)sa * 64 + lane];
    unsigned short ub = xpb2[(size_t)sb * 64 + lane];
    unsigned short uc = xpb2[(size_t)sc * 64 + lane];
    unsigned short ud = xpb2[(size_t)sd * 64 + lane];
    acc = fmaf(bf2f(ua), da, acc);
    acc = fmaf(bf2f(ub), db, acc);
    acc = fmaf(bf2f(uc), dc, acc);
    acc = fmaf(bf2f(ud), dd, acc);
  }
  for (; k < dg; ++k) {
    int s = csr[off + k];
    acc = fmaf(bf2f(xpb2[(size_t)s * 64 + lane]), dinv[s], acc);
  }
  float v = acc * dinv[n] + bias[lane];
  g2[(size_t)n * 64 + lane] = fmaxf(v, 0.f);
}

// ---------------- fused tail: mu/lv GEMMs + reparam + res GEMM (64x64 tile, K=64) ----------------
// Block handles 64 rows. Phase 1: mu = g2@Wmuf + cmu, lv = g2@Wlvf + clv (shared g2 tile),
// z = mu + eps*exp(0.5 lv) in registers. Phase 2: rz = z@res_W + res_b (a 64-row tile holds
// complete z rows, LAT=64 = full contraction dim) -> bf16 rzb.
__global__ __launch_bounds__(256) void tail_fused(const float* __restrict__ g2,
                                                  const float* __restrict__ Wmuf, const float* __restrict__ cmu,
                                                  const float* __restrict__ Wlvf, const float* __restrict__ clv,
                                                  const float* __restrict__ resW, const float* __restrict__ resb,
                                                  const float* __restrict__ eps,
                                                  float* __restrict__ mu, float* __restrict__ lv,
                                                  unsigned short* __restrict__ rzb, int N) {
  __shared__ float Gs[64][68];
  __shared__ float Wm[64][64];
  __shared__ float Wl[64][64];
  __shared__ float Rw[64][64];
  int t = threadIdx.x;
  int m0 = blockIdx.x * 64;
  int tm = t & 15, tn = t >> 4;

  // stage g2 transposed Gs[k][row]; weights natural [k][j]
#pragma unroll
  for (int i = 0; i < 4; ++i) {
    int f4 = t + i * 256;
    int row = f4 >> 4;
    int k4 = (f4 & 15) << 2;
    int gr = m0 + row;
    float4 v = make_float4(0.f, 0.f, 0.f, 0.f);
    if (gr < N) v = ld4(g2 + (size_t)gr * 64 + k4);
    Gs[k4 + 0][row] = v.x; Gs[k4 + 1][row] = v.y; Gs[k4 + 2][row] = v.z; Gs[k4 + 3][row] = v.w;
    st4(&Wm[f4 >> 4][k4], ld4(Wmuf + f4 * 4));
    st4(&Wl[f4 >> 4][k4], ld4(Wlvf + f4 * 4));
    st4(&Rw[f4 >> 4][k4], ld4(resW + f4 * 4));
  }
  __syncthreads();

  float am[4][4], al[4][4];
#pragma unroll
  for (int i = 0; i < 4; ++i)
#pragma unroll
    for (int j = 0; j < 4; ++j) { am[i][j] = 0.f; al[i][j] = 0.f; }

#pragma unroll 8
  for (int k = 0; k < 64; ++k) {
    float4 a = ld4(&Gs[k][tm << 2]);
    float4 bm = ld4(&Wm[k][tn << 2]);
    float4 bl = ld4(&Wl[k][tn << 2]);
    float av[4] = {a.x, a.y, a.z, a.w};
    float bmv[4] = {bm.x, bm.y, bm.z, bm.w};
    float blv[4] = {bl.x, bl.y, bl.z, bl.w};
#pragma unroll
    for (int i = 0; i < 4; ++i)
#pragma unroll
      for (int j = 0; j < 4; ++j) {
        am[i][j] = fmaf(av[i], bmv[j], am[i][j]);
        al[i][j] = fmaf(av[i], blv[j], al[i][j]);
      }
  }

  int nb = tn << 2;
  float cm4[4] = {cmu[nb], cmu[nb + 1], cmu[nb + 2], cmu[nb + 3]};
  float cl4[4] = {clv[nb], clv[nb + 1], clv[nb + 2], clv[nb + 3]};
  float zreg[4][4];
#pragma unroll
  for (int i = 0; i < 4; ++i) {
    int gr = m0 + (tm << 2) + i;
    if (gr < N) {
      float4 ep = ld4(eps + (size_t)gr * 64 + nb);
      float epv[4] = {ep.x, ep.y, ep.z, ep.w};
      float muv[4], lvv[4];
#pragma unroll
      for (int j = 0; j < 4; ++j) {
        muv[j] = am[i][j] + cm4[j];
        lvv[j] = al[i][j] + cl4[j];
        zreg[i][j] = fmaf(epv[j], __expf(0.5f * lvv[j]), muv[j]);
      }
      st4(mu + (size_t)gr * 64 + nb, make_float4(muv[0], muv[1], muv[2], muv[3]));
      st4(lv + (size_t)gr * 64 + nb, make_float4(lvv[0], lvv[1], lvv[2], lvv[3]));
    } else {
#pragma unroll
      for (int j = 0; j < 4; ++j) zreg[i][j] = 0.f;
    }
  }

  __syncthreads();   // all phase-1 Gs reads done
  // scatter z transposed: Gs[zcol][row]
#pragma unroll
  for (int i = 0; i < 4; ++i)
#pragma unroll
    for (int j = 0; j < 4; ++j) Gs[(tn << 2) + j][(tm << 2) + i] = zreg[i][j];
  __syncthreads();

  float ar[4][4];
#pragma unroll
  for (int i = 0; i < 4; ++i)
#pragma unroll
    for (int j = 0; j < 4; ++j) ar[i][j] = 0.f;
#pragma unroll 8
  for (int k = 0; k < 64; ++k) {
    float4 a = ld4(&Gs[k][tm << 2]);
    float4 b = ld4(&Rw[k][tn << 2]);
    float av[4] = {a.x, a.y, a.z, a.w};
    float bv[4] = {b.x, b.y, b.z, b.w};
#pragma unroll
    for (int i = 0; i < 4; ++i)
#pragma unroll
      for (int j = 0; j < 4; ++j) ar[i][j] = fmaf(av[i], bv[j], ar[i][j]);
  }
  float rb4[4] = {resb[nb], resb[nb + 1], resb[nb + 2], resb[nb + 3]};
#pragma unroll
  for (int i = 0; i < 4; ++i) {
    int gr = m0 + (tm << 2) + i;
    if (gr < N) {
      ushort4 o;
      o.x = f2bf(ar[i][0] + rb4[0]);
      o.y = f2bf(ar[i][1] + rb4[1]);
      o.z = f2bf(ar[i][2] + rb4[2]);
      o.w = f2bf(ar[i][3] + rb4[3]);
      *(ushort4*)(rzb + (size_t)gr * 64 + nb) = o;
    }
  }
}

// ---------------- prep gat_W -> transposed bf16 Wtb[col][k] ----------------
__global__ void prep_gatW(const float* __restrict__ W, unsigned short* __restrict__ Wtb) {
  int i = blockIdx.x * blockDim.x + threadIdx.x;
  if (i >= 256 * 256) return;
  int col = i >> 8, k = i & 255;
  Wtb[i] = f2bf(W[k * 256 + col]);
}

// ---------------- prep W1 → bf16 decoder layout [4 kt][256 j][40 kp] (padded) ----------------
__global__ void prep_W1(const float* __restrict__ W1, unsigned short* __restrict__ W1t) {
  int i = blockIdx.x * blockDim.x + threadIdx.x;
  if (i >= 4 * 256 * 40) return;
  int kt = i / 10240;
  int rem = i - kt * 10240;
  int j = rem / 40;
  int kp = rem - j * 40;
  float v = (kp < 32) ? W1[(size_t)(kt * 32 + kp) * 256 + j] : 0.f;
  W1t[i] = f2bf(v);
}

// ---------------- MFMA decoder (64 edges, 4 waves, B per-kt in LDS) ----------------
__global__ __launch_bounds__(256) void decoder_mfma(const int* __restrict__ ei, int E,
                                                    const unsigned short* __restrict__ rzb,
                                                    const unsigned short* __restrict__ W1t,
                                                    const float* __restrict__ b1, const float* __restrict__ W2,
                                                    const float* __restrict__ b2, float* __restrict__ recon) {
  __shared__ unsigned short Als[64 * 128];   // 16 KB
  __shared__ unsigned short Bls[256 * 40];   // 20 KB
  __shared__ float red[4][64];
  int t = threadIdx.x;
  int wv = t >> 6, l = t & 63;
  int lg = l >> 4, ll = l & 15;
  int e0 = blockIdx.x * 64;

  {
    int e = t >> 2;
    int part = (t >> 1) & 1;
    int half = t & 1;
    int eg = e0 + e;
    if (eg >= E) eg = E - 1;
    int r = (part == 0) ? ei[eg] : ei[E + eg];
    const uint4* gsrc = (const uint4*)(rzb + (size_t)r * 64 + half * 32);
    int bo0 = part * 128 + half * 64;
    int swz = (e & 7) << 4;
#pragma unroll
    for (int c = 0; c < 4; ++c) {
      uint4 v = gsrc[c];
      int bo = bo0 + c * 16;
      *(uint4*)&Als[e * 128 + ((bo ^ swz) >> 1)] = v;
    }
  }

  f32x4 acc[4][4];
#pragma unroll
  for (int a = 0; a < 4; ++a)
#pragma unroll
    for (int b = 0; b < 4; ++b) acc[a][b] = (f32x4){0.f, 0.f, 0.f, 0.f};

  for (int kt = 0; kt < 4; ++kt) {
    __syncthreads();
    {
      const uint4* gsrc = (const uint4*)(W1t + kt * 10240);
      uint4* ldst = (uint4*)Bls;
#pragma unroll
      for (int i = 0; i < 5; ++i) ldst[t + i * 256] = gsrc[t + i * 256];
    }
    __syncthreads();

    bfrag af[4];
#pragma unroll
    for (int fm = 0; fm < 4; ++fm) {
      int e = fm * 16 + ll;
      int bo = kt * 64 + lg * 16;
      af[fm] = *(const bfrag*)&Als[e * 128 + ((bo ^ ((e & 7) << 4)) >> 1)];
    }
#pragma unroll
    for (int fn = 0; fn < 4; ++fn) {
      int j = wv * 64 + fn * 16 + ll;
      bfrag bf = *(const bfrag*)&Bls[j * 40 + lg * 8];
#pragma unroll
      for (int fm = 0; fm < 4; ++fm)
        acc[fm][fn] = __builtin_amdgcn_mfma_f32_16x16x32_bf16(af[fm], bf, acc[fm][fn], 0, 0, 0);
    }
  }

  float bj[4], wj[4];
#pragma unroll
  for (int fn = 0; fn < 4; ++fn) {
    int j = wv * 64 + fn * 16 + ll;
    bj[fn] = b1[j];
    wj[fn] = W2[j];
  }
#pragma unroll
  for (int fm = 0; fm < 4; ++fm) {
    float pr[4] = {0.f, 0.f, 0.f, 0.f};
#pragma unroll
    for (int fn = 0; fn < 4; ++fn) {
#pragma unroll
      for (int r = 0; r < 4; ++r)
        pr[r] = fmaf(fmaxf(acc[fm][fn][r] + bj[fn], 0.f), wj[fn], pr[r]);
    }
#pragma unroll
    for (int m = 8; m >= 1; m >>= 1) {
#pragma unroll
      for (int r = 0; r < 4; ++r) pr[r] += __shfl_xor(pr[r], m);
    }
    if (ll == 0) {
#pragma unroll
      for (int r = 0; r < 4; ++r) red[wv][fm * 16 + lg * 4 + r] = pr[r];
    }
  }
  __syncthreads();
  if (t < 64) {
    int eg = e0 + t;
    if (eg < E) recon[eg] = red[0][t] + red[1][t] + red[2][t] + red[3][t] + b2[0];
  }
}

extern "C" void kernel_launch(void* const* d_in, const int* in_sizes, int n_in,
                              void* d_out, int out_size, void* d_ws, size_t ws_size,
                              hipStream_t stream) {
  const float* x = (const float*)d_in[0];
  const int* ei = (const int*)d_in[1];
  const float* gat_W = (const float*)d_in[2];
  const float* att_src = (const float*)d_in[3];
  const float* att_dst = (const float*)d_in[4];
  const float* gat_bias = (const float*)d_in[5];
  const float* bn1_g = (const float*)d_in[6];
  const float* bn1_b = (const float*)d_in[7];
  const float* gcn_W = (const float*)d_in[8];
  const float* gcn_bias = (const float*)d_in[9];
  const float* bn2_g = (const float*)d_in[10];
  const float* bn2_b = (const float*)d_in[11];
  const float* mu_W = (const float*)d_in[12];
  const float* mu_b = (const float*)d_in[13];
  const float* lv_W = (const float*)d_in[14];
  const float* lv_b = (const float*)d_in[15];
  const float* res_W = (const float*)d_in[16];
  const float* res_b = (const float*)d_in[17];
  const float* dec_W1 = (const float*)d_in[18];
  const float* dec_b1 = (const float*)d_in[19];
  const float* dec_W2 = (const float*)d_in[20];
  const float* dec_b2 = (const float*)d_in[21];
  const float* eps = (const float*)d_in[22];

  int N = in_sizes[0] / DIN;   // 50000
  int E = in_sizes[1] / 2;     // 800000
  int Et = E + N;
  int NB = (N + 255) / 256;    // scan chunks (<= 256)

  float* ws = (float*)d_ws;
  size_t off = 0;
  float* xp = ws; off += (size_t)N * 256;
  unsigned short* xpb = (unsigned short*)xp;    // bf16 xp rows, stride 512 ushorts
  unsigned short* xpb2 = (unsigned short*)xp;   // bf16 xp2 [N,64] (xpb dead by then)
  float* g2 = xp + (size_t)N * 64;
  float* rz = xp + (size_t)N * 192;
  unsigned short* rzb = (unsigned short*)rz;    // bf16 res_z [N,64]
  float* h1 = ws + off; off += (size_t)N * 128;
  float* a_src = ws + off; off += (size_t)2 * N;
  float* a_dst = ws + off; off += (size_t)2 * N;
  float* dinv = ws + off; off += N;
  float* P = ws + off; off += 128 * 128;
  float* PS = ws + off; off += 128 * 128;
  float* W2f = ws + off; off += 128 * 64;
  float* c2 = ws + off; off += 64;
  float* Wmuf = ws + off; off += 64 * 64;
  float* cmu = ws + off; off += 64;
  float* Wlvf = ws + off; off += 64 * 64;
  float* clv = ws + off; off += 64;
  unsigned short* W1t = (unsigned short*)(ws + off); off += 20480;   // 4*256*40 bf16
  unsigned short* Wtb = (unsigned short*)(ws + off); off += 32768;   // 256*256 bf16
  int* deg = (int*)(ws + off); off += N;
  int* offs = (int*)(ws + off); off += N;
  int* cursor = (int*)(ws + off); off += N;
  int* bsum = (int*)(ws + off); off += 256;
  int* csr = (int*)(ws + off); off += Et;

  float* recon = (float*)d_out;
  float* mu = recon + E;
  float* lv = mu + (size_t)N * LAT;

  // 0. weight preps + zero attn-score accumulators (a_src/a_dst contiguous)
  prep_W1<<<(4 * 256 * 40 + 255) / 256, 256, 0, stream>>>(dec_W1, W1t);
  prep_gatW<<<(256 * 256 + 255) / 256, 256, 0, stream>>>(gat_W, Wtb);
  hipMemsetAsync(a_src, 0, (size_t)4 * N * sizeof(float), stream);

  // 1. xp = x @ gat_W via MFMA; attention scores fused (atomic partials)
  dim3 gX(4, (N + 63) / 64);
  gemm_xp_mfma<<<gX, 256, 0, stream>>>(x, Wtb, att_src, att_dst, xpb, a_src, a_dst, N);

  // 2. CSR build (parallel 3-phase scan)
  hipMemsetAsync(deg, 0, (size_t)N * sizeof(int), stream);
  deg_count<<<(Et + 255) / 256, 256, 0, stream>>>(ei, E, Et, deg);
  bsum_kernel<<<NB, 256, 0, stream>>>(deg, N, bsum);
  bscan_kernel<<<1, 256, 0, stream>>>(bsum, NB);
  scan_apply<<<NB, 256, 0, stream>>>(deg, bsum, N, offs, cursor, dinv);
  csr_fill<<<(Et + 255) / 256, 256, 0, stream>>>(ei, E, Et, cursor, csr);

  // 3. fused GAT softmax + aggregation (8-way MLP unroll)
  gat_fused<<<(N + 3) / 4, 256, 0, stream>>>(offs, deg, csr, a_src, a_dst, xpb, gat_bias, h1, N);

  // 4. BN1 reduce+fold fused; xp2 (bf16) = h1 @ W2f + c2
  bn_stats<128><<<128, 256, 0, stream>>>(h1, N, P, PS);
  bn_fold_gcn<<<1, 256, 0, stream>>>(P, PS, 128, N, bn1_g, bn1_b, gcn_W, W2f, c2);
  dim3 gB((N + 63) / 64, 1);
  gemm64b<<<gB, 256, 0, stream>>>(h1, W2f, c2, xpb2, N, 64, 128);

  // 5. GCN aggregation (bf16 gather, 8-way MLP unroll)
  gcn_aggregate_bf<<<(N + 3) / 4, 256, 0, stream>>>(offs, deg, csr, xpb2, dinv, gcn_bias, g2, N);

  // 6. BN2 reduce+fold; fused tail (mu, lv, reparam, res GEMM in one kernel)
  bn_stats<64><<<128, 256, 0, stream>>>(g2, N, P, PS);
  bn_fold_mulv<<<1, 256, 0, stream>>>(P, PS, 128, N, bn2_g, bn2_b, mu_W, mu_b, lv_W, lv_b,
                                      Wmuf, cmu, Wlvf, clv);
  tail_fused<<<(N + 63) / 64, 256, 0, stream>>>(g2, Wmuf, cmu, Wlvf, clv, res_W, res_b, eps,
                                                mu, lv, rzb, N);

  // 7. MFMA decoder
  decoder_mfma<<<(E + 63) / 64, 256, 0, stream>>>(ei, E, rzb, W1t, dec_b1, dec_W2, dec_b2, recon);
}